// Round 8
// baseline (1126.821 us; speedup 1.0000x reference)
//
#include <hip/hip_runtime.h>
#include <hip/hip_bf16.h>
#include <stdint.h>

#define N_ROWS 32768
#define K_CODES 8192
#define C_DIM 256
#define DECAYF 0.95f
#define COMMITF 0.25f
#define EPSF 1e-5f
#define RESC_EPS 0.02f
#define RESC_CAP 4096

// d_out layout (floats), reference return order
#define OFF_QUANT 0
#define OFF_ELOSS 8388608
#define OFF_PERP  8388609
#define OFF_UNIQ  8388610
#define OFF_NCB   8388611
#define OFF_NCNT  10485763
#define OFF_NW    10493955
#define OFF_IDX   12591107

typedef __hip_bfloat16 bf16;
typedef float f32x4 __attribute__((ext_vector_type(4)));
typedef short bf16x8 __attribute__((ext_vector_type(8)));
typedef unsigned long long u64;

#define SWZ(r) ((((r) >> 2) & 7) << 2)

#if defined(__has_builtin)
#if __has_builtin(__builtin_amdgcn_global_load_lds)
#define HAVE_GLDS 1
#endif
#endif
#ifdef HAVE_GLDS
#define GLDS16(g, l) __builtin_amdgcn_global_load_lds( \
    (const __attribute__((address_space(1))) void*)(uintptr_t)(g), \
    (__attribute__((address_space(3))) void*)(uint32_t)(uintptr_t)(l), 16, 0, 0)
#else
#define GLDS16(g, l) do { *(float4*)(l) = *(const float4*)(g); } while (0)
#endif

__device__ __forceinline__ uint32_t fkey(float f) {
    uint32_t b = __float_as_uint(f);
    return b ^ ((uint32_t)((int32_t)b >> 31) | 0x80000000u);
}
__device__ __forceinline__ float funkey(uint32_t k) {
    uint32_t b = (k & 0x80000000u) ? (k ^ 0x80000000u) : ~k;
    return __uint_as_float(b);
}
__device__ __forceinline__ void split2(float v, unsigned short& h, unsigned short& m) {
    bf16 hb = __float2bfloat16(v);
    float fh = __bfloat162float(hb);
    bf16 mb = __float2bfloat16(v - fh);
    h = *(unsigned short*)&hb; m = *(unsigned short*)&mb;
}
__device__ __forceinline__ float bf2f(unsigned short u) {
    return __bfloat162float(*(bf16*)&u);
}

// ---------------- codebook row squared-norms (fallback path only) ----------------
__global__ void knorm(const float* __restrict__ cb, float* __restrict__ cnorm) {
    const int wid  = threadIdx.x >> 6;
    const int lane = threadIdx.x & 63;
    const int row  = blockIdx.x * 4 + wid;
    const float4 v = *(const float4*)(cb + (size_t)row * C_DIM + lane * 4);
    float s = v.x * v.x + v.y * v.y + v.z * v.z + v.w * v.w;
    #pragma unroll
    for (int off = 32; off; off >>= 1) s += __shfl_down(s, off);
    if (lane == 0) cnorm[row] = s;
}

// ---------------- split codebook into 2 bf16 planes + row norms (fused) ----------------
__global__ void ksplit_cb(const float* __restrict__ cb, unsigned short* __restrict__ Bsp,
                          float* __restrict__ cnorm) {
    const size_t plane = (size_t)K_CODES * C_DIM;
    const size_t i4 = ((size_t)blockIdx.x * 256 + threadIdx.x) * 4;
    const float4 v = *(const float4*)(cb + i4);
    ushort4 h, m;
    split2(v.x, h.x, m.x); split2(v.y, h.y, m.y);
    split2(v.z, h.z, m.z); split2(v.w, h.w, m.w);
    *(ushort4*)(Bsp + i4) = h;
    *(ushort4*)(Bsp + plane + i4) = m;
    float s = v.x * v.x + v.y * v.y + v.z * v.z + v.w * v.w;
    #pragma unroll
    for (int off = 32; off; off >>= 1) s += __shfl_down(s, off);
    if ((threadIdx.x & 63) == 0) cnorm[i4 >> 8] = s;
}

// ---------------- transpose x to [n][c] and split into 2 bf16 planes ----------------
__global__ __launch_bounds__(256)
void ksplit_x(const float* __restrict__ x, unsigned short* __restrict__ Asp) {
    __shared__ float xt[64][65];
    const int t = threadIdx.x;
    const int bid = blockIdx.x;        // 8 b * 4 ct * 64 st = 2048
    const int st = bid & 63;
    const int ct = (bid >> 6) & 3;
    const int b  = bid >> 8;
    const float* xb = x + ((size_t)b * C_DIM + ct * 64) * 4096 + st * 64;
    {
        const int s_l = t & 63, c0 = t >> 6;
        #pragma unroll
        for (int cc = 0; cc < 16; ++cc) {
            int c_l = cc * 4 + c0;
            xt[c_l][s_l] = xb[(size_t)c_l * 4096 + s_l];
        }
    }
    __syncthreads();
    const size_t plane = (size_t)N_ROWS * C_DIM;
    const int c2 = (t & 31) * 2;
    const int s0 = t >> 5;
    #pragma unroll
    for (int ww = 0; ww < 8; ++ww) {
        int s_o = ww * 8 + s0;
        float v0 = xt[c2][s_o], v1 = xt[c2 + 1][s_o];
        unsigned short h0, m0_, h1, m1_;
        split2(v0, h0, m0_); split2(v1, h1, m1_);
        size_t off = ((size_t)(b * 4096 + st * 64 + s_o)) * C_DIM + ct * 64 + c2;
        *(ushort2*)(Asp + off)         = make_ushort2(h0, h1);
        *(ushort2*)(Asp + plane + off) = make_ushort2(m0_, m1_);
    }
}

// ---------------- MFMA distance GEMM + per-row top-2 argmin ----------------
// 256x256 tile, 8 waves (2Mx4N). LDS [dbuf][half][128x64] per operand.
// Wave owns 64 rows in EACH A-half + 32 cols in EACH B-half.
// 4 quadrant-phases per K-tile: Q(A0,B0) Q(A0,B1) Q(A1,B1) Q(A1,B0);
// one half-tile staged per phase (deadline order A0',B0',B1',A1');
// counted s_waitcnt vmcnt(4) (T4) -- loads stay in flight across barriers.
__global__ __launch_bounds__(512, 2)
void kargmin_mfma(const unsigned short* __restrict__ Asp, const unsigned short* __restrict__ Bsp,
                  const float* __restrict__ cnorm, u64* __restrict__ wsmin) {
    __shared__ unsigned short As[2][2][128 * 64];
    __shared__ unsigned short Bs[2][2][128 * 64];

    const int t = threadIdx.x;
    const int lane = t & 63;
    const int wid = t >> 6;
    const int swz = (blockIdx.x & 7) * 512 + (blockIdx.x >> 3);
    const int mtile = swz & 127;
    const int ntile = swz >> 7;
    const int m0 = mtile * 256;
    const int n0 = ntile * 256;
    const int wr = wid >> 2;          // 0..1
    const int wc = wid & 3;           // 0..3
    const int lm = lane & 15;
    const int lh = lane >> 4;
    const int l7 = lane & 7;
    const int NKT = 12;

    f32x4 acc[8][4];   // [ha*4+i][hb*2+j]
    #pragma unroll
    for (int i = 0; i < 8; ++i)
        #pragma unroll
        for (int j = 0; j < 4; ++j) acc[i][j] = (f32x4){0.f, 0.f, 0.f, 0.f};

    // staging: half-tile = 128 rows x 64 cols bf16 = 16KB = 2 glds/thread-wave set
    const int sr0 = t >> 3;                 // 0..63
    const int gs0 = (t & 7) ^ (sr0 & 7);    // same for row sr0+64

    auto stageA = [&](int kt, int buf, int h) {
        const int seg = kt >> 2;            // 0..2 ; pa = seg>>1
        const int kk0 = (kt & 3) * 64;
        const unsigned short* Ab = Asp + ((size_t)(seg >> 1) * N_ROWS + m0 + h * 128) * C_DIM + kk0;
        GLDS16(Ab + (size_t)sr0 * C_DIM + gs0 * 8,        &As[buf][h][t * 8]);
        GLDS16(Ab + (size_t)(64 + sr0) * C_DIM + gs0 * 8, &As[buf][h][(512 + t) * 8]);
    };
    auto stageB = [&](int kt, int buf, int h) {
        const int seg = kt >> 2;            // pb = seg&1
        const int kk0 = (kt & 3) * 64;
        const unsigned short* Bb = Bsp + ((size_t)(seg & 1) * K_CODES + n0 + h * 128) * C_DIM + kk0;
        GLDS16(Bb + (size_t)sr0 * C_DIM + gs0 * 8,        &Bs[buf][h][t * 8]);
        GLDS16(Bb + (size_t)(64 + sr0) * C_DIM + gs0 * 8, &Bs[buf][h][(512 + t) * 8]);
    };

    const int sw0 = (lh ^ l7) * 8;
    const int sw1 = ((4 + lh) ^ l7) * 8;

    // prologue: 4 half-tiles of K-tile 0; wait oldest 2 (A0,B0)
    stageA(0, 0, 0);
    stageB(0, 0, 0);
    stageB(0, 0, 1);
    stageA(0, 0, 1);
    asm volatile("s_waitcnt vmcnt(4)" ::: "memory");
    __builtin_amdgcn_sched_barrier(0);
    __builtin_amdgcn_s_barrier();

    bf16x8 ar[4][2], b0r[2][2], b1r[2][2];

    #pragma unroll 2
    for (int kt = 0; kt < NKT; ++kt) {
        const int c = kt & 1;
        const bool pf = (kt + 1 < NKT);

        // ---- P1: Q(A0,B0). reads a(ha=0) + b0(hb=0); stage A0'
        #pragma unroll
        for (int i = 0; i < 4; ++i) {
            const int ro = (wr * 64 + i * 16 + lm) * 64;
            ar[i][0] = *(const bf16x8*)&As[c][0][ro + sw0];
            ar[i][1] = *(const bf16x8*)&As[c][0][ro + sw1];
        }
        #pragma unroll
        for (int j = 0; j < 2; ++j) {
            const int ro = (wc * 32 + j * 16 + lm) * 64;
            b0r[j][0] = *(const bf16x8*)&Bs[c][0][ro + sw0];
            b0r[j][1] = *(const bf16x8*)&Bs[c][0][ro + sw1];
        }
        if (pf) {
            stageA(kt + 1, c ^ 1, 0);
            asm volatile("s_waitcnt vmcnt(4)" ::: "memory");   // B1(kt) landed
        } else {
            asm volatile("s_waitcnt vmcnt(2)" ::: "memory");
        }
        __builtin_amdgcn_sched_barrier(0);
        __builtin_amdgcn_s_barrier();
        __builtin_amdgcn_s_setprio(1);
        #pragma unroll
        for (int i = 0; i < 4; ++i)
            #pragma unroll
            for (int j = 0; j < 2; ++j) {
                acc[i][j] = __builtin_amdgcn_mfma_f32_16x16x32_bf16(ar[i][0], b0r[j][0], acc[i][j], 0, 0, 0);
                acc[i][j] = __builtin_amdgcn_mfma_f32_16x16x32_bf16(ar[i][1], b0r[j][1], acc[i][j], 0, 0, 0);
            }
        __builtin_amdgcn_s_setprio(0);
        __builtin_amdgcn_s_barrier();

        // ---- P2: Q(A0,B1). reads b1(hb=1); stage B0'
        #pragma unroll
        for (int j = 0; j < 2; ++j) {
            const int ro = (wc * 32 + j * 16 + lm) * 64;
            b1r[j][0] = *(const bf16x8*)&Bs[c][1][ro + sw0];
            b1r[j][1] = *(const bf16x8*)&Bs[c][1][ro + sw1];
        }
        if (pf) {
            stageB(kt + 1, c ^ 1, 0);
            asm volatile("s_waitcnt vmcnt(4)" ::: "memory");   // A1(kt) landed
        } else {
            asm volatile("s_waitcnt vmcnt(0)" ::: "memory");
        }
        __builtin_amdgcn_sched_barrier(0);
        __builtin_amdgcn_s_barrier();
        __builtin_amdgcn_s_setprio(1);
        #pragma unroll
        for (int i = 0; i < 4; ++i)
            #pragma unroll
            for (int j = 0; j < 2; ++j) {
                acc[i][2 + j] = __builtin_amdgcn_mfma_f32_16x16x32_bf16(ar[i][0], b1r[j][0], acc[i][2 + j], 0, 0, 0);
                acc[i][2 + j] = __builtin_amdgcn_mfma_f32_16x16x32_bf16(ar[i][1], b1r[j][1], acc[i][2 + j], 0, 0, 0);
            }
        __builtin_amdgcn_s_setprio(0);
        __builtin_amdgcn_s_barrier();

        // ---- P3: Q(A1,B1). reads a(ha=1) (reuse ar); stage B1'
        #pragma unroll
        for (int i = 0; i < 4; ++i) {
            const int ro = (wr * 64 + i * 16 + lm) * 64;
            ar[i][0] = *(const bf16x8*)&As[c][1][ro + sw0];
            ar[i][1] = *(const bf16x8*)&As[c][1][ro + sw1];
        }
        if (pf) stageB(kt + 1, c ^ 1, 1);
        __builtin_amdgcn_sched_barrier(0);
        __builtin_amdgcn_s_barrier();
        __builtin_amdgcn_s_setprio(1);
        #pragma unroll
        for (int i = 0; i < 4; ++i)
            #pragma unroll
            for (int j = 0; j < 2; ++j) {
                acc[4 + i][2 + j] = __builtin_amdgcn_mfma_f32_16x16x32_bf16(ar[i][0], b1r[j][0], acc[4 + i][2 + j], 0, 0, 0);
                acc[4 + i][2 + j] = __builtin_amdgcn_mfma_f32_16x16x32_bf16(ar[i][1], b1r[j][1], acc[4 + i][2 + j], 0, 0, 0);
            }
        __builtin_amdgcn_s_setprio(0);
        __builtin_amdgcn_s_barrier();

        // ---- P4: Q(A1,B0). no reads; stage A1'
        if (pf) {
            stageA(kt + 1, c ^ 1, 1);
            asm volatile("s_waitcnt vmcnt(4)" ::: "memory");   // A0',B0' landed
        }
        __builtin_amdgcn_sched_barrier(0);
        __builtin_amdgcn_s_barrier();
        __builtin_amdgcn_s_setprio(1);
        #pragma unroll
        for (int i = 0; i < 4; ++i)
            #pragma unroll
            for (int j = 0; j < 2; ++j) {
                acc[4 + i][j] = __builtin_amdgcn_mfma_f32_16x16x32_bf16(ar[i][0], b0r[j][0], acc[4 + i][j], 0, 0, 0);
                acc[4 + i][j] = __builtin_amdgcn_mfma_f32_16x16x32_bf16(ar[i][1], b0r[j][1], acc[4 + i][j], 0, 0, 0);
            }
        __builtin_amdgcn_s_setprio(0);
        __builtin_amdgcn_s_barrier();
    }

    // epilogue: dist = cnorm - 2*dot ; per-row top-2 (distkey<<32 | code)
    // acc[I][J]: row = m0 + (I>>2)*128 + wr*64 + (I&3)*16 + lh*4 + r
    //            col = n0 + (J>>1)*128 + wc*32 + (J&1)*16 + lm
    float cn[4];
    #pragma unroll
    for (int J = 0; J < 4; ++J)
        cn[J] = cnorm[n0 + (J >> 1) * 128 + wc * 32 + (J & 1) * 16 + lm];

    u64* redbuf = (u64*)&As[0][0];
    #pragma unroll
    for (int I = 0; I < 8; ++I) {
        u64 p1[4], p2[4];
        #pragma unroll
        for (int r = 0; r < 4; ++r) {
            u64 b1_ = ~0ull, b2_ = ~0ull;
            #pragma unroll
            for (int J = 0; J < 4; ++J) {
                float dist = fmaf(-2.f, acc[I][J][r], cn[J]);
                const unsigned code = (unsigned)(n0 + (J >> 1) * 128 + wc * 32 + (J & 1) * 16 + lm);
                u64 pk = ((u64)fkey(dist) << 32) | code;
                if (pk < b1_) { b2_ = b1_; b1_ = pk; }
                else if (pk < b2_) b2_ = pk;
            }
            p1[r] = b1_; p2[r] = b2_;
        }
        #pragma unroll
        for (int off = 1; off < 16; off <<= 1) {
            #pragma unroll
            for (int r = 0; r < 4; ++r) {
                u64 o1 = __shfl_xor(p1[r], off);
                u64 o2 = __shfl_xor(p2[r], off);
                u64 lo = p1[r] < o1 ? p1[r] : o1;
                u64 hi = p1[r] < o1 ? o1 : p1[r];
                u64 mn2 = p2[r] < o2 ? p2[r] : o2;
                p1[r] = lo;
                p2[r] = hi < mn2 ? hi : mn2;
            }
        }
        if (lm == 0) {
            #pragma unroll
            for (int r = 0; r < 4; ++r) {
                const int rl = (I >> 2) * 128 + wr * 64 + (I & 3) * 16 + lh * 4 + r;
                redbuf[rl * 8 + wc * 2 + 0] = p1[r];
                redbuf[rl * 8 + wc * 2 + 1] = p2[r];
            }
        }
    }
    __syncthreads();
    if (t < 256) {
        u64 m1 = ~0ull, m2 = ~0ull;
        #pragma unroll
        for (int w = 0; w < 4; ++w) {
            u64 a1 = redbuf[t * 8 + w * 2 + 0];
            u64 a2 = redbuf[t * 8 + w * 2 + 1];
            u64 lo = m1 < a1 ? m1 : a1;
            u64 hi = m1 < a1 ? a1 : m1;
            u64 mn2 = m2 < a2 ? m2 : a2;
            m1 = lo;
            m2 = hi < mn2 ? hi : mn2;
        }
        size_t o = ((size_t)(m0 + t) * 32 + ntile) * 2;
        wsmin[o] = m1; wsmin[o + 1] = m2;
    }
}

// ---------------- combine per-ntile mins; histogram; flag near-ties ----------------
__global__ void kcombine(const u64* __restrict__ wsmin, float* __restrict__ idxf,
                         unsigned* __restrict__ rcnt, unsigned* __restrict__ rrows,
                         float* __restrict__ counts) {
    const int row = blockIdx.x * 256 + threadIdx.x;
    const u64* p = wsmin + (size_t)row * 64;
    u64 m1 = ~0ull, m2 = ~0ull;
    for (int i = 0; i < 64; i += 2) {
        u64 a = p[i], b = p[i + 1];
        u64 lo = a < m1 ? a : m1;
        u64 hi = a < m1 ? m1 : a;
        u64 c = m2 < b ? m2 : b;
        m1 = lo;
        m2 = hi < c ? hi : c;
    }
    const int k = (int)(unsigned)(m1 & 0xffffffffu);
    idxf[row] = (float)k;
    atomicAdd(&counts[k], 1.0f);
    float d1 = funkey((uint32_t)(m1 >> 32));
    float d2 = funkey((uint32_t)(m2 >> 32));
    if (d2 - d1 < RESC_EPS) {
        unsigned slot = atomicAdd(rcnt, 1u);
        if (slot < RESC_CAP) rrows[slot] = (unsigned)row;
    }
}

// ---------------- exact fp32 re-score for near-tie rows (fixes counts on flip) ----------------
__global__ __launch_bounds__(256)
void krescue(const float* __restrict__ x, const float* __restrict__ cb,
             const float* __restrict__ cnorm, const unsigned* __restrict__ rcnt,
             const unsigned* __restrict__ rrows, float* __restrict__ idxf,
             float* __restrict__ counts) {
    __shared__ float xs[256];
    __shared__ u64 red[4];
    unsigned cnt = *rcnt; if (cnt > RESC_CAP) cnt = RESC_CAP;
    for (unsigned li = blockIdx.x; li < cnt; li += gridDim.x) {
        const int row = (int)rrows[li];
        const int b = row >> 12, s = row & 4095;
        xs[threadIdx.x] = x[((size_t)b * C_DIM + threadIdx.x) * 4096 + s];
        __syncthreads();
        u64 best = ~0ull;
        for (int k0 = 0; k0 < K_CODES; k0 += 256) {
            const int k = k0 + threadIdx.x;
            const float* cr = cb + (size_t)k * C_DIM;
            float dot = 0.f;
            #pragma unroll 8
            for (int c = 0; c < C_DIM; ++c) dot = fmaf(xs[c], cr[c], dot);
            float dist = fmaf(-2.f, dot, cnorm[k]);
            u64 pk = ((u64)fkey(dist) << 32) | (unsigned)k;
            if (pk < best) best = pk;
        }
        #pragma unroll
        for (int off = 32; off; off >>= 1) {
            u64 o = __shfl_down(best, off);
            if (o < best) best = o;
        }
        if ((threadIdx.x & 63) == 0) red[threadIdx.x >> 6] = best;
        __syncthreads();
        if (threadIdx.x == 0) {
            u64 r0 = red[0];
            #pragma unroll
            for (int w = 1; w < 4; ++w) if (red[w] < r0) r0 = red[w];
            const int knew = (int)(unsigned)(r0 & 0xffffffffu);
            const int kold = (int)idxf[row];
            if (knew != kold) {
                atomicAdd(&counts[kold], -1.0f);
                atomicAdd(&counts[knew], 1.0f);
                idxf[row] = (float)knew;
            }
        }
        __syncthreads();
    }
}

// ---------------- CSR build: scan / scatter ----------------
__global__ void kscan(const float* __restrict__ counts, unsigned* __restrict__ off,
                      unsigned* __restrict__ cursor) {
    __shared__ unsigned part[256];
    const int t = threadIdx.x;
    unsigned local[32];
    unsigned s = 0;
    #pragma unroll
    for (int i = 0; i < 32; ++i) { local[i] = s; s += (unsigned)counts[t * 32 + i]; }
    part[t] = s;
    __syncthreads();
    if (t == 0) {
        unsigned run = 0;
        for (int i = 0; i < 256; ++i) { unsigned v = part[i]; part[i] = run; run += v; }
    }
    __syncthreads();
    const unsigned base = part[t];
    #pragma unroll
    for (int i = 0; i < 32; ++i) {
        unsigned o = base + local[i];
        off[t * 32 + i] = o;
        cursor[t * 32 + i] = o;
    }
}

__global__ void kscatter(const float* __restrict__ idxf, unsigned* __restrict__ cursor,
                         unsigned* __restrict__ rowlist) {
    const int n = blockIdx.x * 256 + threadIdx.x;
    const int k = (int)idxf[n];
    unsigned pos = atomicAdd(&cursor[k], 1u);
    rowlist[pos] = (unsigned)n;
}

// ---------------- dw = segment_sum(x) via CSR, from bf16 h+m planes ----------------
__global__ void kdw(const unsigned short* __restrict__ Asp, const float* __restrict__ counts,
                    const unsigned* __restrict__ off, const unsigned* __restrict__ rowlist,
                    float* __restrict__ dwout) {
    const int k = blockIdx.x;
    const int lane = threadIdx.x;   // 64
    const int cnt = (int)counts[k];
    const unsigned base = off[k];
    const size_t plane = (size_t)N_ROWS * C_DIM;
    float4 acc = make_float4(0.f, 0.f, 0.f, 0.f);
    for (int i = 0; i < cnt; ++i) {
        const unsigned row = rowlist[base + i];
        const ushort4 h = *(const ushort4*)(Asp + (size_t)row * C_DIM + lane * 4);
        const ushort4 m = *(const ushort4*)(Asp + plane + (size_t)row * C_DIM + lane * 4);
        acc.x += bf2f(h.x) + bf2f(m.x);
        acc.y += bf2f(h.y) + bf2f(m.y);
        acc.z += bf2f(h.z) + bf2f(m.z);
        acc.w += bf2f(h.w) + bf2f(m.w);
    }
    *(float4*)(dwout + (size_t)k * C_DIM + lane * 4) = acc;
}

// ---------------- quantize (gather-transpose) + e_loss ----------------
__global__ __launch_bounds__(256)
void kquant2(const float* __restrict__ x, const float* __restrict__ cb,
             const float* __restrict__ idxf, float* __restrict__ qout,
             float* __restrict__ loss_arr) {
    __shared__ int ki[64];
    __shared__ float cbt[64][257];
    const int t = threadIdx.x;
    const int bid = blockIdx.x;
    const int chunk = bid & 63;
    const int b = bid >> 6;
    const int s0 = chunk * 64;
    if (t < 64) ki[t] = (int)idxf[b * 4096 + s0 + t];
    __syncthreads();
    {
        const int lane = t & 63;
        const int rr = t >> 6;
        #pragma unroll
        for (int p = 0; p < 16; ++p) {
            const int r = p * 4 + rr;
            const float4 v = *(const float4*)(cb + (size_t)ki[r] * C_DIM + lane * 4);
            cbt[r][lane * 4 + 0] = v.x;
            cbt[r][lane * 4 + 1] = v.y;
            cbt[r][lane * 4 + 2] = v.z;
            cbt[r][lane * 4 + 3] = v.w;
        }
    }
    __syncthreads();
    const int sg = t & 15;
    const int c0 = t >> 4;
    float lsum = 0.f;
    #pragma unroll
    for (int cc = 0; cc < 16; ++cc) {
        const int c = cc * 16 + c0;
        const size_t go = ((size_t)b * C_DIM + c) * 4096 + s0 + sg * 4;
        const float4 xv = *(const float4*)(x + go);
        float qx = cbt[sg * 4 + 0][c];
        float qy = cbt[sg * 4 + 1][c];
        float qz = cbt[sg * 4 + 2][c];
        float qw = cbt[sg * 4 + 3][c];
        float4 st;
        st.x = xv.x + (qx - xv.x);
        st.y = xv.y + (qy - xv.y);
        st.z = xv.z + (qz - xv.z);
        st.w = xv.w + (qw - xv.w);
        *(float4*)(qout + go) = st;
        float dx = qx - xv.x, dy = qy - xv.y, dz = qz - xv.z, dw_ = qw - xv.w;
        lsum += dx * dx + dy * dy + dz * dz + dw_ * dw_;
    }
    #pragma unroll
    for (int off = 32; off; off >>= 1) lsum += __shfl_down(lsum, off);
    __shared__ float ps[4];
    if ((t & 63) == 0) ps[t >> 6] = lsum;
    __syncthreads();
    if (t == 0) atomicAdd(&loss_arr[bid & 255], ps[0] + ps[1] + ps[2] + ps[3]);
}

// ---------------- perplexity / unique / e_loss ----------------
__global__ void kstats(const float* __restrict__ counts, const float* __restrict__ loss_arr,
                       float* __restrict__ out) {
    const int t = threadIdx.x;
    float nz = 0.f, s = 0.f;
    for (int k = t; k < K_CODES; k += 256) {
        float cnt = counts[k];
        if (cnt != 0.f) nz += 1.f;
        float p = cnt * (1.f / 32768.f);
        s += p * logf(p + 1e-10f);
    }
    float ls = loss_arr[t];
    #pragma unroll
    for (int off = 32; off; off >>= 1) {
        s  += __shfl_down(s, off);
        nz += __shfl_down(nz, off);
        ls += __shfl_down(ls, off);
    }
    __shared__ float ss[4], zz[4], ll[4];
    const int wid = t >> 6, lane = t & 63;
    if (lane == 0) { ss[wid] = s; zz[wid] = nz; ll[wid] = ls; }
    __syncthreads();
    if (t == 0) {
        float st = ss[0] + ss[1] + ss[2] + ss[3];
        float zt = zz[0] + zz[1] + zz[2] + zz[3];
        float lt = ll[0] + ll[1] + ll[2] + ll[3];
        out[OFF_ELOSS] = COMMITF * lt / 8388608.f;
        out[OFF_PERP]  = expf(-st);
        out[OFF_UNIQ]  = zt;
    }
}

// ---------------- EMA finalize ----------------
__global__ void kfinal2(const float* __restrict__ ema_c, const float* __restrict__ ema_w,
                        const float* __restrict__ counts, float* __restrict__ dw,
                        float* __restrict__ ncb, float* __restrict__ ncnt_out) {
    const int k = blockIdx.x;
    const int c = threadIdx.x;
    const float ncnt = (DECAYF * ema_c[k] + (1.f - DECAYF) * counts[k] + EPSF)
                       / (8.f + (float)K_CODES * EPSF) * 8.f;
    const size_t o = (size_t)k * C_DIM + c;
    const float nwv = DECAYF * ema_w[o] + (1.f - DECAYF) * dw[o];
    dw[o]  = nwv;
    ncb[o] = nwv / ncnt;
    if (c == 0) ncnt_out[k] = ncnt;
}

// ======= fallback fp32 path (used only if ws too small) =======
__launch_bounds__(256, 1)
__global__ void kargmin_fp32(const float* __restrict__ x, const float* __restrict__ cb,
                             const float* __restrict__ cnorm, float* __restrict__ idxf) {
    __shared__ float xs[64][256];
    __shared__ float es[64][256];
    const int t  = threadIdx.x;
    const int n0 = blockIdx.x * 64;
    const int b  = n0 >> 12;
    const int s0 = n0 & 4095;
    {
        const int r  = t & 63;
        const int c0 = t >> 6;
        const float* xb = x + (size_t)b * C_DIM * 4096 + s0 + r;
        const int sw = SWZ(r);
        #pragma unroll 8
        for (int cc = 0; cc < 64; ++cc) {
            int c = cc * 4 + c0;
            xs[r][c ^ sw] = xb[(size_t)c * 4096];
        }
    }
    const int mg  = t >> 4;
    const int ng  = t & 15;
    const int m0  = mg * 4;
    const int nn0 = ng * 4;
    const int swm = SWZ(m0);
    const int swn = SWZ(nn0);
    float minv[4] = {1e30f, 1e30f, 1e30f, 1e30f};
    int   mini[4] = {0, 0, 0, 0};
    for (int k0 = 0; k0 < K_CODES; k0 += 64) {
        __syncthreads();
        {
            const int lane = t & 63;
            const int cw   = t >> 6;
            #pragma unroll
            for (int p = 0; p < 16; ++p) {
                int code = p * 4 + cw;
                float4 v = *(const float4*)(cb + (size_t)(k0 + code) * C_DIM + lane * 4);
                *(float4*)&es[code][(lane * 4) ^ SWZ(code)] = v;
            }
        }
        float cn[4];
        #pragma unroll
        for (int j = 0; j < 4; ++j) cn[j] = cnorm[k0 + nn0 + j];
        __syncthreads();
        float acc[4][4];
        #pragma unroll
        for (int i = 0; i < 4; ++i)
            #pragma unroll
            for (int j = 0; j < 4; ++j) acc[i][j] = 0.f;
        #pragma unroll 4
        for (int c = 0; c < C_DIM; c += 4) {
            float4 xa[4], eb[4];
            #pragma unroll
            for (int i = 0; i < 4; ++i) xa[i] = *(const float4*)&xs[m0 + i][c ^ swm];
            #pragma unroll
            for (int j = 0; j < 4; ++j) eb[j] = *(const float4*)&es[nn0 + j][c ^ swn];
            #pragma unroll
            for (int i = 0; i < 4; ++i)
                #pragma unroll
                for (int j = 0; j < 4; ++j)
                    acc[i][j] += xa[i].x * eb[j].x + xa[i].y * eb[j].y +
                                 xa[i].z * eb[j].z + xa[i].w * eb[j].w;
        }
        #pragma unroll
        for (int j = 0; j < 4; ++j) {
            const int kg = k0 + nn0 + j;
            #pragma unroll
            for (int i = 0; i < 4; ++i) {
                float dist = fmaf(-2.f, acc[i][j], cn[j]);
                if (dist < minv[i]) { minv[i] = dist; mini[i] = kg; }
            }
        }
    }
    #pragma unroll
    for (int off = 1; off < 16; off <<= 1) {
        #pragma unroll
        for (int i = 0; i < 4; ++i) {
            float ov = __shfl_xor(minv[i], off);
            int   oi = __shfl_xor(mini[i], off);
            if (ov < minv[i] || (ov == minv[i] && oi < mini[i])) { minv[i] = ov; mini[i] = oi; }
        }
    }
    if (ng == 0) {
        #pragma unroll
        for (int i = 0; i < 4; ++i) idxf[n0 + m0 + i] = (float)mini[i];
    }
}

__global__ void kquant_legacy(const float* __restrict__ x, const float* __restrict__ cb,
                              const float* __restrict__ idxf, float* __restrict__ qout,
                              float* __restrict__ dw, float* __restrict__ counts,
                              float* __restrict__ loss_arr) {
    const int t   = threadIdx.x;
    const int bid = blockIdx.x;
    const int sc  = bid & 15;
    const int c   = (bid >> 4) & 255;
    const int b   = bid >> 12;
    const int s   = sc * 256 + t;
    const int n   = b * 4096 + s;
    const int k   = (int)idxf[n];
    const size_t xoff = ((size_t)b * C_DIM + c) * 4096 + s;
    const float xv = x[xoff];
    const float q  = cb[(size_t)k * C_DIM + c];
    qout[xoff] = xv + (q - xv);
    atomicAdd(&dw[(size_t)k * C_DIM + c], xv);
    if (c == 0) atomicAdd(&counts[k], 1.0f);
    float d = q - xv;
    float p = d * d;
    #pragma unroll
    for (int off = 32; off; off >>= 1) p += __shfl_down(p, off);
    __shared__ float ps[4];
    if ((t & 63) == 0) ps[t >> 6] = p;
    __syncthreads();
    if (t == 0) atomicAdd(&loss_arr[bid & 255], ps[0] + ps[1] + ps[2] + ps[3]);
}

__global__ void kfinal_legacy(const float* __restrict__ ema_c, const float* __restrict__ ema_w,
                              float* __restrict__ counts, float* __restrict__ dw,
                              float* __restrict__ ncb) {
    const int k = blockIdx.x;
    const int c = threadIdx.x;
    const float cnt  = counts[k];
    const float ncnt = (DECAYF * ema_c[k] + (1.f - DECAYF) * cnt + EPSF)
                       / (8.f + (float)K_CODES * EPSF) * 8.f;
    const size_t o = (size_t)k * C_DIM + c;
    const float nw = DECAYF * ema_w[o] + (1.f - DECAYF) * dw[o];
    __syncthreads();
    dw[o]  = nw;
    ncb[o] = nw / ncnt;
    if (c == 0) counts[k] = ncnt;
}

extern "C" void kernel_launch(void* const* d_in, const int* in_sizes, int n_in,
                              void* d_out, int out_size, void* d_ws, size_t ws_size,
                              hipStream_t stream) {
    const float* x     = (const float*)d_in[0];
    const float* cb    = (const float*)d_in[1];
    const float* ema_c = (const float*)d_in[2];
    const float* ema_w = (const float*)d_in[3];
    float* out = (float*)d_out;

    float* qout = out + OFF_QUANT;
    float* ncb  = out + OFF_NCB;
    float* ncnt = out + OFF_NCNT;
    float* nw   = out + OFF_NW;
    float* idxf = out + OFF_IDX;

    const size_t planeA = (size_t)2 * N_ROWS * C_DIM;   // bf16 elems (h,m)
    const size_t planeB = (size_t)2 * K_CODES * C_DIM;
    const size_t tail_f = K_CODES + 256 + K_CODES;
    const size_t tail_u = 1 + RESC_CAP + K_CODES + K_CODES + N_ROWS;
    const size_t need = (planeA + planeB) * 2 + (tail_f + tail_u) * 4 + 64;
    const bool use_mfma = ws_size >= need;

    if (use_mfma) {
        unsigned short* Asp = (unsigned short*)d_ws;
        unsigned short* Bsp = Asp + planeA;
        float* cnorm      = (float*)(Bsp + planeB);
        float* loss_arr   = cnorm + K_CODES;
        float* counts_raw = loss_arr + 256;
        unsigned* rcnt    = (unsigned*)(counts_raw + K_CODES);
        unsigned* rrows   = rcnt + 1;
        unsigned* off     = rrows + RESC_CAP;
        unsigned* cursor  = off + K_CODES;
        unsigned* rowlist = cursor + K_CODES;
        u64* wsmin = (u64*)(out + OFF_QUANT);   // 16 MB, consumed before kquant2 writes qout

        hipMemsetAsync(loss_arr, 0, 256 * sizeof(float), stream);
        hipMemsetAsync(counts_raw, 0, K_CODES * sizeof(float), stream);
        hipMemsetAsync(rcnt, 0, sizeof(unsigned), stream);

        ksplit_cb<<<(K_CODES * C_DIM / 4) / 256, 256, 0, stream>>>(cb, Bsp, cnorm);
        ksplit_x<<<2048, 256, 0, stream>>>(x, Asp);
        kargmin_mfma<<<4096, 512, 0, stream>>>(Asp, Bsp, cnorm, wsmin);
        kcombine<<<N_ROWS / 256, 256, 0, stream>>>(wsmin, idxf, rcnt, rrows, counts_raw);
        krescue<<<256, 256, 0, stream>>>(x, cb, cnorm, rcnt, rrows, idxf, counts_raw);
        kscan<<<1, 256, 0, stream>>>(counts_raw, off, cursor);
        kscatter<<<N_ROWS / 256, 256, 0, stream>>>(idxf, cursor, rowlist);
        kdw<<<K_CODES, 64, 0, stream>>>(Asp, counts_raw, off, rowlist, nw);
        kquant2<<<512, 256, 0, stream>>>(x, cb, idxf, qout, loss_arr);
        kstats<<<1, 256, 0, stream>>>(counts_raw, loss_arr, out);
        kfinal2<<<K_CODES, C_DIM, 0, stream>>>(ema_c, ema_w, counts_raw, nw, ncb, ncnt);
    } else {
        float* cnorm = (float*)d_ws;
        float* loss_arr = cnorm + K_CODES;
        hipMemsetAsync(ncnt, 0, K_CODES * sizeof(float), stream);
        hipMemsetAsync(nw, 0, (size_t)K_CODES * C_DIM * sizeof(float), stream);
        hipMemsetAsync(loss_arr, 0, 256 * sizeof(float), stream);
        knorm<<<K_CODES / 4, 256, 0, stream>>>(cb, cnorm);
        kargmin_fp32<<<N_ROWS / 64, 256, 0, stream>>>(x, cb, cnorm, idxf);
        kquant_legacy<<<32768, 256, 0, stream>>>(x, cb, idxf, qout, nw, ncnt, loss_arr);
        kstats<<<1, 256, 0, stream>>>(ncnt, loss_arr, out);
        kfinal_legacy<<<K_CODES, C_DIM, 0, stream>>>(ema_c, ema_w, ncnt, nw, ncb);
    }
}

// Round 9
// 1073.315 us; speedup vs baseline: 1.0499x; 1.0499x over previous
//
#include <hip/hip_runtime.h>
#include <hip/hip_bf16.h>
#include <stdint.h>

#define N_ROWS 32768
#define K_CODES 8192
#define C_DIM 256
#define DECAYF 0.95f
#define COMMITF 0.25f
#define EPSF 1e-5f
#define RESC_EPS 0.006f
#define RESC_CAP 8192

// d_out layout (floats), reference return order
#define OFF_QUANT 0
#define OFF_ELOSS 8388608
#define OFF_PERP  8388609
#define OFF_UNIQ  8388610
#define OFF_NCB   8388611
#define OFF_NCNT  10485763
#define OFF_NW    10493955
#define OFF_IDX   12591107

typedef __hip_bfloat16 bf16;
typedef float f32x4 __attribute__((ext_vector_type(4)));
typedef short bf16x8 __attribute__((ext_vector_type(8)));
typedef unsigned long long u64;

#define SWZ(r) ((((r) >> 2) & 7) << 2)

#if defined(__has_builtin)
#if __has_builtin(__builtin_amdgcn_global_load_lds)
#define HAVE_GLDS 1
#endif
#endif
#ifdef HAVE_GLDS
#define GLDS16(g, l) __builtin_amdgcn_global_load_lds( \
    (const __attribute__((address_space(1))) void*)(uintptr_t)(g), \
    (__attribute__((address_space(3))) void*)(uint32_t)(uintptr_t)(l), 16, 0, 0)
#else
#define GLDS16(g, l) do { *(float4*)(l) = *(const float4*)(g); } while (0)
#endif

__device__ __forceinline__ uint32_t fkey(float f) {
    uint32_t b = __float_as_uint(f);
    return b ^ ((uint32_t)((int32_t)b >> 31) | 0x80000000u);
}
__device__ __forceinline__ float funkey(uint32_t k) {
    uint32_t b = (k & 0x80000000u) ? (k ^ 0x80000000u) : ~k;
    return __uint_as_float(b);
}
__device__ __forceinline__ void split2(float v, unsigned short& h, unsigned short& m) {
    bf16 hb = __float2bfloat16(v);
    float fh = __bfloat162float(hb);
    bf16 mb = __float2bfloat16(v - fh);
    h = *(unsigned short*)&hb; m = *(unsigned short*)&mb;
}
__device__ __forceinline__ float bf2f(unsigned short u) {
    return __bfloat162float(*(bf16*)&u);
}

// ---------------- fused prep: split cb (+norms), transpose+split x, zero accums ----------------
__global__ __launch_bounds__(256)
void kprep(const float* __restrict__ cb, unsigned short* __restrict__ Bsp,
           float* __restrict__ cnorm, const float* __restrict__ x,
           unsigned short* __restrict__ Asp, float* __restrict__ counts,
           float* __restrict__ loss_arr, unsigned* __restrict__ rcnt) {
    const int bid = blockIdx.x;
    const int t = threadIdx.x;
    if (bid < 2048) {
        // codebook split + row norms
        const size_t plane = (size_t)K_CODES * C_DIM;
        const size_t i4 = ((size_t)bid * 256 + t) * 4;
        const float4 v = *(const float4*)(cb + i4);
        ushort4 h, m;
        split2(v.x, h.x, m.x); split2(v.y, h.y, m.y);
        split2(v.z, h.z, m.z); split2(v.w, h.w, m.w);
        *(ushort4*)(Bsp + i4) = h;
        *(ushort4*)(Bsp + plane + i4) = m;
        float s = v.x * v.x + v.y * v.y + v.z * v.z + v.w * v.w;
        #pragma unroll
        for (int off = 32; off; off >>= 1) s += __shfl_down(s, off);
        if ((t & 63) == 0) cnorm[i4 >> 8] = s;
    } else if (bid < 4096) {
        // x transpose + split
        __shared__ float xt[64][65];
        const int xb_id = bid - 2048;       // 8 b * 4 ct * 64 st = 2048
        const int st = xb_id & 63;
        const int ct = (xb_id >> 6) & 3;
        const int b  = xb_id >> 8;
        const float* xb = x + ((size_t)b * C_DIM + ct * 64) * 4096 + st * 64;
        {
            const int s_l = t & 63, c0 = t >> 6;
            #pragma unroll
            for (int cc = 0; cc < 16; ++cc) {
                int c_l = cc * 4 + c0;
                xt[c_l][s_l] = xb[(size_t)c_l * 4096 + s_l];
            }
        }
        __syncthreads();
        const size_t plane = (size_t)N_ROWS * C_DIM;
        const int c2 = (t & 31) * 2;
        const int s0 = t >> 5;
        #pragma unroll
        for (int ww = 0; ww < 8; ++ww) {
            int s_o = ww * 8 + s0;
            float v0 = xt[c2][s_o], v1 = xt[c2 + 1][s_o];
            unsigned short h0, m0_, h1, m1_;
            split2(v0, h0, m0_); split2(v1, h1, m1_);
            size_t off = ((size_t)(b * 4096 + st * 64 + s_o)) * C_DIM + ct * 64 + c2;
            *(ushort2*)(Asp + off)         = make_ushort2(h0, h1);
            *(ushort2*)(Asp + plane + off) = make_ushort2(m0_, m1_);
        }
    } else {
        // zero accumulators (runs before kcombine's atomics)
        for (int i = t; i < K_CODES; i += 256) counts[i] = 0.f;
        loss_arr[t] = 0.f;
        if (t == 0) *rcnt = 0u;
    }
}

// ---------------- MFMA distance GEMM + per-row top-2 argmin (r6 structure) ----------------
// 256x256 block tile, 512 threads = 8 waves (2M x 4N), per-wave 128x64 out.
// 2-phase double-buffered 128 KiB LDS, issue-early staging, one barrier/K-tile.
__global__ __launch_bounds__(512, 2)
void kargmin_mfma(const unsigned short* __restrict__ Asp, const unsigned short* __restrict__ Bsp,
                  const float* __restrict__ cnorm, u64* __restrict__ wsmin) {
    __shared__ unsigned short As[2][256 * 64];
    __shared__ unsigned short Bs[2][256 * 64];

    const int t = threadIdx.x;
    const int lane = t & 63;
    const int wid = t >> 6;
    const int swz = (blockIdx.x & 7) * 512 + (blockIdx.x >> 3);
    const int mtile = swz & 127;
    const int ntile = swz >> 7;
    const int m0 = mtile * 256;
    const int n0 = ntile * 256;
    const int wr = wid >> 2;
    const int wc = wid & 3;
    const int wm = wr * 128;
    const int wn = wc * 64;
    const int lm = lane & 15;
    const int lh = lane >> 4;
    const int l7 = lane & 7;
    const int NKT = 12;

    f32x4 acc[8][4];
    #pragma unroll
    for (int i = 0; i < 8; ++i)
        #pragma unroll
        for (int j = 0; j < 4; ++j) acc[i][j] = (f32x4){0.f, 0.f, 0.f, 0.f};

    const int PA[3] = {0, 0, 1};
    const int PB[3] = {0, 1, 0};

    const int sgr = t >> 3;
    const int gslot = (t & 7) ^ (sgr & 7);

    auto stage = [&](int kt, int buf) {
        const int seg = kt >> 2;
        const int kk0 = (kt & 3) * 64;
        const unsigned short* Ab = Asp + ((size_t)PA[seg] * N_ROWS + m0) * C_DIM + kk0;
        const unsigned short* Bb = Bsp + ((size_t)PB[seg] * K_CODES + n0) * C_DIM + kk0;
        #pragma unroll
        for (int it = 0; it < 4; ++it) {
            const int chunk = it * 512 + t;
            const int r = it * 64 + sgr;
            GLDS16(Ab + (size_t)r * C_DIM + gslot * 8, &As[buf][chunk * 8]);
            GLDS16(Bb + (size_t)r * C_DIM + gslot * 8, &Bs[buf][chunk * 8]);
        }
    };

    stage(0, 0);
    __syncthreads();

    for (int kt = 0; kt < NKT; ++kt) {
        const int cur = kt & 1;
        if (kt + 1 < NKT) stage(kt + 1, cur ^ 1);
        #pragma unroll
        for (int kh = 0; kh < 2; ++kh) {
            const int sw = ((kh * 4 + lh) ^ l7) * 8;
            bf16x8 a[8], b[4];
            #pragma unroll
            for (int j = 0; j < 4; ++j)
                b[j] = *(const bf16x8*)&Bs[cur][(wn + j * 16 + lm) * 64 + sw];
            #pragma unroll
            for (int i = 0; i < 8; ++i)
                a[i] = *(const bf16x8*)&As[cur][(wm + i * 16 + lm) * 64 + sw];
            #pragma unroll
            for (int i = 0; i < 8; ++i)
                #pragma unroll
                for (int j = 0; j < 4; ++j)
                    acc[i][j] = __builtin_amdgcn_mfma_f32_16x16x32_bf16(a[i], b[j], acc[i][j], 0, 0, 0);
        }
        __syncthreads();
    }

    float cn[4];
    #pragma unroll
    for (int j = 0; j < 4; ++j) cn[j] = cnorm[n0 + wn + j * 16 + lm];

    u64* redbuf = (u64*)&As[0][0];
    #pragma unroll
    for (int i = 0; i < 8; ++i) {
        u64 p1[4], p2[4];
        #pragma unroll
        for (int r = 0; r < 4; ++r) {
            u64 b1 = ~0ull, b2 = ~0ull;
            #pragma unroll
            for (int j = 0; j < 4; ++j) {
                float dist = fmaf(-2.f, acc[i][j][r], cn[j]);
                u64 pk = ((u64)fkey(dist) << 32) | (unsigned)(n0 + wn + j * 16 + lm);
                if (pk < b1) { b2 = b1; b1 = pk; }
                else if (pk < b2) b2 = pk;
            }
            p1[r] = b1; p2[r] = b2;
        }
        #pragma unroll
        for (int off = 1; off < 16; off <<= 1) {
            #pragma unroll
            for (int r = 0; r < 4; ++r) {
                u64 o1 = __shfl_xor(p1[r], off);
                u64 o2 = __shfl_xor(p2[r], off);
                u64 lo = p1[r] < o1 ? p1[r] : o1;
                u64 hi = p1[r] < o1 ? o1 : p1[r];
                u64 mn2 = p2[r] < o2 ? p2[r] : o2;
                p1[r] = lo;
                p2[r] = hi < mn2 ? hi : mn2;
            }
        }
        if (lm == 0) {
            #pragma unroll
            for (int r = 0; r < 4; ++r) {
                const int rl = wm + i * 16 + lh * 4 + r;
                redbuf[rl * 8 + wc * 2 + 0] = p1[r];
                redbuf[rl * 8 + wc * 2 + 1] = p2[r];
            }
        }
    }
    __syncthreads();
    if (t < 256) {
        u64 m1 = ~0ull, m2 = ~0ull;
        #pragma unroll
        for (int w = 0; w < 4; ++w) {
            u64 a1 = redbuf[t * 8 + w * 2 + 0];
            u64 a2 = redbuf[t * 8 + w * 2 + 1];
            u64 lo = m1 < a1 ? m1 : a1;
            u64 hi = m1 < a1 ? a1 : m1;
            u64 mn2 = m2 < a2 ? m2 : a2;
            m1 = lo;
            m2 = hi < mn2 ? hi : mn2;
        }
        size_t o = ((size_t)(m0 + t) * 32 + ntile) * 2;
        wsmin[o] = m1; wsmin[o + 1] = m2;
    }
}

// ---------------- combine per-ntile mins; histogram; flag near-ties ----------------
__global__ void kcombine(const u64* __restrict__ wsmin, float* __restrict__ idxf,
                         unsigned* __restrict__ rcnt, unsigned* __restrict__ rrows,
                         float* __restrict__ counts) {
    const int row = blockIdx.x * 256 + threadIdx.x;
    const u64* p = wsmin + (size_t)row * 64;
    u64 m1 = ~0ull, m2 = ~0ull;
    for (int i = 0; i < 64; i += 2) {
        u64 a = p[i], b = p[i + 1];
        u64 lo = a < m1 ? a : m1;
        u64 hi = a < m1 ? m1 : a;
        u64 c = m2 < b ? m2 : b;
        m1 = lo;
        m2 = hi < c ? hi : c;
    }
    const int k = (int)(unsigned)(m1 & 0xffffffffu);
    idxf[row] = (float)k;
    atomicAdd(&counts[k], 1.0f);
    float d1 = funkey((uint32_t)(m1 >> 32));
    float d2 = funkey((uint32_t)(m2 >> 32));
    if (d2 - d1 < RESC_EPS) {
        unsigned slot = atomicAdd(rcnt, 1u);
        if (slot < RESC_CAP) rrows[slot] = (unsigned)row;
    }
}

// ---------------- exact fp32 re-score for near-tie rows (4-chain ILP) ----------------
__global__ __launch_bounds__(256)
void krescue(const float* __restrict__ x, const float* __restrict__ cb,
             const float* __restrict__ cnorm, const unsigned* __restrict__ rcnt,
             const unsigned* __restrict__ rrows, float* __restrict__ idxf,
             float* __restrict__ counts) {
    __shared__ float xs[256];
    __shared__ u64 red[4];
    unsigned cnt = *rcnt; if (cnt > RESC_CAP) cnt = RESC_CAP;
    for (unsigned li = blockIdx.x; li < cnt; li += gridDim.x) {
        const int row = (int)rrows[li];
        const int b = row >> 12, s = row & 4095;
        xs[threadIdx.x] = x[((size_t)b * C_DIM + threadIdx.x) * 4096 + s];
        __syncthreads();
        u64 best = ~0ull;
        for (int k0 = 0; k0 < K_CODES; k0 += 256) {
            const int k = k0 + threadIdx.x;
            const float* cr = cb + (size_t)k * C_DIM;
            float a0 = 0.f, a1 = 0.f, a2 = 0.f, a3 = 0.f;
            #pragma unroll 8
            for (int c = 0; c < C_DIM; c += 4) {
                const float4 cv = *(const float4*)(cr + c);
                a0 = fmaf(xs[c + 0], cv.x, a0);
                a1 = fmaf(xs[c + 1], cv.y, a1);
                a2 = fmaf(xs[c + 2], cv.z, a2);
                a3 = fmaf(xs[c + 3], cv.w, a3);
            }
            float dot = (a0 + a1) + (a2 + a3);
            float dist = fmaf(-2.f, dot, cnorm[k]);
            u64 pk = ((u64)fkey(dist) << 32) | (unsigned)k;
            if (pk < best) best = pk;
        }
        #pragma unroll
        for (int off = 32; off; off >>= 1) {
            u64 o = __shfl_down(best, off);
            if (o < best) best = o;
        }
        if ((threadIdx.x & 63) == 0) red[threadIdx.x >> 6] = best;
        __syncthreads();
        if (threadIdx.x == 0) {
            u64 r0 = red[0];
            #pragma unroll
            for (int w = 1; w < 4; ++w) if (red[w] < r0) r0 = red[w];
            const int knew = (int)(unsigned)(r0 & 0xffffffffu);
            const int kold = (int)idxf[row];
            if (knew != kold) {
                atomicAdd(&counts[kold], -1.0f);
                atomicAdd(&counts[knew], 1.0f);
                idxf[row] = (float)knew;
            }
        }
        __syncthreads();
    }
}

// ---------------- CSR build: scan / scatter ----------------
__global__ void kscan(const float* __restrict__ counts, unsigned* __restrict__ off,
                      unsigned* __restrict__ cursor) {
    __shared__ unsigned part[256];
    const int t = threadIdx.x;
    unsigned local[32];
    unsigned s = 0;
    #pragma unroll
    for (int i = 0; i < 32; ++i) { local[i] = s; s += (unsigned)counts[t * 32 + i]; }
    part[t] = s;
    __syncthreads();
    if (t == 0) {
        unsigned run = 0;
        for (int i = 0; i < 256; ++i) { unsigned v = part[i]; part[i] = run; run += v; }
    }
    __syncthreads();
    const unsigned base = part[t];
    #pragma unroll
    for (int i = 0; i < 32; ++i) {
        unsigned o = base + local[i];
        off[t * 32 + i] = o;
        cursor[t * 32 + i] = o;
    }
}

__global__ void kscatter(const float* __restrict__ idxf, unsigned* __restrict__ cursor,
                         unsigned* __restrict__ rowlist) {
    const int n = blockIdx.x * 256 + threadIdx.x;
    const int k = (int)idxf[n];
    unsigned pos = atomicAdd(&cursor[k], 1u);
    rowlist[pos] = (unsigned)n;
}

// ---------------- dw = segment_sum(x) via CSR, from bf16 h+m planes ----------------
__global__ void kdw(const unsigned short* __restrict__ Asp, const float* __restrict__ counts,
                    const unsigned* __restrict__ off, const unsigned* __restrict__ rowlist,
                    float* __restrict__ dwout) {
    const int k = blockIdx.x;
    const int lane = threadIdx.x;   // 64
    const int cnt = (int)counts[k];
    const unsigned base = off[k];
    const size_t plane = (size_t)N_ROWS * C_DIM;
    float4 acc = make_float4(0.f, 0.f, 0.f, 0.f);
    for (int i = 0; i < cnt; ++i) {
        const unsigned row = rowlist[base + i];
        const ushort4 h = *(const ushort4*)(Asp + (size_t)row * C_DIM + lane * 4);
        const ushort4 m = *(const ushort4*)(Asp + plane + (size_t)row * C_DIM + lane * 4);
        acc.x += bf2f(h.x) + bf2f(m.x);
        acc.y += bf2f(h.y) + bf2f(m.y);
        acc.z += bf2f(h.z) + bf2f(m.z);
        acc.w += bf2f(h.w) + bf2f(m.w);
    }
    *(float4*)(dwout + (size_t)k * C_DIM + lane * 4) = acc;
}

// ---------------- quantize (gather-transpose) + e_loss ----------------
__global__ __launch_bounds__(256)
void kquant2(const float* __restrict__ x, const float* __restrict__ cb,
             const float* __restrict__ idxf, float* __restrict__ qout,
             float* __restrict__ loss_arr) {
    __shared__ int ki[64];
    __shared__ float cbt[64][257];
    const int t = threadIdx.x;
    const int bid = blockIdx.x;
    const int chunk = bid & 63;
    const int b = bid >> 6;
    const int s0 = chunk * 64;
    if (t < 64) ki[t] = (int)idxf[b * 4096 + s0 + t];
    __syncthreads();
    {
        const int lane = t & 63;
        const int rr = t >> 6;
        #pragma unroll
        for (int p = 0; p < 16; ++p) {
            const int r = p * 4 + rr;
            const float4 v = *(const float4*)(cb + (size_t)ki[r] * C_DIM + lane * 4);
            cbt[r][lane * 4 + 0] = v.x;
            cbt[r][lane * 4 + 1] = v.y;
            cbt[r][lane * 4 + 2] = v.z;
            cbt[r][lane * 4 + 3] = v.w;
        }
    }
    __syncthreads();
    const int sg = t & 15;
    const int c0 = t >> 4;
    float lsum = 0.f;
    #pragma unroll
    for (int cc = 0; cc < 16; ++cc) {
        const int c = cc * 16 + c0;
        const size_t go = ((size_t)b * C_DIM + c) * 4096 + s0 + sg * 4;
        const float4 xv = *(const float4*)(x + go);
        float qx = cbt[sg * 4 + 0][c];
        float qy = cbt[sg * 4 + 1][c];
        float qz = cbt[sg * 4 + 2][c];
        float qw = cbt[sg * 4 + 3][c];
        float4 st;
        st.x = xv.x + (qx - xv.x);
        st.y = xv.y + (qy - xv.y);
        st.z = xv.z + (qz - xv.z);
        st.w = xv.w + (qw - xv.w);
        *(float4*)(qout + go) = st;
        float dx = qx - xv.x, dy = qy - xv.y, dz = qz - xv.z, dw_ = qw - xv.w;
        lsum += dx * dx + dy * dy + dz * dz + dw_ * dw_;
    }
    #pragma unroll
    for (int off = 32; off; off >>= 1) lsum += __shfl_down(lsum, off);
    __shared__ float ps[4];
    if ((t & 63) == 0) ps[t >> 6] = lsum;
    __syncthreads();
    if (t == 0) atomicAdd(&loss_arr[bid & 255], ps[0] + ps[1] + ps[2] + ps[3]);
}

// ---------------- EMA finalize + stats (fused; block K_CODES does stats) ----------------
__global__ void kfinal2(const float* __restrict__ ema_c, const float* __restrict__ ema_w,
                        const float* __restrict__ counts, float* __restrict__ dw,
                        float* __restrict__ ncb, float* __restrict__ ncnt_out,
                        const float* __restrict__ loss_arr, float* __restrict__ out) {
    const int k = blockIdx.x;
    const int t = threadIdx.x;
    if (k < K_CODES) {
        const float ncnt = (DECAYF * ema_c[k] + (1.f - DECAYF) * counts[k] + EPSF)
                           / (8.f + (float)K_CODES * EPSF) * 8.f;
        const size_t o = (size_t)k * C_DIM + t;
        const float nwv = DECAYF * ema_w[o] + (1.f - DECAYF) * dw[o];
        dw[o]  = nwv;
        ncb[o] = nwv / ncnt;
        if (t == 0) ncnt_out[k] = ncnt;
    } else {
        float nz = 0.f, s = 0.f;
        for (int kk = t; kk < K_CODES; kk += 256) {
            float cnt = counts[kk];
            if (cnt != 0.f) nz += 1.f;
            float p = cnt * (1.f / 32768.f);
            s += p * logf(p + 1e-10f);
        }
        float ls = loss_arr[t];
        #pragma unroll
        for (int off = 32; off; off >>= 1) {
            s  += __shfl_down(s, off);
            nz += __shfl_down(nz, off);
            ls += __shfl_down(ls, off);
        }
        __shared__ float ss[4], zz[4], ll[4];
        const int wid = t >> 6, lane = t & 63;
        if (lane == 0) { ss[wid] = s; zz[wid] = nz; ll[wid] = ls; }
        __syncthreads();
        if (t == 0) {
            float st = ss[0] + ss[1] + ss[2] + ss[3];
            float zt = zz[0] + zz[1] + zz[2] + zz[3];
            float lt = ll[0] + ll[1] + ll[2] + ll[3];
            out[OFF_ELOSS] = COMMITF * lt / 8388608.f;
            out[OFF_PERP]  = expf(-st);
            out[OFF_UNIQ]  = zt;
        }
    }
}

// ======= fallback fp32 path (used only if ws too small) =======
__global__ void knorm(const float* __restrict__ cb, float* __restrict__ cnorm) {
    const int wid  = threadIdx.x >> 6;
    const int lane = threadIdx.x & 63;
    const int row  = blockIdx.x * 4 + wid;
    const float4 v = *(const float4*)(cb + (size_t)row * C_DIM + lane * 4);
    float s = v.x * v.x + v.y * v.y + v.z * v.z + v.w * v.w;
    #pragma unroll
    for (int off = 32; off; off >>= 1) s += __shfl_down(s, off);
    if (lane == 0) cnorm[row] = s;
}

__launch_bounds__(256, 1)
__global__ void kargmin_fp32(const float* __restrict__ x, const float* __restrict__ cb,
                             const float* __restrict__ cnorm, float* __restrict__ idxf) {
    __shared__ float xs[64][256];
    __shared__ float es[64][256];
    const int t  = threadIdx.x;
    const int n0 = blockIdx.x * 64;
    const int b  = n0 >> 12;
    const int s0 = n0 & 4095;
    {
        const int r  = t & 63;
        const int c0 = t >> 6;
        const float* xb = x + (size_t)b * C_DIM * 4096 + s0 + r;
        const int sw = SWZ(r);
        #pragma unroll 8
        for (int cc = 0; cc < 64; ++cc) {
            int c = cc * 4 + c0;
            xs[r][c ^ sw] = xb[(size_t)c * 4096];
        }
    }
    const int mg  = t >> 4;
    const int ng  = t & 15;
    const int m0  = mg * 4;
    const int nn0 = ng * 4;
    const int swm = SWZ(m0);
    const int swn = SWZ(nn0);
    float minv[4] = {1e30f, 1e30f, 1e30f, 1e30f};
    int   mini[4] = {0, 0, 0, 0};
    for (int k0 = 0; k0 < K_CODES; k0 += 64) {
        __syncthreads();
        {
            const int lane = t & 63;
            const int cw   = t >> 6;
            #pragma unroll
            for (int p = 0; p < 16; ++p) {
                int code = p * 4 + cw;
                float4 v = *(const float4*)(cb + (size_t)(k0 + code) * C_DIM + lane * 4);
                *(float4*)&es[code][(lane * 4) ^ SWZ(code)] = v;
            }
        }
        float cn[4];
        #pragma unroll
        for (int j = 0; j < 4; ++j) cn[j] = cnorm[k0 + nn0 + j];
        __syncthreads();
        float acc[4][4];
        #pragma unroll
        for (int i = 0; i < 4; ++i)
            #pragma unroll
            for (int j = 0; j < 4; ++j) acc[i][j] = 0.f;
        #pragma unroll 4
        for (int c = 0; c < C_DIM; c += 4) {
            float4 xa[4], eb[4];
            #pragma unroll
            for (int i = 0; i < 4; ++i) xa[i] = *(const float4*)&xs[m0 + i][c ^ swm];
            #pragma unroll
            for (int j = 0; j < 4; ++j) eb[j] = *(const float4*)&es[nn0 + j][c ^ swn];
            #pragma unroll
            for (int i = 0; i < 4; ++i)
                #pragma unroll
                for (int j = 0; j < 4; ++j)
                    acc[i][j] += xa[i].x * eb[j].x + xa[i].y * eb[j].y +
                                 xa[i].z * eb[j].z + xa[i].w * eb[j].w;
        }
        #pragma unroll
        for (int j = 0; j < 4; ++j) {
            const int kg = k0 + nn0 + j;
            #pragma unroll
            for (int i = 0; i < 4; ++i) {
                float dist = fmaf(-2.f, acc[i][j], cn[j]);
                if (dist < minv[i]) { minv[i] = dist; mini[i] = kg; }
            }
        }
    }
    #pragma unroll
    for (int off = 1; off < 16; off <<= 1) {
        #pragma unroll
        for (int i = 0; i < 4; ++i) {
            float ov = __shfl_xor(minv[i], off);
            int   oi = __shfl_xor(mini[i], off);
            if (ov < minv[i] || (ov == minv[i] && oi < mini[i])) { minv[i] = ov; mini[i] = oi; }
        }
    }
    if (ng == 0) {
        #pragma unroll
        for (int i = 0; i < 4; ++i) idxf[n0 + m0 + i] = (float)mini[i];
    }
}

__global__ void kquant_legacy(const float* __restrict__ x, const float* __restrict__ cb,
                              const float* __restrict__ idxf, float* __restrict__ qout,
                              float* __restrict__ dw, float* __restrict__ counts,
                              float* __restrict__ loss_arr) {
    const int t   = threadIdx.x;
    const int bid = blockIdx.x;
    const int sc  = bid & 15;
    const int c   = (bid >> 4) & 255;
    const int b   = bid >> 12;
    const int s   = sc * 256 + t;
    const int n   = b * 4096 + s;
    const int k   = (int)idxf[n];
    const size_t xoff = ((size_t)b * C_DIM + c) * 4096 + s;
    const float xv = x[xoff];
    const float q  = cb[(size_t)k * C_DIM + c];
    qout[xoff] = xv + (q - xv);
    atomicAdd(&dw[(size_t)k * C_DIM + c], xv);
    if (c == 0) atomicAdd(&counts[k], 1.0f);
    float d = q - xv;
    float p = d * d;
    #pragma unroll
    for (int off = 32; off; off >>= 1) p += __shfl_down(p, off);
    __shared__ float ps[4];
    if ((t & 63) == 0) ps[t >> 6] = p;
    __syncthreads();
    if (t == 0) atomicAdd(&loss_arr[bid & 255], ps[0] + ps[1] + ps[2] + ps[3]);
}

__global__ void kstats_legacy(const float* __restrict__ counts, const float* __restrict__ loss_arr,
                              float* __restrict__ out) {
    const int t = threadIdx.x;
    float nz = 0.f, s = 0.f;
    for (int k = t; k < K_CODES; k += 256) {
        float cnt = counts[k];
        if (cnt != 0.f) nz += 1.f;
        float p = cnt * (1.f / 32768.f);
        s += p * logf(p + 1e-10f);
    }
    float ls = loss_arr[t];
    #pragma unroll
    for (int off = 32; off; off >>= 1) {
        s  += __shfl_down(s, off);
        nz += __shfl_down(nz, off);
        ls += __shfl_down(ls, off);
    }
    __shared__ float ss[4], zz[4], ll[4];
    const int wid = t >> 6, lane = t & 63;
    if (lane == 0) { ss[wid] = s; zz[wid] = nz; ll[wid] = ls; }
    __syncthreads();
    if (t == 0) {
        out[OFF_ELOSS] = COMMITF * (ll[0] + ll[1] + ll[2] + ll[3]) / 8388608.f;
        out[OFF_PERP]  = expf(-(ss[0] + ss[1] + ss[2] + ss[3]));
        out[OFF_UNIQ]  = zz[0] + zz[1] + zz[2] + zz[3];
    }
}

__global__ void kfinal_legacy(const float* __restrict__ ema_c, const float* __restrict__ ema_w,
                              float* __restrict__ counts, float* __restrict__ dw,
                              float* __restrict__ ncb) {
    const int k = blockIdx.x;
    const int c = threadIdx.x;
    const float cnt  = counts[k];
    const float ncnt = (DECAYF * ema_c[k] + (1.f - DECAYF) * cnt + EPSF)
                       / (8.f + (float)K_CODES * EPSF) * 8.f;
    const size_t o = (size_t)k * C_DIM + c;
    const float nw = DECAYF * ema_w[o] + (1.f - DECAYF) * dw[o];
    __syncthreads();
    dw[o]  = nw;
    ncb[o] = nw / ncnt;
    if (c == 0) counts[k] = ncnt;
}

extern "C" void kernel_launch(void* const* d_in, const int* in_sizes, int n_in,
                              void* d_out, int out_size, void* d_ws, size_t ws_size,
                              hipStream_t stream) {
    const float* x     = (const float*)d_in[0];
    const float* cb    = (const float*)d_in[1];
    const float* ema_c = (const float*)d_in[2];
    const float* ema_w = (const float*)d_in[3];
    float* out = (float*)d_out;

    float* qout = out + OFF_QUANT;
    float* ncb  = out + OFF_NCB;
    float* ncnt = out + OFF_NCNT;
    float* nw   = out + OFF_NW;
    float* idxf = out + OFF_IDX;

    const size_t planeA = (size_t)2 * N_ROWS * C_DIM;   // bf16 elems (h,m)
    const size_t planeB = (size_t)2 * K_CODES * C_DIM;
    const size_t tail_f = K_CODES + 256 + K_CODES;
    const size_t tail_u = 1 + RESC_CAP + K_CODES + K_CODES + N_ROWS;
    const size_t need = (planeA + planeB) * 2 + (tail_f + tail_u) * 4 + 64;
    const bool use_mfma = ws_size >= need;

    if (use_mfma) {
        unsigned short* Asp = (unsigned short*)d_ws;
        unsigned short* Bsp = Asp + planeA;
        float* cnorm      = (float*)(Bsp + planeB);
        float* loss_arr   = cnorm + K_CODES;
        float* counts_raw = loss_arr + 256;
        unsigned* rcnt    = (unsigned*)(counts_raw + K_CODES);
        unsigned* rrows   = rcnt + 1;
        unsigned* off     = rrows + RESC_CAP;
        unsigned* cursor  = off + K_CODES;
        unsigned* rowlist = cursor + K_CODES;
        u64* wsmin = (u64*)(out + OFF_QUANT);   // 16.8 MB, consumed before kquant2 writes qout

        kprep<<<4097, 256, 0, stream>>>(cb, Bsp, cnorm, x, Asp, counts_raw, loss_arr, rcnt);
        kargmin_mfma<<<4096, 512, 0, stream>>>(Asp, Bsp, cnorm, wsmin);
        kcombine<<<N_ROWS / 256, 256, 0, stream>>>(wsmin, idxf, rcnt, rrows, counts_raw);
        krescue<<<256, 256, 0, stream>>>(x, cb, cnorm, rcnt, rrows, idxf, counts_raw);
        kscan<<<1, 256, 0, stream>>>(counts_raw, off, cursor);
        kscatter<<<N_ROWS / 256, 256, 0, stream>>>(idxf, cursor, rowlist);
        kdw<<<K_CODES, 64, 0, stream>>>(Asp, counts_raw, off, rowlist, nw);
        kquant2<<<512, 256, 0, stream>>>(x, cb, idxf, qout, loss_arr);
        kfinal2<<<K_CODES + 1, C_DIM, 0, stream>>>(ema_c, ema_w, counts_raw, nw, ncb, ncnt,
                                                   loss_arr, out);
    } else {
        float* cnorm = (float*)d_ws;
        float* loss_arr = cnorm + K_CODES;
        hipMemsetAsync(ncnt, 0, K_CODES * sizeof(float), stream);
        hipMemsetAsync(nw, 0, (size_t)K_CODES * C_DIM * sizeof(float), stream);
        hipMemsetAsync(loss_arr, 0, 256 * sizeof(float), stream);
        knorm<<<K_CODES / 4, 256, 0, stream>>>(cb, cnorm);
        kargmin_fp32<<<N_ROWS / 64, 256, 0, stream>>>(x, cb, cnorm, idxf);
        kquant_legacy<<<32768, 256, 0, stream>>>(x, cb, idxf, qout, nw, ncnt, loss_arr);
        kstats_legacy<<<1, 256, 0, stream>>>(ncnt, loss_arr, out);
        kfinal_legacy<<<K_CODES, C_DIM, 0, stream>>>(ema_c, ema_w, ncnt, nw, ncb);
    }
}

// Round 10
// 1034.209 us; speedup vs baseline: 1.0895x; 1.0378x over previous
//
#include <hip/hip_runtime.h>
#include <hip/hip_bf16.h>
#include <stdint.h>

#define N_ROWS 32768
#define K_CODES 8192
#define C_DIM 256
#define DECAYF 0.95f
#define COMMITF 0.25f
#define EPSF 1e-5f
#define RESC_EPS 0.006f
#define RESC_CAP 8192

// d_out layout (floats), reference return order
#define OFF_QUANT 0
#define OFF_ELOSS 8388608
#define OFF_PERP  8388609
#define OFF_UNIQ  8388610
#define OFF_NCB   8388611
#define OFF_NCNT  10485763
#define OFF_NW    10493955
#define OFF_IDX   12591107

typedef __hip_bfloat16 bf16;
typedef float f32x4 __attribute__((ext_vector_type(4)));
typedef short bf16x8 __attribute__((ext_vector_type(8)));
typedef unsigned long long u64;

#define SWZ(r) ((((r) >> 2) & 7) << 2)

#if defined(__has_builtin)
#if __has_builtin(__builtin_amdgcn_global_load_lds)
#define HAVE_GLDS 1
#endif
#endif
#ifdef HAVE_GLDS
#define GLDS16(g, l) __builtin_amdgcn_global_load_lds( \
    (const __attribute__((address_space(1))) void*)(uintptr_t)(g), \
    (__attribute__((address_space(3))) void*)(uint32_t)(uintptr_t)(l), 16, 0, 0)
#else
#define GLDS16(g, l) do { *(float4*)(l) = *(const float4*)(g); } while (0)
#endif

__device__ __forceinline__ uint32_t fkey(float f) {
    uint32_t b = __float_as_uint(f);
    return b ^ ((uint32_t)((int32_t)b >> 31) | 0x80000000u);
}
__device__ __forceinline__ float funkey(uint32_t k) {
    uint32_t b = (k & 0x80000000u) ? (k ^ 0x80000000u) : ~k;
    return __uint_as_float(b);
}
__device__ __forceinline__ void split2(float v, unsigned short& h, unsigned short& m) {
    bf16 hb = __float2bfloat16(v);
    float fh = __bfloat162float(hb);
    bf16 mb = __float2bfloat16(v - fh);
    h = *(unsigned short*)&hb; m = *(unsigned short*)&mb;
}
__device__ __forceinline__ float bf2f(unsigned short u) {
    return __bfloat162float(*(bf16*)&u);
}

// ---------------- fused prep: split cb (+norms), transpose+split x, zero accums ----------------
__global__ __launch_bounds__(256)
void kprep(const float* __restrict__ cb, unsigned short* __restrict__ Bsp,
           float* __restrict__ cnorm, const float* __restrict__ x,
           unsigned short* __restrict__ Asp, float* __restrict__ counts,
           float* __restrict__ loss_arr, unsigned* __restrict__ rcnt) {
    const int bid = blockIdx.x;
    const int t = threadIdx.x;
    if (bid < 2048) {
        // codebook split + row norms
        const size_t plane = (size_t)K_CODES * C_DIM;
        const size_t i4 = ((size_t)bid * 256 + t) * 4;
        const float4 v = *(const float4*)(cb + i4);
        ushort4 h, m;
        split2(v.x, h.x, m.x); split2(v.y, h.y, m.y);
        split2(v.z, h.z, m.z); split2(v.w, h.w, m.w);
        *(ushort4*)(Bsp + i4) = h;
        *(ushort4*)(Bsp + plane + i4) = m;
        float s = v.x * v.x + v.y * v.y + v.z * v.z + v.w * v.w;
        #pragma unroll
        for (int off = 32; off; off >>= 1) s += __shfl_down(s, off);
        if ((t & 63) == 0) cnorm[i4 >> 8] = s;
    } else if (bid < 4096) {
        // x transpose + split
        __shared__ float xt[64][65];
        const int xb_id = bid - 2048;       // 8 b * 4 ct * 64 st = 2048
        const int st = xb_id & 63;
        const int ct = (xb_id >> 6) & 3;
        const int b  = xb_id >> 8;
        const float* xb = x + ((size_t)b * C_DIM + ct * 64) * 4096 + st * 64;
        {
            const int s_l = t & 63, c0 = t >> 6;
            #pragma unroll
            for (int cc = 0; cc < 16; ++cc) {
                int c_l = cc * 4 + c0;
                xt[c_l][s_l] = xb[(size_t)c_l * 4096 + s_l];
            }
        }
        __syncthreads();
        const size_t plane = (size_t)N_ROWS * C_DIM;
        const int c2 = (t & 31) * 2;
        const int s0 = t >> 5;
        #pragma unroll
        for (int ww = 0; ww < 8; ++ww) {
            int s_o = ww * 8 + s0;
            float v0 = xt[c2][s_o], v1 = xt[c2 + 1][s_o];
            unsigned short h0, m0_, h1, m1_;
            split2(v0, h0, m0_); split2(v1, h1, m1_);
            size_t off = ((size_t)(b * 4096 + st * 64 + s_o)) * C_DIM + ct * 64 + c2;
            *(ushort2*)(Asp + off)         = make_ushort2(h0, h1);
            *(ushort2*)(Asp + plane + off) = make_ushort2(m0_, m1_);
        }
    } else {
        // zero accumulators (runs before kcombine's atomics)
        for (int i = t; i < K_CODES; i += 256) counts[i] = 0.f;
        loss_arr[t] = 0.f;
        if (t == 0) *rcnt = 0u;
    }
}

// ---------------- MFMA distance GEMM + per-row top-2 argmin ----------------
// 256x256 block tile, 512 threads = 8 waves (2M x 4N), per-wave 128x64 out.
// 2-phase double-buffered 128 KiB LDS, issue-early staging, one barrier/K-tile.
// 2D supergroup XCD swizzle: XCD x owns ntiles [4x,4x+4) x all mtiles,
// visited as (2-mtile x 4-ntile) supergroups -> B panels (3MB) L2-resident
// per XCD; each A-pair read once per XCD. Cuts L2-miss staging traffic ~7x.
__global__ __launch_bounds__(512, 2)
void kargmin_mfma(const unsigned short* __restrict__ Asp, const unsigned short* __restrict__ Bsp,
                  const float* __restrict__ cnorm, u64* __restrict__ wsmin) {
    __shared__ unsigned short As[2][256 * 64];
    __shared__ unsigned short Bs[2][256 * 64];

    const int t = threadIdx.x;
    const int lane = t & 63;
    const int wid = t >> 6;
    const int xcd = blockIdx.x & 7;
    const int ii = blockIdx.x >> 3;            // 0..511 within XCD
    const int sub = ii & 7;
    const int mtile = (ii >> 3) * 2 + (sub >> 2);   // 0..127
    const int ntile = xcd * 4 + (sub & 3);          // 0..31
    const int m0 = mtile * 256;
    const int n0 = ntile * 256;
    const int wr = wid >> 2;
    const int wc = wid & 3;
    const int wm = wr * 128;
    const int wn = wc * 64;
    const int lm = lane & 15;
    const int lh = lane >> 4;
    const int l7 = lane & 7;
    const int NKT = 12;

    f32x4 acc[8][4];
    #pragma unroll
    for (int i = 0; i < 8; ++i)
        #pragma unroll
        for (int j = 0; j < 4; ++j) acc[i][j] = (f32x4){0.f, 0.f, 0.f, 0.f};

    const int PA[3] = {0, 0, 1};
    const int PB[3] = {0, 1, 0};

    const int sgr = t >> 3;
    const int gslot = (t & 7) ^ (sgr & 7);

    auto stage = [&](int kt, int buf) {
        const int seg = kt >> 2;
        const int kk0 = (kt & 3) * 64;
        const unsigned short* Ab = Asp + ((size_t)PA[seg] * N_ROWS + m0) * C_DIM + kk0;
        const unsigned short* Bb = Bsp + ((size_t)PB[seg] * K_CODES + n0) * C_DIM + kk0;
        #pragma unroll
        for (int it = 0; it < 4; ++it) {
            const int chunk = it * 512 + t;
            const int r = it * 64 + sgr;
            GLDS16(Ab + (size_t)r * C_DIM + gslot * 8, &As[buf][chunk * 8]);
            GLDS16(Bb + (size_t)r * C_DIM + gslot * 8, &Bs[buf][chunk * 8]);
        }
    };

    stage(0, 0);
    __syncthreads();

    for (int kt = 0; kt < NKT; ++kt) {
        const int cur = kt & 1;
        if (kt + 1 < NKT) stage(kt + 1, cur ^ 1);
        #pragma unroll
        for (int kh = 0; kh < 2; ++kh) {
            const int sw = ((kh * 4 + lh) ^ l7) * 8;
            bf16x8 a[8], b[4];
            #pragma unroll
            for (int j = 0; j < 4; ++j)
                b[j] = *(const bf16x8*)&Bs[cur][(wn + j * 16 + lm) * 64 + sw];
            #pragma unroll
            for (int i = 0; i < 8; ++i)
                a[i] = *(const bf16x8*)&As[cur][(wm + i * 16 + lm) * 64 + sw];
            #pragma unroll
            for (int i = 0; i < 8; ++i)
                #pragma unroll
                for (int j = 0; j < 4; ++j)
                    acc[i][j] = __builtin_amdgcn_mfma_f32_16x16x32_bf16(a[i], b[j], acc[i][j], 0, 0, 0);
        }
        __syncthreads();
    }

    float cn[4];
    #pragma unroll
    for (int j = 0; j < 4; ++j) cn[j] = cnorm[n0 + wn + j * 16 + lm];

    u64* redbuf = (u64*)&As[0][0];
    #pragma unroll
    for (int i = 0; i < 8; ++i) {
        u64 p1[4], p2[4];
        #pragma unroll
        for (int r = 0; r < 4; ++r) {
            u64 b1 = ~0ull, b2 = ~0ull;
            #pragma unroll
            for (int j = 0; j < 4; ++j) {
                float dist = fmaf(-2.f, acc[i][j][r], cn[j]);
                u64 pk = ((u64)fkey(dist) << 32) | (unsigned)(n0 + wn + j * 16 + lm);
                if (pk < b1) { b2 = b1; b1 = pk; }
                else if (pk < b2) b2 = pk;
            }
            p1[r] = b1; p2[r] = b2;
        }
        #pragma unroll
        for (int off = 1; off < 16; off <<= 1) {
            #pragma unroll
            for (int r = 0; r < 4; ++r) {
                u64 o1 = __shfl_xor(p1[r], off);
                u64 o2 = __shfl_xor(p2[r], off);
                u64 lo = p1[r] < o1 ? p1[r] : o1;
                u64 hi = p1[r] < o1 ? o1 : p1[r];
                u64 mn2 = p2[r] < o2 ? p2[r] : o2;
                p1[r] = lo;
                p2[r] = hi < mn2 ? hi : mn2;
            }
        }
        if (lm == 0) {
            #pragma unroll
            for (int r = 0; r < 4; ++r) {
                const int rl = wm + i * 16 + lh * 4 + r;
                redbuf[rl * 8 + wc * 2 + 0] = p1[r];
                redbuf[rl * 8 + wc * 2 + 1] = p2[r];
            }
        }
    }
    __syncthreads();
    if (t < 256) {
        u64 m1 = ~0ull, m2 = ~0ull;
        #pragma unroll
        for (int w = 0; w < 4; ++w) {
            u64 a1 = redbuf[t * 8 + w * 2 + 0];
            u64 a2 = redbuf[t * 8 + w * 2 + 1];
            u64 lo = m1 < a1 ? m1 : a1;
            u64 hi = m1 < a1 ? a1 : m1;
            u64 mn2 = m2 < a2 ? m2 : a2;
            m1 = lo;
            m2 = hi < mn2 ? hi : mn2;
        }
        size_t o = ((size_t)(m0 + t) * 32 + ntile) * 2;
        wsmin[o] = m1; wsmin[o + 1] = m2;
    }
}

// ---------------- combine per-ntile mins; histogram; flag near-ties ----------------
__global__ void kcombine(const u64* __restrict__ wsmin, float* __restrict__ idxf,
                         unsigned* __restrict__ rcnt, unsigned* __restrict__ rrows,
                         float* __restrict__ counts) {
    const int row = blockIdx.x * 256 + threadIdx.x;
    const u64* p = wsmin + (size_t)row * 64;
    u64 m1 = ~0ull, m2 = ~0ull;
    for (int i = 0; i < 64; i += 2) {
        u64 a = p[i], b = p[i + 1];
        u64 lo = a < m1 ? a : m1;
        u64 hi = a < m1 ? m1 : a;
        u64 c = m2 < b ? m2 : b;
        m1 = lo;
        m2 = hi < c ? hi : c;
    }
    const int k = (int)(unsigned)(m1 & 0xffffffffu);
    idxf[row] = (float)k;
    atomicAdd(&counts[k], 1.0f);
    float d1 = funkey((uint32_t)(m1 >> 32));
    float d2 = funkey((uint32_t)(m2 >> 32));
    if (d2 - d1 < RESC_EPS) {
        unsigned slot = atomicAdd(rcnt, 1u);
        if (slot < RESC_CAP) rrows[slot] = (unsigned)row;
    }
}

// ---------------- exact fp32 re-score for near-tie rows (4-chain ILP) ----------------
__global__ __launch_bounds__(256)
void krescue(const float* __restrict__ x, const float* __restrict__ cb,
             const float* __restrict__ cnorm, const unsigned* __restrict__ rcnt,
             const unsigned* __restrict__ rrows, float* __restrict__ idxf,
             float* __restrict__ counts) {
    __shared__ float xs[256];
    __shared__ u64 red[4];
    unsigned cnt = *rcnt; if (cnt > RESC_CAP) cnt = RESC_CAP;
    for (unsigned li = blockIdx.x; li < cnt; li += gridDim.x) {
        const int row = (int)rrows[li];
        const int b = row >> 12, s = row & 4095;
        xs[threadIdx.x] = x[((size_t)b * C_DIM + threadIdx.x) * 4096 + s];
        __syncthreads();
        u64 best = ~0ull;
        for (int k0 = 0; k0 < K_CODES; k0 += 256) {
            const int k = k0 + threadIdx.x;
            const float* cr = cb + (size_t)k * C_DIM;
            float a0 = 0.f, a1 = 0.f, a2 = 0.f, a3 = 0.f;
            #pragma unroll 8
            for (int c = 0; c < C_DIM; c += 4) {
                const float4 cv = *(const float4*)(cr + c);
                a0 = fmaf(xs[c + 0], cv.x, a0);
                a1 = fmaf(xs[c + 1], cv.y, a1);
                a2 = fmaf(xs[c + 2], cv.z, a2);
                a3 = fmaf(xs[c + 3], cv.w, a3);
            }
            float dot = (a0 + a1) + (a2 + a3);
            float dist = fmaf(-2.f, dot, cnorm[k]);
            u64 pk = ((u64)fkey(dist) << 32) | (unsigned)k;
            if (pk < best) best = pk;
        }
        #pragma unroll
        for (int off = 32; off; off >>= 1) {
            u64 o = __shfl_down(best, off);
            if (o < best) best = o;
        }
        if ((threadIdx.x & 63) == 0) red[threadIdx.x >> 6] = best;
        __syncthreads();
        if (threadIdx.x == 0) {
            u64 r0 = red[0];
            #pragma unroll
            for (int w = 1; w < 4; ++w) if (red[w] < r0) r0 = red[w];
            const int knew = (int)(unsigned)(r0 & 0xffffffffu);
            const int kold = (int)idxf[row];
            if (knew != kold) {
                atomicAdd(&counts[kold], -1.0f);
                atomicAdd(&counts[knew], 1.0f);
                idxf[row] = (float)knew;
            }
        }
        __syncthreads();
    }
}

// ---------------- CSR build: scan / scatter ----------------
__global__ void kscan(const float* __restrict__ counts, unsigned* __restrict__ off,
                      unsigned* __restrict__ cursor) {
    __shared__ unsigned part[256];
    const int t = threadIdx.x;
    unsigned local[32];
    unsigned s = 0;
    #pragma unroll
    for (int i = 0; i < 32; ++i) { local[i] = s; s += (unsigned)counts[t * 32 + i]; }
    part[t] = s;
    __syncthreads();
    if (t == 0) {
        unsigned run = 0;
        for (int i = 0; i < 256; ++i) { unsigned v = part[i]; part[i] = run; run += v; }
    }
    __syncthreads();
    const unsigned base = part[t];
    #pragma unroll
    for (int i = 0; i < 32; ++i) {
        unsigned o = base + local[i];
        off[t * 32 + i] = o;
        cursor[t * 32 + i] = o;
    }
}

__global__ void kscatter(const float* __restrict__ idxf, unsigned* __restrict__ cursor,
                         unsigned* __restrict__ rowlist) {
    const int n = blockIdx.x * 256 + threadIdx.x;
    const int k = (int)idxf[n];
    unsigned pos = atomicAdd(&cursor[k], 1u);
    rowlist[pos] = (unsigned)n;
}

// ---------------- dw = segment_sum(x) via CSR, from bf16 h+m planes ----------------
__global__ void kdw(const unsigned short* __restrict__ Asp, const float* __restrict__ counts,
                    const unsigned* __restrict__ off, const unsigned* __restrict__ rowlist,
                    float* __restrict__ dwout) {
    const int k = blockIdx.x;
    const int lane = threadIdx.x;   // 64
    const int cnt = (int)counts[k];
    const unsigned base = off[k];
    const size_t plane = (size_t)N_ROWS * C_DIM;
    float4 acc = make_float4(0.f, 0.f, 0.f, 0.f);
    for (int i = 0; i < cnt; ++i) {
        const unsigned row = rowlist[base + i];
        const ushort4 h = *(const ushort4*)(Asp + (size_t)row * C_DIM + lane * 4);
        const ushort4 m = *(const ushort4*)(Asp + plane + (size_t)row * C_DIM + lane * 4);
        acc.x += bf2f(h.x) + bf2f(m.x);
        acc.y += bf2f(h.y) + bf2f(m.y);
        acc.z += bf2f(h.z) + bf2f(m.z);
        acc.w += bf2f(h.w) + bf2f(m.w);
    }
    *(float4*)(dwout + (size_t)k * C_DIM + lane * 4) = acc;
}

// ---------------- quantize (gather-transpose) + e_loss ----------------
__global__ __launch_bounds__(256)
void kquant2(const float* __restrict__ x, const float* __restrict__ cb,
             const float* __restrict__ idxf, float* __restrict__ qout,
             float* __restrict__ loss_arr) {
    __shared__ int ki[64];
    __shared__ float cbt[64][257];
    const int t = threadIdx.x;
    const int bid = blockIdx.x;
    const int chunk = bid & 63;
    const int b = bid >> 6;
    const int s0 = chunk * 64;
    if (t < 64) ki[t] = (int)idxf[b * 4096 + s0 + t];
    __syncthreads();
    {
        const int lane = t & 63;
        const int rr = t >> 6;
        #pragma unroll
        for (int p = 0; p < 16; ++p) {
            const int r = p * 4 + rr;
            const float4 v = *(const float4*)(cb + (size_t)ki[r] * C_DIM + lane * 4);
            cbt[r][lane * 4 + 0] = v.x;
            cbt[r][lane * 4 + 1] = v.y;
            cbt[r][lane * 4 + 2] = v.z;
            cbt[r][lane * 4 + 3] = v.w;
        }
    }
    __syncthreads();
    const int sg = t & 15;
    const int c0 = t >> 4;
    float lsum = 0.f;
    #pragma unroll
    for (int cc = 0; cc < 16; ++cc) {
        const int c = cc * 16 + c0;
        const size_t go = ((size_t)b * C_DIM + c) * 4096 + s0 + sg * 4;
        const float4 xv = *(const float4*)(x + go);
        float qx = cbt[sg * 4 + 0][c];
        float qy = cbt[sg * 4 + 1][c];
        float qz = cbt[sg * 4 + 2][c];
        float qw = cbt[sg * 4 + 3][c];
        float4 st;
        st.x = xv.x + (qx - xv.x);
        st.y = xv.y + (qy - xv.y);
        st.z = xv.z + (qz - xv.z);
        st.w = xv.w + (qw - xv.w);
        *(float4*)(qout + go) = st;
        float dx = qx - xv.x, dy = qy - xv.y, dz = qz - xv.z, dw_ = qw - xv.w;
        lsum += dx * dx + dy * dy + dz * dz + dw_ * dw_;
    }
    #pragma unroll
    for (int off = 32; off; off >>= 1) lsum += __shfl_down(lsum, off);
    __shared__ float ps[4];
    if ((t & 63) == 0) ps[t >> 6] = lsum;
    __syncthreads();
    if (t == 0) atomicAdd(&loss_arr[bid & 255], ps[0] + ps[1] + ps[2] + ps[3]);
}

// ---------------- EMA finalize + stats (fused; block K_CODES does stats) ----------------
__global__ void kfinal2(const float* __restrict__ ema_c, const float* __restrict__ ema_w,
                        const float* __restrict__ counts, float* __restrict__ dw,
                        float* __restrict__ ncb, float* __restrict__ ncnt_out,
                        const float* __restrict__ loss_arr, float* __restrict__ out) {
    const int k = blockIdx.x;
    const int t = threadIdx.x;
    if (k < K_CODES) {
        const float ncnt = (DECAYF * ema_c[k] + (1.f - DECAYF) * counts[k] + EPSF)
                           / (8.f + (float)K_CODES * EPSF) * 8.f;
        const size_t o = (size_t)k * C_DIM + t;
        const float nwv = DECAYF * ema_w[o] + (1.f - DECAYF) * dw[o];
        dw[o]  = nwv;
        ncb[o] = nwv / ncnt;
        if (t == 0) ncnt_out[k] = ncnt;
    } else {
        float nz = 0.f, s = 0.f;
        for (int kk = t; kk < K_CODES; kk += 256) {
            float cnt = counts[kk];
            if (cnt != 0.f) nz += 1.f;
            float p = cnt * (1.f / 32768.f);
            s += p * logf(p + 1e-10f);
        }
        float ls = loss_arr[t];
        #pragma unroll
        for (int off = 32; off; off >>= 1) {
            s  += __shfl_down(s, off);
            nz += __shfl_down(nz, off);
            ls += __shfl_down(ls, off);
        }
        __shared__ float ss[4], zz[4], ll[4];
        const int wid = t >> 6, lane = t & 63;
        if (lane == 0) { ss[wid] = s; zz[wid] = nz; ll[wid] = ls; }
        __syncthreads();
        if (t == 0) {
            float st = ss[0] + ss[1] + ss[2] + ss[3];
            float zt = zz[0] + zz[1] + zz[2] + zz[3];
            float lt = ll[0] + ll[1] + ll[2] + ll[3];
            out[OFF_ELOSS] = COMMITF * lt / 8388608.f;
            out[OFF_PERP]  = expf(-st);
            out[OFF_UNIQ]  = zt;
        }
    }
}

// ======= fallback fp32 path (used only if ws too small) =======
__global__ void knorm(const float* __restrict__ cb, float* __restrict__ cnorm) {
    const int wid  = threadIdx.x >> 6;
    const int lane = threadIdx.x & 63;
    const int row  = blockIdx.x * 4 + wid;
    const float4 v = *(const float4*)(cb + (size_t)row * C_DIM + lane * 4);
    float s = v.x * v.x + v.y * v.y + v.z * v.z + v.w * v.w;
    #pragma unroll
    for (int off = 32; off; off >>= 1) s += __shfl_down(s, off);
    if (lane == 0) cnorm[row] = s;
}

__launch_bounds__(256, 1)
__global__ void kargmin_fp32(const float* __restrict__ x, const float* __restrict__ cb,
                             const float* __restrict__ cnorm, float* __restrict__ idxf) {
    __shared__ float xs[64][256];
    __shared__ float es[64][256];
    const int t  = threadIdx.x;
    const int n0 = blockIdx.x * 64;
    const int b  = n0 >> 12;
    const int s0 = n0 & 4095;
    {
        const int r  = t & 63;
        const int c0 = t >> 6;
        const float* xb = x + (size_t)b * C_DIM * 4096 + s0 + r;
        const int sw = SWZ(r);
        #pragma unroll 8
        for (int cc = 0; cc < 64; ++cc) {
            int c = cc * 4 + c0;
            xs[r][c ^ sw] = xb[(size_t)c * 4096];
        }
    }
    const int mg  = t >> 4;
    const int ng  = t & 15;
    const int m0  = mg * 4;
    const int nn0 = ng * 4;
    const int swm = SWZ(m0);
    const int swn = SWZ(nn0);
    float minv[4] = {1e30f, 1e30f, 1e30f, 1e30f};
    int   mini[4] = {0, 0, 0, 0};
    for (int k0 = 0; k0 < K_CODES; k0 += 64) {
        __syncthreads();
        {
            const int lane = t & 63;
            const int cw   = t >> 6;
            #pragma unroll
            for (int p = 0; p < 16; ++p) {
                int code = p * 4 + cw;
                float4 v = *(const float4*)(cb + (size_t)(k0 + code) * C_DIM + lane * 4);
                *(float4*)&es[code][(lane * 4) ^ SWZ(code)] = v;
            }
        }
        float cn[4];
        #pragma unroll
        for (int j = 0; j < 4; ++j) cn[j] = cnorm[k0 + nn0 + j];
        __syncthreads();
        float acc[4][4];
        #pragma unroll
        for (int i = 0; i < 4; ++i)
            #pragma unroll
            for (int j = 0; j < 4; ++j) acc[i][j] = 0.f;
        #pragma unroll 4
        for (int c = 0; c < C_DIM; c += 4) {
            float4 xa[4], eb[4];
            #pragma unroll
            for (int i = 0; i < 4; ++i) xa[i] = *(const float4*)&xs[m0 + i][c ^ swm];
            #pragma unroll
            for (int j = 0; j < 4; ++j) eb[j] = *(const float4*)&es[nn0 + j][c ^ swn];
            #pragma unroll
            for (int i = 0; i < 4; ++i)
                #pragma unroll
                for (int j = 0; j < 4; ++j)
                    acc[i][j] += xa[i].x * eb[j].x + xa[i].y * eb[j].y +
                                 xa[i].z * eb[j].z + xa[i].w * eb[j].w;
        }
        #pragma unroll
        for (int j = 0; j < 4; ++j) {
            const int kg = k0 + nn0 + j;
            #pragma unroll
            for (int i = 0; i < 4; ++i) {
                float dist = fmaf(-2.f, acc[i][j], cn[j]);
                if (dist < minv[i]) { minv[i] = dist; mini[i] = kg; }
            }
        }
    }
    #pragma unroll
    for (int off = 1; off < 16; off <<= 1) {
        #pragma unroll
        for (int i = 0; i < 4; ++i) {
            float ov = __shfl_xor(minv[i], off);
            int   oi = __shfl_xor(mini[i], off);
            if (ov < minv[i] || (ov == minv[i] && oi < mini[i])) { minv[i] = ov; mini[i] = oi; }
        }
    }
    if (ng == 0) {
        #pragma unroll
        for (int i = 0; i < 4; ++i) idxf[n0 + m0 + i] = (float)mini[i];
    }
}

__global__ void kquant_legacy(const float* __restrict__ x, const float* __restrict__ cb,
                              const float* __restrict__ idxf, float* __restrict__ qout,
                              float* __restrict__ dw, float* __restrict__ counts,
                              float* __restrict__ loss_arr) {
    const int t   = threadIdx.x;
    const int bid = blockIdx.x;
    const int sc  = bid & 15;
    const int c   = (bid >> 4) & 255;
    const int b   = bid >> 12;
    const int s   = sc * 256 + t;
    const int n   = b * 4096 + s;
    const int k   = (int)idxf[n];
    const size_t xoff = ((size_t)b * C_DIM + c) * 4096 + s;
    const float xv = x[xoff];
    const float q  = cb[(size_t)k * C_DIM + c];
    qout[xoff] = xv + (q - xv);
    atomicAdd(&dw[(size_t)k * C_DIM + c], xv);
    if (c == 0) atomicAdd(&counts[k], 1.0f);
    float d = q - xv;
    float p = d * d;
    #pragma unroll
    for (int off = 32; off; off >>= 1) p += __shfl_down(p, off);
    __shared__ float ps[4];
    if ((t & 63) == 0) ps[t >> 6] = p;
    __syncthreads();
    if (t == 0) atomicAdd(&loss_arr[bid & 255], ps[0] + ps[1] + ps[2] + ps[3]);
}

__global__ void kstats_legacy(const float* __restrict__ counts, const float* __restrict__ loss_arr,
                              float* __restrict__ out) {
    const int t = threadIdx.x;
    float nz = 0.f, s = 0.f;
    for (int k = t; k < K_CODES; k += 256) {
        float cnt = counts[k];
        if (cnt != 0.f) nz += 1.f;
        float p = cnt * (1.f / 32768.f);
        s += p * logf(p + 1e-10f);
    }
    float ls = loss_arr[t];
    #pragma unroll
    for (int off = 32; off; off >>= 1) {
        s  += __shfl_down(s, off);
        nz += __shfl_down(nz, off);
        ls += __shfl_down(ls, off);
    }
    __shared__ float ss[4], zz[4], ll[4];
    const int wid = t >> 6, lane = t & 63;
    if (lane == 0) { ss[wid] = s; zz[wid] = nz; ll[wid] = ls; }
    __syncthreads();
    if (t == 0) {
        out[OFF_ELOSS] = COMMITF * (ll[0] + ll[1] + ll[2] + ll[3]) / 8388608.f;
        out[OFF_PERP]  = expf(-(ss[0] + ss[1] + ss[2] + ss[3]));
        out[OFF_UNIQ]  = zz[0] + zz[1] + zz[2] + zz[3];
    }
}

__global__ void kfinal_legacy(const float* __restrict__ ema_c, const float* __restrict__ ema_w,
                              float* __restrict__ counts, float* __restrict__ dw,
                              float* __restrict__ ncb) {
    const int k = blockIdx.x;
    const int c = threadIdx.x;
    const float cnt  = counts[k];
    const float ncnt = (DECAYF * ema_c[k] + (1.f - DECAYF) * cnt + EPSF)
                       / (8.f + (float)K_CODES * EPSF) * 8.f;
    const size_t o = (size_t)k * C_DIM + c;
    const float nw = DECAYF * ema_w[o] + (1.f - DECAYF) * dw[o];
    __syncthreads();
    dw[o]  = nw;
    ncb[o] = nw / ncnt;
    if (c == 0) counts[k] = ncnt;
}

extern "C" void kernel_launch(void* const* d_in, const int* in_sizes, int n_in,
                              void* d_out, int out_size, void* d_ws, size_t ws_size,
                              hipStream_t stream) {
    const float* x     = (const float*)d_in[0];
    const float* cb    = (const float*)d_in[1];
    const float* ema_c = (const float*)d_in[2];
    const float* ema_w = (const float*)d_in[3];
    float* out = (float*)d_out;

    float* qout = out + OFF_QUANT;
    float* ncb  = out + OFF_NCB;
    float* ncnt = out + OFF_NCNT;
    float* nw   = out + OFF_NW;
    float* idxf = out + OFF_IDX;

    const size_t planeA = (size_t)2 * N_ROWS * C_DIM;   // bf16 elems (h,m)
    const size_t planeB = (size_t)2 * K_CODES * C_DIM;
    const size_t tail_f = K_CODES + 256 + K_CODES;
    const size_t tail_u = 1 + RESC_CAP + K_CODES + K_CODES + N_ROWS;
    const size_t need = (planeA + planeB) * 2 + (tail_f + tail_u) * 4 + 64;
    const bool use_mfma = ws_size >= need;

    if (use_mfma) {
        unsigned short* Asp = (unsigned short*)d_ws;
        unsigned short* Bsp = Asp + planeA;
        float* cnorm      = (float*)(Bsp + planeB);
        float* loss_arr   = cnorm + K_CODES;
        float* counts_raw = loss_arr + 256;
        unsigned* rcnt    = (unsigned*)(counts_raw + K_CODES);
        unsigned* rrows   = rcnt + 1;
        unsigned* off     = rrows + RESC_CAP;
        unsigned* cursor  = off + K_CODES;
        unsigned* rowlist = cursor + K_CODES;
        u64* wsmin = (u64*)(out + OFF_QUANT);   // 16.8 MB, consumed before kquant2 writes qout

        kprep<<<4097, 256, 0, stream>>>(cb, Bsp, cnorm, x, Asp, counts_raw, loss_arr, rcnt);
        kargmin_mfma<<<4096, 512, 0, stream>>>(Asp, Bsp, cnorm, wsmin);
        kcombine<<<N_ROWS / 256, 256, 0, stream>>>(wsmin, idxf, rcnt, rrows, counts_raw);
        krescue<<<256, 256, 0, stream>>>(x, cb, cnorm, rcnt, rrows, idxf, counts_raw);
        kscan<<<1, 256, 0, stream>>>(counts_raw, off, cursor);
        kscatter<<<N_ROWS / 256, 256, 0, stream>>>(idxf, cursor, rowlist);
        kdw<<<K_CODES, 64, 0, stream>>>(Asp, counts_raw, off, rowlist, nw);
        kquant2<<<512, 256, 0, stream>>>(x, cb, idxf, qout, loss_arr);
        kfinal2<<<K_CODES + 1, C_DIM, 0, stream>>>(ema_c, ema_w, counts_raw, nw, ncb, ncnt,
                                                   loss_arr, out);
    } else {
        float* cnorm = (float*)d_ws;
        float* loss_arr = cnorm + K_CODES;
        hipMemsetAsync(ncnt, 0, K_CODES * sizeof(float), stream);
        hipMemsetAsync(nw, 0, (size_t)K_CODES * C_DIM * sizeof(float), stream);
        hipMemsetAsync(loss_arr, 0, 256 * sizeof(float), stream);
        knorm<<<K_CODES / 4, 256, 0, stream>>>(cb, cnorm);
        kargmin_fp32<<<N_ROWS / 64, 256, 0, stream>>>(x, cb, cnorm, idxf);
        kquant_legacy<<<32768, 256, 0, stream>>>(x, cb, idxf, qout, nw, ncnt, loss_arr);
        kstats_legacy<<<1, 256, 0, stream>>>(ncnt, loss_arr, out);
        kfinal_legacy<<<K_CODES, C_DIM, 0, stream>>>(ema_c, ema_w, ncnt, nw, ncb);
    }
}

// Round 11
// 854.075 us; speedup vs baseline: 1.3193x; 1.2109x over previous
//
#include <hip/hip_runtime.h>
#include <hip/hip_bf16.h>
#include <stdint.h>

#define N_ROWS 32768
#define K_CODES 8192
#define C_DIM 256
#define DECAYF 0.95f
#define COMMITF 0.25f
#define EPSF 1e-5f
#define RESC_EPS 0.045f
#define RESC_CAP 16384

// d_out layout (floats), reference return order
#define OFF_QUANT 0
#define OFF_ELOSS 8388608
#define OFF_PERP  8388609
#define OFF_UNIQ  8388610
#define OFF_NCB   8388611
#define OFF_NCNT  10485763
#define OFF_NW    10493955
#define OFF_IDX   12591107

typedef float f32x4 __attribute__((ext_vector_type(4)));
typedef int i32x4 __attribute__((ext_vector_type(4)));
typedef unsigned long long u64;

#define SWZ(r) ((((r) >> 2) & 7) << 2)

#if defined(__has_builtin)
#if __has_builtin(__builtin_amdgcn_global_load_lds)
#define HAVE_GLDS 1
#endif
#endif
#ifdef HAVE_GLDS
#define GLDS16(g, l) __builtin_amdgcn_global_load_lds( \
    (const __attribute__((address_space(1))) void*)(uintptr_t)(g), \
    (__attribute__((address_space(3))) void*)(uint32_t)(uintptr_t)(l), 16, 0, 0)
#else
#define GLDS16(g, l) do { *(float4*)(l) = *(const float4*)(g); } while (0)
#endif

__device__ __forceinline__ uint32_t fkey(float f) {
    uint32_t b = __float_as_uint(f);
    return b ^ ((uint32_t)((int32_t)b >> 31) | 0x80000000u);
}
__device__ __forceinline__ float funkey(uint32_t k) {
    uint32_t b = (k & 0x80000000u) ? (k ^ 0x80000000u) : ~k;
    return __uint_as_float(b);
}
// 14-bit fixed-point -> two signed i8 (h*128 + l), l in [-64,63]
__device__ __forceinline__ void enc8(float v, float inv, signed char& h, signed char& l) {
    int q = __float2int_rn(v * inv);
    q = q > 16319 ? 16319 : (q < -16320 ? -16320 : q);
    int hh = (q + 64) >> 7;
    h = (signed char)hh;
    l = (signed char)(q - (hh << 7));
}

// ---------------- per-block absmax of x (blocks 0-2047) and cb (2048-2559) ----------------
__global__ __launch_bounds__(256)
void kmax(const float* __restrict__ x, const float* __restrict__ cb, float* __restrict__ maxbuf) {
    const int bid = blockIdx.x, t = threadIdx.x;
    const float* src = bid < 2048 ? x : cb;
    const size_t base = bid < 2048 ? (size_t)bid * 4096 : (size_t)(bid - 2048) * 4096;
    float m = 0.f;
    #pragma unroll
    for (int i = 0; i < 4; ++i) {
        const float4 v = *(const float4*)(src + base + ((size_t)i * 256 + t) * 4);
        m = fmaxf(m, fmaxf(fmaxf(fabsf(v.x), fabsf(v.y)), fmaxf(fabsf(v.z), fabsf(v.w))));
    }
    #pragma unroll
    for (int off = 32; off; off >>= 1) m = fmaxf(m, __shfl_down(m, off));
    __shared__ float ps[4];
    if ((t & 63) == 0) ps[t >> 6] = m;
    __syncthreads();
    if (t == 0) maxbuf[bid] = fmaxf(fmaxf(ps[0], ps[1]), fmaxf(ps[2], ps[3]));
}

// ---------------- final scales + zero accumulators ----------------
__global__ void kscale(const float* __restrict__ maxbuf, float* __restrict__ scl,
                       float* __restrict__ counts, float* __restrict__ loss_arr,
                       unsigned* __restrict__ rcnt) {
    const int t = threadIdx.x;
    float mx = 0.f, me = 0.f;
    for (int i = t; i < 2048; i += 256) mx = fmaxf(mx, maxbuf[i]);
    for (int i = 2048 + t; i < 2560; i += 256) me = fmaxf(me, maxbuf[i]);
    #pragma unroll
    for (int off = 32; off; off >>= 1) {
        mx = fmaxf(mx, __shfl_down(mx, off));
        me = fmaxf(me, __shfl_down(me, off));
    }
    __shared__ float px[4], pe[4];
    if ((t & 63) == 0) { px[t >> 6] = mx; pe[t >> 6] = me; }
    __syncthreads();
    if (t == 0) {
        const float Sx = fmaxf(fmaxf(px[0], px[1]), fmaxf(px[2], px[3])) * (16384.f / 16320.f) + 1e-20f;
        const float Se = fmaxf(fmaxf(pe[0], pe[1]), fmaxf(pe[2], pe[3])) * (16384.f / 16320.f) + 1e-20f;
        scl[0] = Sx; scl[1] = Se; scl[2] = Sx * Se / 268435456.f;
        *rcnt = 0u;
    }
    for (int i = t; i < K_CODES; i += 256) counts[i] = 0.f;
    loss_arr[t] = 0.f;
}

// ---------------- encode cb (blocks 0-2047, + cnorm) and x (2048-4095, transpose) ----------------
__global__ __launch_bounds__(256)
void kprep(const float* __restrict__ cb, const float* __restrict__ x,
           signed char* __restrict__ Ah, signed char* __restrict__ Al,
           signed char* __restrict__ Bh, signed char* __restrict__ Bl,
           float* __restrict__ cnorm, const float* __restrict__ scl) {
    const int bid = blockIdx.x;
    const int t = threadIdx.x;
    if (bid < 2048) {
        const float inve = 16384.f / scl[1];
        const size_t i4 = ((size_t)bid * 256 + t) * 4;
        const float4 v = *(const float4*)(cb + i4);
        signed char h0, h1, h2, h3, l0, l1, l2, l3;
        enc8(v.x, inve, h0, l0); enc8(v.y, inve, h1, l1);
        enc8(v.z, inve, h2, l2); enc8(v.w, inve, h3, l3);
        *(char4*)(Bh + i4) = make_char4(h0, h1, h2, h3);
        *(char4*)(Bl + i4) = make_char4(l0, l1, l2, l3);
        float s = v.x * v.x + v.y * v.y + v.z * v.z + v.w * v.w;
        #pragma unroll
        for (int off = 32; off; off >>= 1) s += __shfl_down(s, off);
        if ((t & 63) == 0) cnorm[i4 >> 8] = s;
    } else {
        const float invx = 16384.f / scl[0];
        __shared__ float xt[64][65];
        const int xb_id = bid - 2048;       // 8 b * 4 ct * 64 st = 2048
        const int st = xb_id & 63;
        const int ct = (xb_id >> 6) & 3;
        const int b  = xb_id >> 8;
        const float* xb = x + ((size_t)b * C_DIM + ct * 64) * 4096 + st * 64;
        {
            const int s_l = t & 63, c0 = t >> 6;
            #pragma unroll
            for (int cc = 0; cc < 16; ++cc) {
                int c_l = cc * 4 + c0;
                xt[c_l][s_l] = xb[(size_t)c_l * 4096 + s_l];
            }
        }
        __syncthreads();
        const int c2 = (t & 31) * 2;
        const int s0 = t >> 5;
        #pragma unroll
        for (int ww = 0; ww < 8; ++ww) {
            int s_o = ww * 8 + s0;
            signed char h0, l0, h1, l1;
            enc8(xt[c2][s_o], invx, h0, l0);
            enc8(xt[c2 + 1][s_o], invx, h1, l1);
            size_t off = ((size_t)(b * 4096 + st * 64 + s_o)) * C_DIM + ct * 64 + c2;
            *(char2*)(Ah + off) = make_char2(h0, h1);
            *(char2*)(Al + off) = make_char2(l0, l1);
        }
    }
}

// ---------------- i8 MFMA distance GEMM + per-row top-2 argmin ----------------
// 256x256 tile, 8 waves, per-wave 128x64. 6 K-tiles of BK=128 i8:
// segments (h,h)*2^14, (h,l)+(l,h)*2^7 (ll dropped; pair-rescue covers).
// 2-phase dbuf 128KB LDS, issue-early staging, 2D supergroup XCD swizzle.
__global__ __launch_bounds__(512, 2)
void kargmin_i8(const signed char* __restrict__ Ah, const signed char* __restrict__ Al,
                const signed char* __restrict__ Bh, const signed char* __restrict__ Bl,
                const float* __restrict__ cnorm, const float* __restrict__ scl,
                u64* __restrict__ wsmin) {
    __shared__ unsigned char As[2][256 * 128];
    __shared__ unsigned char Bs[2][256 * 128];

    const int t = threadIdx.x;
    const int lane = t & 63;
    const int wid = t >> 6;
    const int xcd = blockIdx.x & 7;
    const int ii = blockIdx.x >> 3;
    const int sub = ii & 7;
    const int mtile = (ii >> 3) * 2 + (sub >> 2);
    const int ntile = xcd * 4 + (sub & 3);
    const int m0 = mtile * 256;
    const int n0 = ntile * 256;
    const int wr = wid >> 2;
    const int wc = wid & 3;
    const int wm = wr * 128;
    const int wn = wc * 64;
    const int lm = lane & 15;
    const int lh = lane >> 4;
    const int l7 = lane & 7;
    const int NKT = 6;

    i32x4 accH[8][4], accM[8][4];
    #pragma unroll
    for (int i = 0; i < 8; ++i)
        #pragma unroll
        for (int j = 0; j < 4; ++j) {
            accH[i][j] = (i32x4){0, 0, 0, 0};
            accM[i][j] = (i32x4){0, 0, 0, 0};
        }

    const signed char* const PAp[3] = {Ah, Ah, Al};
    const signed char* const PBp[3] = {Bh, Bl, Bh};

    const int sgr = t >> 3;
    const int gslot = (t & 7) ^ (sgr & 7);

    auto stage = [&](int kt, int buf) {
        const int seg = kt >> 1;
        const int kk0 = (kt & 1) * 128;
        const signed char* Ab = PAp[seg] + (size_t)m0 * 256 + kk0;
        const signed char* Bb = PBp[seg] + (size_t)n0 * 256 + kk0;
        #pragma unroll
        for (int it = 0; it < 4; ++it) {
            const int chunk = it * 512 + t;
            const int r = it * 64 + sgr;
            GLDS16(Ab + (size_t)r * 256 + gslot * 16, &As[buf][chunk * 16]);
            GLDS16(Bb + (size_t)r * 256 + gslot * 16, &Bs[buf][chunk * 16]);
        }
    };

    stage(0, 0);
    __syncthreads();

#define QUADK(ACC) \
    _Pragma("unroll") \
    for (int kh = 0; kh < 2; ++kh) { \
        const int swb = ((kh * 4 + lh) ^ l7) * 16; \
        i32x4 a[8], b[4]; \
        _Pragma("unroll") \
        for (int j = 0; j < 4; ++j) \
            b[j] = *(const i32x4*)&Bs[cur][(wn + j * 16 + lm) * 128 + swb]; \
        _Pragma("unroll") \
        for (int i = 0; i < 8; ++i) \
            a[i] = *(const i32x4*)&As[cur][(wm + i * 16 + lm) * 128 + swb]; \
        _Pragma("unroll") \
        for (int i = 0; i < 8; ++i) \
            _Pragma("unroll") \
            for (int j = 0; j < 4; ++j) \
                ACC[i][j] = __builtin_amdgcn_mfma_i32_16x16x64_i8(a[i], b[j], ACC[i][j], 0, 0, 0); \
    }

    for (int kt = 0; kt < NKT; ++kt) {
        const int cur = kt & 1;
        if (kt + 1 < NKT) stage(kt + 1, cur ^ 1);
        if (kt < 2) {
            QUADK(accH)
        } else {
            QUADK(accM)
        }
        __syncthreads();
    }
#undef QUADK

    // epilogue: dist = cnorm - 2*scale*(2^14*accH + 2^7*accM); per-row top-2
    const double dsc = (double)scl[2];
    float cn[4];
    #pragma unroll
    for (int j = 0; j < 4; ++j) cn[j] = cnorm[n0 + wn + j * 16 + lm];

    u64* redbuf = (u64*)&As[0][0];
    #pragma unroll
    for (int i = 0; i < 8; ++i) {
        u64 p1[4], p2[4];
        #pragma unroll
        for (int r = 0; r < 4; ++r) {
            u64 b1 = ~0ull, b2 = ~0ull;
            #pragma unroll
            for (int j = 0; j < 4; ++j) {
                const double val = 16384.0 * (double)accH[i][j][r] + 128.0 * (double)accM[i][j][r];
                const float dist = (float)((double)cn[j] - 2.0 * dsc * val);
                u64 pk = ((u64)fkey(dist) << 32) | (unsigned)(n0 + wn + j * 16 + lm);
                if (pk < b1) { b2 = b1; b1 = pk; }
                else if (pk < b2) b2 = pk;
            }
            p1[r] = b1; p2[r] = b2;
        }
        #pragma unroll
        for (int off = 1; off < 16; off <<= 1) {
            #pragma unroll
            for (int r = 0; r < 4; ++r) {
                u64 o1 = __shfl_xor(p1[r], off);
                u64 o2 = __shfl_xor(p2[r], off);
                u64 lo = p1[r] < o1 ? p1[r] : o1;
                u64 hi = p1[r] < o1 ? o1 : p1[r];
                u64 mn2 = p2[r] < o2 ? p2[r] : o2;
                p1[r] = lo;
                p2[r] = hi < mn2 ? hi : mn2;
            }
        }
        if (lm == 0) {
            #pragma unroll
            for (int r = 0; r < 4; ++r) {
                const int rl = wm + i * 16 + lh * 4 + r;
                redbuf[rl * 8 + wc * 2 + 0] = p1[r];
                redbuf[rl * 8 + wc * 2 + 1] = p2[r];
            }
        }
    }
    __syncthreads();
    if (t < 256) {
        u64 m1 = ~0ull, m2 = ~0ull;
        #pragma unroll
        for (int w = 0; w < 4; ++w) {
            u64 a1 = redbuf[t * 8 + w * 2 + 0];
            u64 a2 = redbuf[t * 8 + w * 2 + 1];
            u64 lo = m1 < a1 ? m1 : a1;
            u64 hi = m1 < a1 ? a1 : m1;
            u64 mn2 = m2 < a2 ? m2 : a2;
            m1 = lo;
            m2 = hi < mn2 ? hi : mn2;
        }
        size_t o = ((size_t)(m0 + t) * 32 + ntile) * 2;
        wsmin[o] = m1; wsmin[o + 1] = m2;
    }
}

// ---------------- combine per-ntile mins; histogram; flag near-ties ----------------
__global__ void kcombine(const u64* __restrict__ wsmin, float* __restrict__ idxf,
                         unsigned* __restrict__ rcnt, unsigned* __restrict__ rrows,
                         uint2* __restrict__ rpair, float* __restrict__ counts) {
    const int row = blockIdx.x * 256 + threadIdx.x;
    const u64* p = wsmin + (size_t)row * 64;
    u64 m1 = ~0ull, m2 = ~0ull;
    for (int i = 0; i < 64; i += 2) {
        u64 a = p[i], b = p[i + 1];
        u64 lo = a < m1 ? a : m1;
        u64 hi = a < m1 ? m1 : a;
        u64 c = m2 < b ? m2 : b;
        m1 = lo;
        m2 = hi < c ? hi : c;
    }
    const int k = (int)(unsigned)(m1 & 0xffffffffu);
    idxf[row] = (float)k;
    atomicAdd(&counts[k], 1.0f);
    float d1 = funkey((uint32_t)(m1 >> 32));
    float d2 = funkey((uint32_t)(m2 >> 32));
    if (d2 - d1 < RESC_EPS) {
        unsigned slot = atomicAdd(rcnt, 1u);
        if (slot < RESC_CAP) {
            rrows[slot] = (unsigned)row;
            rpair[slot] = make_uint2((unsigned)k, (unsigned)(m2 & 0xffffffffu));
        }
    }
}

// ---------------- exact fp32 pair re-score (wave per flagged row) ----------------
__global__ __launch_bounds__(256)
void krescue2(const float* __restrict__ x, const float* __restrict__ cb,
              const float* __restrict__ cnorm, const unsigned* __restrict__ rcnt,
              const unsigned* __restrict__ rrows, const uint2* __restrict__ rpair,
              float* __restrict__ idxf, float* __restrict__ counts) {
    const int lane = threadIdx.x & 63;
    const int wv = threadIdx.x >> 6;
    unsigned cnt = *rcnt; if (cnt > RESC_CAP) cnt = RESC_CAP;
    for (unsigned i = blockIdx.x * 4 + wv; i < cnt; i += gridDim.x * 4) {
        const int row = (int)rrows[i];
        const uint2 kk = rpair[i];
        const int b = row >> 12, s = row & 4095;
        float d1 = 0.f, d2 = 0.f;
        #pragma unroll
        for (int q = 0; q < 4; ++q) {
            const int c = lane + q * 64;
            const float xv = x[((size_t)(b * 256 + c)) * 4096 + s];
            d1 = fmaf(xv, cb[(size_t)kk.x * 256 + c], d1);
            d2 = fmaf(xv, cb[(size_t)kk.y * 256 + c], d2);
        }
        #pragma unroll
        for (int off = 32; off; off >>= 1) {
            d1 += __shfl_down(d1, off);
            d2 += __shfl_down(d2, off);
        }
        if (lane == 0) {
            const float dist1 = fmaf(-2.f, d1, cnorm[kk.x]);
            const float dist2 = fmaf(-2.f, d2, cnorm[kk.y]);
            const u64 p1 = ((u64)fkey(dist1) << 32) | kk.x;
            const u64 p2 = ((u64)fkey(dist2) << 32) | kk.y;
            const int knew = (int)(unsigned)((p1 < p2 ? p1 : p2) & 0xffffffffu);
            const int kold = (int)kk.x;
            if (knew != kold) {
                atomicAdd(&counts[kold], -1.0f);
                atomicAdd(&counts[knew], 1.0f);
                idxf[row] = (float)knew;
            }
        }
    }
}

// ---------------- CSR build: scan / scatter ----------------
__global__ void kscan(const float* __restrict__ counts, unsigned* __restrict__ off,
                      unsigned* __restrict__ cursor) {
    __shared__ unsigned part[256];
    const int t = threadIdx.x;
    unsigned local[32];
    unsigned s = 0;
    #pragma unroll
    for (int i = 0; i < 32; ++i) { local[i] = s; s += (unsigned)counts[t * 32 + i]; }
    part[t] = s;
    __syncthreads();
    if (t == 0) {
        unsigned run = 0;
        for (int i = 0; i < 256; ++i) { unsigned v = part[i]; part[i] = run; run += v; }
    }
    __syncthreads();
    const unsigned base = part[t];
    #pragma unroll
    for (int i = 0; i < 32; ++i) {
        unsigned o = base + local[i];
        off[t * 32 + i] = o;
        cursor[t * 32 + i] = o;
    }
}

__global__ void kscatter(const float* __restrict__ idxf, unsigned* __restrict__ cursor,
                         unsigned* __restrict__ rowlist) {
    const int n = blockIdx.x * 256 + threadIdx.x;
    const int k = (int)idxf[n];
    unsigned pos = atomicAdd(&cursor[k], 1u);
    rowlist[pos] = (unsigned)n;
}

// ---------------- dw = segment_sum(x) via CSR, exact-int from i8 planes ----------------
__global__ void kdw(const signed char* __restrict__ Ah, const signed char* __restrict__ Al,
                    const float* __restrict__ counts, const unsigned* __restrict__ off,
                    const unsigned* __restrict__ rowlist, const float* __restrict__ scl,
                    float* __restrict__ dwout) {
    const int k = blockIdx.x;
    const int lane = threadIdx.x;   // 64
    const int cnt = (int)counts[k];
    const unsigned base = off[k];
    int ax = 0, ay = 0, az = 0, aw = 0;
    for (int i = 0; i < cnt; ++i) {
        const unsigned row = rowlist[base + i];
        const char4 h = *(const char4*)(Ah + (size_t)row * C_DIM + lane * 4);
        const char4 l = *(const char4*)(Al + (size_t)row * C_DIM + lane * 4);
        ax += h.x * 128 + l.x;
        ay += h.y * 128 + l.y;
        az += h.z * 128 + l.z;
        aw += h.w * 128 + l.w;
    }
    const float sxf = scl[0] * (1.f / 16384.f);
    float4 o;
    o.x = (float)ax * sxf; o.y = (float)ay * sxf;
    o.z = (float)az * sxf; o.w = (float)aw * sxf;
    *(float4*)(dwout + (size_t)k * C_DIM + lane * 4) = o;
}

// ---------------- quantize (gather-transpose) + e_loss ----------------
__global__ __launch_bounds__(256)
void kquant2(const float* __restrict__ x, const float* __restrict__ cb,
             const float* __restrict__ idxf, float* __restrict__ qout,
             float* __restrict__ loss_arr) {
    __shared__ int ki[64];
    __shared__ float cbt[64][257];
    const int t = threadIdx.x;
    const int bid = blockIdx.x;
    const int chunk = bid & 63;
    const int b = bid >> 6;
    const int s0 = chunk * 64;
    if (t < 64) ki[t] = (int)idxf[b * 4096 + s0 + t];
    __syncthreads();
    {
        const int lane = t & 63;
        const int rr = t >> 6;
        #pragma unroll
        for (int p = 0; p < 16; ++p) {
            const int r = p * 4 + rr;
            const float4 v = *(const float4*)(cb + (size_t)ki[r] * C_DIM + lane * 4);
            cbt[r][lane * 4 + 0] = v.x;
            cbt[r][lane * 4 + 1] = v.y;
            cbt[r][lane * 4 + 2] = v.z;
            cbt[r][lane * 4 + 3] = v.w;
        }
    }
    __syncthreads();
    const int sg = t & 15;
    const int c0 = t >> 4;
    float lsum = 0.f;
    #pragma unroll
    for (int cc = 0; cc < 16; ++cc) {
        const int c = cc * 16 + c0;
        const size_t go = ((size_t)b * C_DIM + c) * 4096 + s0 + sg * 4;
        const float4 xv = *(const float4*)(x + go);
        float qx = cbt[sg * 4 + 0][c];
        float qy = cbt[sg * 4 + 1][c];
        float qz = cbt[sg * 4 + 2][c];
        float qw = cbt[sg * 4 + 3][c];
        float4 st;
        st.x = xv.x + (qx - xv.x);
        st.y = xv.y + (qy - xv.y);
        st.z = xv.z + (qz - xv.z);
        st.w = xv.w + (qw - xv.w);
        *(float4*)(qout + go) = st;
        float dx = qx - xv.x, dy = qy - xv.y, dz = qz - xv.z, dw_ = qw - xv.w;
        lsum += dx * dx + dy * dy + dz * dz + dw_ * dw_;
    }
    #pragma unroll
    for (int off = 32; off; off >>= 1) lsum += __shfl_down(lsum, off);
    __shared__ float ps[4];
    if ((t & 63) == 0) ps[t >> 6] = lsum;
    __syncthreads();
    if (t == 0) atomicAdd(&loss_arr[bid & 255], ps[0] + ps[1] + ps[2] + ps[3]);
}

// ---------------- EMA finalize + stats (fused; block K_CODES does stats) ----------------
__global__ void kfinal2(const float* __restrict__ ema_c, const float* __restrict__ ema_w,
                        const float* __restrict__ counts, float* __restrict__ dw,
                        float* __restrict__ ncb, float* __restrict__ ncnt_out,
                        const float* __restrict__ loss_arr, float* __restrict__ out) {
    const int k = blockIdx.x;
    const int t = threadIdx.x;
    if (k < K_CODES) {
        const float ncnt = (DECAYF * ema_c[k] + (1.f - DECAYF) * counts[k] + EPSF)
                           / (8.f + (float)K_CODES * EPSF) * 8.f;
        const size_t o = (size_t)k * C_DIM + t;
        const float nwv = DECAYF * ema_w[o] + (1.f - DECAYF) * dw[o];
        dw[o]  = nwv;
        ncb[o] = nwv / ncnt;
        if (t == 0) ncnt_out[k] = ncnt;
    } else {
        float nz = 0.f, s = 0.f;
        for (int kk = t; kk < K_CODES; kk += 256) {
            float cnt = counts[kk];
            if (cnt != 0.f) nz += 1.f;
            float p = cnt * (1.f / 32768.f);
            s += p * logf(p + 1e-10f);
        }
        float ls = loss_arr[t];
        #pragma unroll
        for (int off = 32; off; off >>= 1) {
            s  += __shfl_down(s, off);
            nz += __shfl_down(nz, off);
            ls += __shfl_down(ls, off);
        }
        __shared__ float ss[4], zz[4], ll[4];
        const int wid = t >> 6, lane = t & 63;
        if (lane == 0) { ss[wid] = s; zz[wid] = nz; ll[wid] = ls; }
        __syncthreads();
        if (t == 0) {
            float st = ss[0] + ss[1] + ss[2] + ss[3];
            float zt = zz[0] + zz[1] + zz[2] + zz[3];
            float lt = ll[0] + ll[1] + ll[2] + ll[3];
            out[OFF_ELOSS] = COMMITF * lt / 8388608.f;
            out[OFF_PERP]  = expf(-st);
            out[OFF_UNIQ]  = zt;
        }
    }
}

// ======= fallback fp32 path (used only if ws too small) =======
__global__ void knorm(const float* __restrict__ cb, float* __restrict__ cnorm) {
    const int wid  = threadIdx.x >> 6;
    const int lane = threadIdx.x & 63;
    const int row  = blockIdx.x * 4 + wid;
    const float4 v = *(const float4*)(cb + (size_t)row * C_DIM + lane * 4);
    float s = v.x * v.x + v.y * v.y + v.z * v.z + v.w * v.w;
    #pragma unroll
    for (int off = 32; off; off >>= 1) s += __shfl_down(s, off);
    if (lane == 0) cnorm[row] = s;
}

__launch_bounds__(256, 1)
__global__ void kargmin_fp32(const float* __restrict__ x, const float* __restrict__ cb,
                             const float* __restrict__ cnorm, float* __restrict__ idxf) {
    __shared__ float xs[64][256];
    __shared__ float es[64][256];
    const int t  = threadIdx.x;
    const int n0 = blockIdx.x * 64;
    const int b  = n0 >> 12;
    const int s0 = n0 & 4095;
    {
        const int r  = t & 63;
        const int c0 = t >> 6;
        const float* xb = x + (size_t)b * C_DIM * 4096 + s0 + r;
        const int sw = SWZ(r);
        #pragma unroll 8
        for (int cc = 0; cc < 64; ++cc) {
            int c = cc * 4 + c0;
            xs[r][c ^ sw] = xb[(size_t)c * 4096];
        }
    }
    const int mg  = t >> 4;
    const int ng  = t & 15;
    const int m0  = mg * 4;
    const int nn0 = ng * 4;
    const int swm = SWZ(m0);
    const int swn = SWZ(nn0);
    float minv[4] = {1e30f, 1e30f, 1e30f, 1e30f};
    int   mini[4] = {0, 0, 0, 0};
    for (int k0 = 0; k0 < K_CODES; k0 += 64) {
        __syncthreads();
        {
            const int lane = t & 63;
            const int cw   = t >> 6;
            #pragma unroll
            for (int p = 0; p < 16; ++p) {
                int code = p * 4 + cw;
                float4 v = *(const float4*)(cb + (size_t)(k0 + code) * C_DIM + lane * 4);
                *(float4*)&es[code][(lane * 4) ^ SWZ(code)] = v;
            }
        }
        float cn[4];
        #pragma unroll
        for (int j = 0; j < 4; ++j) cn[j] = cnorm[k0 + nn0 + j];
        __syncthreads();
        float acc[4][4];
        #pragma unroll
        for (int i = 0; i < 4; ++i)
            #pragma unroll
            for (int j = 0; j < 4; ++j) acc[i][j] = 0.f;
        #pragma unroll 4
        for (int c = 0; c < C_DIM; c += 4) {
            float4 xa[4], eb[4];
            #pragma unroll
            for (int i = 0; i < 4; ++i) xa[i] = *(const float4*)&xs[m0 + i][c ^ swm];
            #pragma unroll
            for (int j = 0; j < 4; ++j) eb[j] = *(const float4*)&es[nn0 + j][c ^ swn];
            #pragma unroll
            for (int i = 0; i < 4; ++i)
                #pragma unroll
                for (int j = 0; j < 4; ++j)
                    acc[i][j] += xa[i].x * eb[j].x + xa[i].y * eb[j].y +
                                 xa[i].z * eb[j].z + xa[i].w * eb[j].w;
        }
        #pragma unroll
        for (int j = 0; j < 4; ++j) {
            const int kg = k0 + nn0 + j;
            #pragma unroll
            for (int i = 0; i < 4; ++i) {
                float dist = fmaf(-2.f, acc[i][j], cn[j]);
                if (dist < minv[i]) { minv[i] = dist; mini[i] = kg; }
            }
        }
    }
    #pragma unroll
    for (int off = 1; off < 16; off <<= 1) {
        #pragma unroll
        for (int i = 0; i < 4; ++i) {
            float ov = __shfl_xor(minv[i], off);
            int   oi = __shfl_xor(mini[i], off);
            if (ov < minv[i] || (ov == minv[i] && oi < mini[i])) { minv[i] = ov; mini[i] = oi; }
        }
    }
    if (ng == 0) {
        #pragma unroll
        for (int i = 0; i < 4; ++i) idxf[n0 + m0 + i] = (float)mini[i];
    }
}

__global__ void kquant_legacy(const float* __restrict__ x, const float* __restrict__ cb,
                              const float* __restrict__ idxf, float* __restrict__ qout,
                              float* __restrict__ dw, float* __restrict__ counts,
                              float* __restrict__ loss_arr) {
    const int t   = threadIdx.x;
    const int bid = blockIdx.x;
    const int sc  = bid & 15;
    const int c   = (bid >> 4) & 255;
    const int b   = bid >> 12;
    const int s   = sc * 256 + t;
    const int n   = b * 4096 + s;
    const int k   = (int)idxf[n];
    const size_t xoff = ((size_t)b * C_DIM + c) * 4096 + s;
    const float xv = x[xoff];
    const float q  = cb[(size_t)k * C_DIM + c];
    qout[xoff] = xv + (q - xv);
    atomicAdd(&dw[(size_t)k * C_DIM + c], xv);
    if (c == 0) atomicAdd(&counts[k], 1.0f);
    float d = q - xv;
    float p = d * d;
    #pragma unroll
    for (int off = 32; off; off >>= 1) p += __shfl_down(p, off);
    __shared__ float ps[4];
    if ((t & 63) == 0) ps[t >> 6] = p;
    __syncthreads();
    if (t == 0) atomicAdd(&loss_arr[bid & 255], ps[0] + ps[1] + ps[2] + ps[3]);
}

__global__ void kstats_legacy(const float* __restrict__ counts, const float* __restrict__ loss_arr,
                              float* __restrict__ out) {
    const int t = threadIdx.x;
    float nz = 0.f, s = 0.f;
    for (int k = t; k < K_CODES; k += 256) {
        float cnt = counts[k];
        if (cnt != 0.f) nz += 1.f;
        float p = cnt * (1.f / 32768.f);
        s += p * logf(p + 1e-10f);
    }
    float ls = loss_arr[t];
    #pragma unroll
    for (int off = 32; off; off >>= 1) {
        s  += __shfl_down(s, off);
        nz += __shfl_down(nz, off);
        ls += __shfl_down(ls, off);
    }
    __shared__ float ss[4], zz[4], ll[4];
    const int wid = t >> 6, lane = t & 63;
    if (lane == 0) { ss[wid] = s; zz[wid] = nz; ll[wid] = ls; }
    __syncthreads();
    if (t == 0) {
        out[OFF_ELOSS] = COMMITF * (ll[0] + ll[1] + ll[2] + ll[3]) / 8388608.f;
        out[OFF_PERP]  = expf(-(ss[0] + ss[1] + ss[2] + ss[3]));
        out[OFF_UNIQ]  = zz[0] + zz[1] + zz[2] + zz[3];
    }
}

__global__ void kfinal_legacy(const float* __restrict__ ema_c, const float* __restrict__ ema_w,
                              float* __restrict__ counts, float* __restrict__ dw,
                              float* __restrict__ ncb) {
    const int k = blockIdx.x;
    const int c = threadIdx.x;
    const float cnt  = counts[k];
    const float ncnt = (DECAYF * ema_c[k] + (1.f - DECAYF) * cnt + EPSF)
                       / (8.f + (float)K_CODES * EPSF) * 8.f;
    const size_t o = (size_t)k * C_DIM + c;
    const float nw = DECAYF * ema_w[o] + (1.f - DECAYF) * dw[o];
    __syncthreads();
    dw[o]  = nw;
    ncb[o] = nw / ncnt;
    if (c == 0) counts[k] = ncnt;
}

extern "C" void kernel_launch(void* const* d_in, const int* in_sizes, int n_in,
                              void* d_out, int out_size, void* d_ws, size_t ws_size,
                              hipStream_t stream) {
    const float* x     = (const float*)d_in[0];
    const float* cb    = (const float*)d_in[1];
    const float* ema_c = (const float*)d_in[2];
    const float* ema_w = (const float*)d_in[3];
    float* out = (float*)d_out;

    float* qout = out + OFF_QUANT;
    float* ncb  = out + OFF_NCB;
    float* ncnt = out + OFF_NCNT;
    float* nw   = out + OFF_NW;
    float* idxf = out + OFF_IDX;

    const size_t szA = (size_t)N_ROWS * C_DIM;    // 8388608 bytes per plane
    const size_t szB = (size_t)K_CODES * C_DIM;   // 2097152
    const size_t fcount = 8192 + 256 + 8192 + 4 + 2560;
    const size_t need = 2 * szA + 2 * szB + fcount * 4
                      + RESC_CAP * 8 + RESC_CAP * 4 + 4 + 8192 * 4 * 2 + 32768 * 4 + 64;
    const bool use_i8 = ws_size >= need;

    if (use_i8) {
        signed char* Ah = (signed char*)d_ws;
        signed char* Al = Ah + szA;
        signed char* Bh = Al + szA;
        signed char* Bl = Bh + szB;
        float* fbase      = (float*)(Bl + szB);
        float* cnorm      = fbase;
        float* loss_arr   = fbase + 8192;
        float* counts_raw = fbase + 8448;
        float* scl        = fbase + 16640;
        float* maxbuf     = fbase + 16644;
        uint2* rpair      = (uint2*)(fbase + fcount);
        unsigned* rrows   = (unsigned*)(rpair + RESC_CAP);
        unsigned* rcnt    = rrows + RESC_CAP;
        unsigned* off     = rcnt + 1;
        unsigned* cursor  = off + K_CODES;
        unsigned* rowlist = cursor + K_CODES;
        u64* wsmin = (u64*)(out + OFF_QUANT);   // 16.8 MB, consumed before kquant2 writes qout

        kmax<<<2560, 256, 0, stream>>>(x, cb, maxbuf);
        kscale<<<1, 256, 0, stream>>>(maxbuf, scl, counts_raw, loss_arr, rcnt);
        kprep<<<4096, 256, 0, stream>>>(cb, x, Ah, Al, Bh, Bl, cnorm, scl);
        kargmin_i8<<<4096, 512, 0, stream>>>(Ah, Al, Bh, Bl, cnorm, scl, wsmin);
        kcombine<<<N_ROWS / 256, 256, 0, stream>>>(wsmin, idxf, rcnt, rrows, rpair, counts_raw);
        krescue2<<<256, 256, 0, stream>>>(x, cb, cnorm, rcnt, rrows, rpair, idxf, counts_raw);
        kscan<<<1, 256, 0, stream>>>(counts_raw, off, cursor);
        kscatter<<<N_ROWS / 256, 256, 0, stream>>>(idxf, cursor, rowlist);
        kdw<<<K_CODES, 64, 0, stream>>>(Ah, Al, counts_raw, off, rowlist, scl, nw);
        kquant2<<<512, 256, 0, stream>>>(x, cb, idxf, qout, loss_arr);
        kfinal2<<<K_CODES + 1, C_DIM, 0, stream>>>(ema_c, ema_w, counts_raw, nw, ncb, ncnt,
                                                   loss_arr, out);
    } else {
        float* cnorm = (float*)d_ws;
        float* loss_arr = cnorm + K_CODES;
        hipMemsetAsync(ncnt, 0, K_CODES * sizeof(float), stream);
        hipMemsetAsync(nw, 0, (size_t)K_CODES * C_DIM * sizeof(float), stream);
        hipMemsetAsync(loss_arr, 0, 256 * sizeof(float), stream);
        knorm<<<K_CODES / 4, 256, 0, stream>>>(cb, cnorm);
        kargmin_fp32<<<N_ROWS / 64, 256, 0, stream>>>(x, cb, cnorm, idxf);
        kquant_legacy<<<32768, 256, 0, stream>>>(x, cb, idxf, qout, nw, ncnt, loss_arr);
        kstats_legacy<<<1, 256, 0, stream>>>(ncnt, loss_arr, out);
        kfinal_legacy<<<K_CODES, C_DIM, 0, stream>>>(ema_c, ema_w, ncnt, nw, ncb);
    }
}

// Round 12
// 671.425 us; speedup vs baseline: 1.6783x; 1.2720x over previous
//
#include <hip/hip_runtime.h>
#include <hip/hip_bf16.h>
#include <stdint.h>

#define N_ROWS 32768
#define K_CODES 8192
#define C_DIM 256
#define DECAYF 0.95f
#define COMMITF 0.25f
#define EPSF 1e-5f
#define RESC_EPS 0.045f
#define RESC_CAP 16384

// d_out layout (floats), reference return order
#define OFF_QUANT 0
#define OFF_ELOSS 8388608
#define OFF_PERP  8388609
#define OFF_UNIQ  8388610
#define OFF_NCB   8388611
#define OFF_NCNT  10485763
#define OFF_NW    10493955
#define OFF_IDX   12591107

typedef float f32x4 __attribute__((ext_vector_type(4)));
typedef int i32x4 __attribute__((ext_vector_type(4)));
typedef unsigned long long u64;

#define SWZ(r) ((((r) >> 2) & 7) << 2)

#if defined(__has_builtin)
#if __has_builtin(__builtin_amdgcn_global_load_lds)
#define HAVE_GLDS 1
#endif
#endif
#ifdef HAVE_GLDS
#define GLDS16(g, l) __builtin_amdgcn_global_load_lds( \
    (const __attribute__((address_space(1))) void*)(uintptr_t)(g), \
    (__attribute__((address_space(3))) void*)(uint32_t)(uintptr_t)(l), 16, 0, 0)
#else
#define GLDS16(g, l) do { *(float4*)(l) = *(const float4*)(g); } while (0)
#endif

__device__ __forceinline__ uint32_t fkey(float f) {
    uint32_t b = __float_as_uint(f);
    return b ^ ((uint32_t)((int32_t)b >> 31) | 0x80000000u);
}
__device__ __forceinline__ float funkey(uint32_t k) {
    uint32_t b = (k & 0x80000000u) ? (k ^ 0x80000000u) : ~k;
    return __uint_as_float(b);
}
// 14-bit fixed-point -> two signed i8 (h*128 + l), l in [-64,63]
__device__ __forceinline__ void enc8(float v, float inv, signed char& h, signed char& l) {
    int q = __float2int_rn(v * inv);
    q = q > 16319 ? 16319 : (q < -16320 ? -16320 : q);
    int hh = (q + 64) >> 7;
    h = (signed char)hh;
    l = (signed char)(q - (hh << 7));
}

// ---------------- per-block absmax of x (blocks 0-2047) and cb (2048-2559) ----------------
__global__ __launch_bounds__(256)
void kmax(const float* __restrict__ x, const float* __restrict__ cb, float* __restrict__ maxbuf) {
    const int bid = blockIdx.x, t = threadIdx.x;
    const float* src = bid < 2048 ? x : cb;
    const size_t base = bid < 2048 ? (size_t)bid * 4096 : (size_t)(bid - 2048) * 4096;
    float m = 0.f;
    #pragma unroll
    for (int i = 0; i < 4; ++i) {
        const float4 v = *(const float4*)(src + base + ((size_t)i * 256 + t) * 4);
        m = fmaxf(m, fmaxf(fmaxf(fabsf(v.x), fabsf(v.y)), fmaxf(fabsf(v.z), fabsf(v.w))));
    }
    #pragma unroll
    for (int off = 32; off; off >>= 1) m = fmaxf(m, __shfl_down(m, off));
    __shared__ float ps[4];
    if ((t & 63) == 0) ps[t >> 6] = m;
    __syncthreads();
    if (t == 0) maxbuf[bid] = fmaxf(fmaxf(ps[0], ps[1]), fmaxf(ps[2], ps[3]));
}

// ---------------- final scales + zero accumulators ----------------
__global__ void kscale(const float* __restrict__ maxbuf, float* __restrict__ scl,
                       float* __restrict__ counts, float* __restrict__ loss_arr,
                       unsigned* __restrict__ rcnt) {
    const int t = threadIdx.x;
    float mx = 0.f, me = 0.f;
    for (int i = t; i < 2048; i += 256) mx = fmaxf(mx, maxbuf[i]);
    for (int i = 2048 + t; i < 2560; i += 256) me = fmaxf(me, maxbuf[i]);
    #pragma unroll
    for (int off = 32; off; off >>= 1) {
        mx = fmaxf(mx, __shfl_down(mx, off));
        me = fmaxf(me, __shfl_down(me, off));
    }
    __shared__ float px[4], pe[4];
    if ((t & 63) == 0) { px[t >> 6] = mx; pe[t >> 6] = me; }
    __syncthreads();
    if (t == 0) {
        const float Sx = fmaxf(fmaxf(px[0], px[1]), fmaxf(px[2], px[3])) * (16384.f / 16320.f) + 1e-20f;
        const float Se = fmaxf(fmaxf(pe[0], pe[1]), fmaxf(pe[2], pe[3])) * (16384.f / 16320.f) + 1e-20f;
        scl[0] = Sx; scl[1] = Se; scl[2] = Sx * Se / 268435456.f;
        *rcnt = 0u;
    }
    for (int i = t; i < K_CODES; i += 256) counts[i] = 0.f;
    loss_arr[t] = 0.f;
}

// ---------------- encode cb (blocks 0-2047, + cnorm) and x (2048-4095, transpose) ----------------
__global__ __launch_bounds__(256)
void kprep(const float* __restrict__ cb, const float* __restrict__ x,
           signed char* __restrict__ Ah, signed char* __restrict__ Al,
           signed char* __restrict__ Bh, signed char* __restrict__ Bl,
           float* __restrict__ cnorm, const float* __restrict__ scl) {
    const int bid = blockIdx.x;
    const int t = threadIdx.x;
    if (bid < 2048) {
        const float inve = 16384.f / scl[1];
        const size_t i4 = ((size_t)bid * 256 + t) * 4;
        const float4 v = *(const float4*)(cb + i4);
        signed char h0, h1, h2, h3, l0, l1, l2, l3;
        enc8(v.x, inve, h0, l0); enc8(v.y, inve, h1, l1);
        enc8(v.z, inve, h2, l2); enc8(v.w, inve, h3, l3);
        *(char4*)(Bh + i4) = make_char4(h0, h1, h2, h3);
        *(char4*)(Bl + i4) = make_char4(l0, l1, l2, l3);
        float s = v.x * v.x + v.y * v.y + v.z * v.z + v.w * v.w;
        #pragma unroll
        for (int off = 32; off; off >>= 1) s += __shfl_down(s, off);
        if ((t & 63) == 0) cnorm[i4 >> 8] = s;
    } else {
        const float invx = 16384.f / scl[0];
        __shared__ float xt[64][65];
        const int xb_id = bid - 2048;       // 8 b * 4 ct * 64 st = 2048
        const int st = xb_id & 63;
        const int ct = (xb_id >> 6) & 3;
        const int b  = xb_id >> 8;
        const float* xb = x + ((size_t)b * C_DIM + ct * 64) * 4096 + st * 64;
        {
            const int s_l = t & 63, c0 = t >> 6;
            #pragma unroll
            for (int cc = 0; cc < 16; ++cc) {
                int c_l = cc * 4 + c0;
                xt[c_l][s_l] = xb[(size_t)c_l * 4096 + s_l];
            }
        }
        __syncthreads();
        const int c2 = (t & 31) * 2;
        const int s0 = t >> 5;
        #pragma unroll
        for (int ww = 0; ww < 8; ++ww) {
            int s_o = ww * 8 + s0;
            signed char h0, l0, h1, l1;
            enc8(xt[c2][s_o], invx, h0, l0);
            enc8(xt[c2 + 1][s_o], invx, h1, l1);
            size_t off = ((size_t)(b * 4096 + st * 64 + s_o)) * C_DIM + ct * 64 + c2;
            *(char2*)(Ah + off) = make_char2(h0, h1);
            *(char2*)(Al + off) = make_char2(l0, l1);
        }
    }
}

// ---------------- i8 MFMA distance GEMM + per-row top-2 argmin ----------------
// 256x256 tile, 8 waves, per-wave 128x64. 6 K-tiles of BK=128 i8:
// tiles 0-1 = (h,h); then acc <<= 7; tiles 2-3 = (h,l); tiles 4-5 = (l,h).
// Final acc = 128*H + M; dist = cn - 2*scale*128*acc. SINGLE accumulator
// (128 VGPR) -- the r11 dual-acc version spilled 256 VGPRs to scratch.
__global__ __launch_bounds__(512, 2)
void kargmin_i8(const signed char* __restrict__ Ah, const signed char* __restrict__ Al,
                const signed char* __restrict__ Bh, const signed char* __restrict__ Bl,
                const float* __restrict__ cnorm, const float* __restrict__ scl,
                u64* __restrict__ wsmin) {
    __shared__ unsigned char As[2][256 * 128];
    __shared__ unsigned char Bs[2][256 * 128];

    const int t = threadIdx.x;
    const int lane = t & 63;
    const int wid = t >> 6;
    const int xcd = blockIdx.x & 7;
    const int ii = blockIdx.x >> 3;
    const int sub = ii & 7;
    const int mtile = (ii >> 3) * 2 + (sub >> 2);
    const int ntile = xcd * 4 + (sub & 3);
    const int m0 = mtile * 256;
    const int n0 = ntile * 256;
    const int wr = wid >> 2;
    const int wc = wid & 3;
    const int wm = wr * 128;
    const int wn = wc * 64;
    const int lm = lane & 15;
    const int lh = lane >> 4;
    const int l7 = lane & 7;
    const int NKT = 6;

    i32x4 acc[8][4];
    #pragma unroll
    for (int i = 0; i < 8; ++i)
        #pragma unroll
        for (int j = 0; j < 4; ++j) acc[i][j] = (i32x4){0, 0, 0, 0};

    const signed char* const PAp[3] = {Ah, Ah, Al};
    const signed char* const PBp[3] = {Bh, Bl, Bh};

    const int sgr = t >> 3;
    const int gslot = (t & 7) ^ (sgr & 7);

    auto stage = [&](int kt, int buf) {
        const int seg = kt >> 1;
        const int kk0 = (kt & 1) * 128;
        const signed char* Ab = PAp[seg] + (size_t)m0 * 256 + kk0;
        const signed char* Bb = PBp[seg] + (size_t)n0 * 256 + kk0;
        #pragma unroll
        for (int it = 0; it < 4; ++it) {
            const int chunk = it * 512 + t;
            const int r = it * 64 + sgr;
            GLDS16(Ab + (size_t)r * 256 + gslot * 16, &As[buf][chunk * 16]);
            GLDS16(Bb + (size_t)r * 256 + gslot * 16, &Bs[buf][chunk * 16]);
        }
    };

    stage(0, 0);
    __syncthreads();

    for (int kt = 0; kt < NKT; ++kt) {
        const int cur = kt & 1;
        if (kt + 1 < NKT) stage(kt + 1, cur ^ 1);
        #pragma unroll
        for (int kh = 0; kh < 2; ++kh) {
            const int swb = ((kh * 4 + lh) ^ l7) * 16;
            i32x4 a[8], b[4];
            #pragma unroll
            for (int j = 0; j < 4; ++j)
                b[j] = *(const i32x4*)&Bs[cur][(wn + j * 16 + lm) * 128 + swb];
            #pragma unroll
            for (int i = 0; i < 8; ++i)
                a[i] = *(const i32x4*)&As[cur][(wm + i * 16 + lm) * 128 + swb];
            #pragma unroll
            for (int i = 0; i < 8; ++i)
                #pragma unroll
                for (int j = 0; j < 4; ++j)
                    acc[i][j] = __builtin_amdgcn_mfma_i32_16x16x64_i8(a[i], b[j], acc[i][j], 0, 0, 0);
        }
        if (kt == 1) {
            // H complete: fold 128*H into the same accumulator (no spill)
            #pragma unroll
            for (int i = 0; i < 8; ++i)
                #pragma unroll
                for (int j = 0; j < 4; ++j)
                    acc[i][j] = acc[i][j] << 7;
        }
        __syncthreads();
    }

    // epilogue: dist = cnorm - 2*scale*128*(128*H + M); per-row top-2
    const double dsc = (double)scl[2] * 128.0;
    float cn[4];
    #pragma unroll
    for (int j = 0; j < 4; ++j) cn[j] = cnorm[n0 + wn + j * 16 + lm];

    u64* redbuf = (u64*)&As[0][0];
    #pragma unroll
    for (int i = 0; i < 8; ++i) {
        u64 p1[4], p2[4];
        #pragma unroll
        for (int r = 0; r < 4; ++r) {
            u64 b1 = ~0ull, b2 = ~0ull;
            #pragma unroll
            for (int j = 0; j < 4; ++j) {
                const float dist = (float)((double)cn[j] - 2.0 * dsc * (double)acc[i][j][r]);
                u64 pk = ((u64)fkey(dist) << 32) | (unsigned)(n0 + wn + j * 16 + lm);
                if (pk < b1) { b2 = b1; b1 = pk; }
                else if (pk < b2) b2 = pk;
            }
            p1[r] = b1; p2[r] = b2;
        }
        #pragma unroll
        for (int off = 1; off < 16; off <<= 1) {
            #pragma unroll
            for (int r = 0; r < 4; ++r) {
                u64 o1 = __shfl_xor(p1[r], off);
                u64 o2 = __shfl_xor(p2[r], off);
                u64 lo = p1[r] < o1 ? p1[r] : o1;
                u64 hi = p1[r] < o1 ? o1 : p1[r];
                u64 mn2 = p2[r] < o2 ? p2[r] : o2;
                p1[r] = lo;
                p2[r] = hi < mn2 ? hi : mn2;
            }
        }
        if (lm == 0) {
            #pragma unroll
            for (int r = 0; r < 4; ++r) {
                const int rl = wm + i * 16 + lh * 4 + r;
                redbuf[rl * 8 + wc * 2 + 0] = p1[r];
                redbuf[rl * 8 + wc * 2 + 1] = p2[r];
            }
        }
    }
    __syncthreads();
    if (t < 256) {
        u64 m1 = ~0ull, m2 = ~0ull;
        #pragma unroll
        for (int w = 0; w < 4; ++w) {
            u64 a1 = redbuf[t * 8 + w * 2 + 0];
            u64 a2 = redbuf[t * 8 + w * 2 + 1];
            u64 lo = m1 < a1 ? m1 : a1;
            u64 hi = m1 < a1 ? a1 : m1;
            u64 mn2 = m2 < a2 ? m2 : a2;
            m1 = lo;
            m2 = hi < mn2 ? hi : mn2;
        }
        size_t o = ((size_t)(m0 + t) * 32 + ntile) * 2;
        wsmin[o] = m1; wsmin[o + 1] = m2;
    }
}

// ---------------- combine per-ntile mins; histogram; flag near-ties ----------------
__global__ void kcombine(const u64* __restrict__ wsmin, float* __restrict__ idxf,
                         unsigned* __restrict__ rcnt, unsigned* __restrict__ rrows,
                         uint2* __restrict__ rpair, float* __restrict__ counts) {
    const int row = blockIdx.x * 256 + threadIdx.x;
    const u64* p = wsmin + (size_t)row * 64;
    u64 m1 = ~0ull, m2 = ~0ull;
    for (int i = 0; i < 64; i += 2) {
        u64 a = p[i], b = p[i + 1];
        u64 lo = a < m1 ? a : m1;
        u64 hi = a < m1 ? m1 : a;
        u64 c = m2 < b ? m2 : b;
        m1 = lo;
        m2 = hi < c ? hi : c;
    }
    const int k = (int)(unsigned)(m1 & 0xffffffffu);
    idxf[row] = (float)k;
    atomicAdd(&counts[k], 1.0f);
    float d1 = funkey((uint32_t)(m1 >> 32));
    float d2 = funkey((uint32_t)(m2 >> 32));
    if (d2 - d1 < RESC_EPS) {
        unsigned slot = atomicAdd(rcnt, 1u);
        if (slot < RESC_CAP) {
            rrows[slot] = (unsigned)row;
            rpair[slot] = make_uint2((unsigned)k, (unsigned)(m2 & 0xffffffffu));
        }
    }
}

// ---------------- exact fp32 pair re-score (wave per flagged row) ----------------
__global__ __launch_bounds__(256)
void krescue2(const float* __restrict__ x, const float* __restrict__ cb,
              const float* __restrict__ cnorm, const unsigned* __restrict__ rcnt,
              const unsigned* __restrict__ rrows, const uint2* __restrict__ rpair,
              float* __restrict__ idxf, float* __restrict__ counts) {
    const int lane = threadIdx.x & 63;
    const int wv = threadIdx.x >> 6;
    unsigned cnt = *rcnt; if (cnt > RESC_CAP) cnt = RESC_CAP;
    for (unsigned i = blockIdx.x * 4 + wv; i < cnt; i += gridDim.x * 4) {
        const int row = (int)rrows[i];
        const uint2 kk = rpair[i];
        const int b = row >> 12, s = row & 4095;
        float d1 = 0.f, d2 = 0.f;
        #pragma unroll
        for (int q = 0; q < 4; ++q) {
            const int c = lane + q * 64;
            const float xv = x[((size_t)(b * 256 + c)) * 4096 + s];
            d1 = fmaf(xv, cb[(size_t)kk.x * 256 + c], d1);
            d2 = fmaf(xv, cb[(size_t)kk.y * 256 + c], d2);
        }
        #pragma unroll
        for (int off = 32; off; off >>= 1) {
            d1 += __shfl_down(d1, off);
            d2 += __shfl_down(d2, off);
        }
        if (lane == 0) {
            const float dist1 = fmaf(-2.f, d1, cnorm[kk.x]);
            const float dist2 = fmaf(-2.f, d2, cnorm[kk.y]);
            const u64 p1 = ((u64)fkey(dist1) << 32) | kk.x;
            const u64 p2 = ((u64)fkey(dist2) << 32) | kk.y;
            const int knew = (int)(unsigned)((p1 < p2 ? p1 : p2) & 0xffffffffu);
            const int kold = (int)kk.x;
            if (knew != kold) {
                atomicAdd(&counts[kold], -1.0f);
                atomicAdd(&counts[knew], 1.0f);
                idxf[row] = (float)knew;
            }
        }
    }
}

// ---------------- CSR build: scan / scatter ----------------
__global__ void kscan(const float* __restrict__ counts, unsigned* __restrict__ off,
                      unsigned* __restrict__ cursor) {
    __shared__ unsigned part[256];
    const int t = threadIdx.x;
    unsigned local[32];
    unsigned s = 0;
    #pragma unroll
    for (int i = 0; i < 32; ++i) { local[i] = s; s += (unsigned)counts[t * 32 + i]; }
    part[t] = s;
    __syncthreads();
    if (t == 0) {
        unsigned run = 0;
        for (int i = 0; i < 256; ++i) { unsigned v = part[i]; part[i] = run; run += v; }
    }
    __syncthreads();
    const unsigned base = part[t];
    #pragma unroll
    for (int i = 0; i < 32; ++i) {
        unsigned o = base + local[i];
        off[t * 32 + i] = o;
        cursor[t * 32 + i] = o;
    }
}

__global__ void kscatter(const float* __restrict__ idxf, unsigned* __restrict__ cursor,
                         unsigned* __restrict__ rowlist) {
    const int n = blockIdx.x * 256 + threadIdx.x;
    const int k = (int)idxf[n];
    unsigned pos = atomicAdd(&cursor[k], 1u);
    rowlist[pos] = (unsigned)n;
}

// ---------------- dw = segment_sum(x) via CSR, exact-int from i8 planes ----------------
__global__ void kdw(const signed char* __restrict__ Ah, const signed char* __restrict__ Al,
                    const float* __restrict__ counts, const unsigned* __restrict__ off,
                    const unsigned* __restrict__ rowlist, const float* __restrict__ scl,
                    float* __restrict__ dwout) {
    const int k = blockIdx.x;
    const int lane = threadIdx.x;   // 64
    const int cnt = (int)counts[k];
    const unsigned base = off[k];
    int ax = 0, ay = 0, az = 0, aw = 0;
    for (int i = 0; i < cnt; ++i) {
        const unsigned row = rowlist[base + i];
        const char4 h = *(const char4*)(Ah + (size_t)row * C_DIM + lane * 4);
        const char4 l = *(const char4*)(Al + (size_t)row * C_DIM + lane * 4);
        ax += h.x * 128 + l.x;
        ay += h.y * 128 + l.y;
        az += h.z * 128 + l.z;
        aw += h.w * 128 + l.w;
    }
    const float sxf = scl[0] * (1.f / 16384.f);
    float4 o;
    o.x = (float)ax * sxf; o.y = (float)ay * sxf;
    o.z = (float)az * sxf; o.w = (float)aw * sxf;
    *(float4*)(dwout + (size_t)k * C_DIM + lane * 4) = o;
}

// ---------------- quantize (gather-transpose) + e_loss ----------------
__global__ __launch_bounds__(256)
void kquant2(const float* __restrict__ x, const float* __restrict__ cb,
             const float* __restrict__ idxf, float* __restrict__ qout,
             float* __restrict__ loss_arr) {
    __shared__ int ki[64];
    __shared__ float cbt[64][257];
    const int t = threadIdx.x;
    const int bid = blockIdx.x;
    const int chunk = bid & 63;
    const int b = bid >> 6;
    const int s0 = chunk * 64;
    if (t < 64) ki[t] = (int)idxf[b * 4096 + s0 + t];
    __syncthreads();
    {
        const int lane = t & 63;
        const int rr = t >> 6;
        #pragma unroll
        for (int p = 0; p < 16; ++p) {
            const int r = p * 4 + rr;
            const float4 v = *(const float4*)(cb + (size_t)ki[r] * C_DIM + lane * 4);
            cbt[r][lane * 4 + 0] = v.x;
            cbt[r][lane * 4 + 1] = v.y;
            cbt[r][lane * 4 + 2] = v.z;
            cbt[r][lane * 4 + 3] = v.w;
        }
    }
    __syncthreads();
    const int sg = t & 15;
    const int c0 = t >> 4;
    float lsum = 0.f;
    #pragma unroll
    for (int cc = 0; cc < 16; ++cc) {
        const int c = cc * 16 + c0;
        const size_t go = ((size_t)b * C_DIM + c) * 4096 + s0 + sg * 4;
        const float4 xv = *(const float4*)(x + go);
        float qx = cbt[sg * 4 + 0][c];
        float qy = cbt[sg * 4 + 1][c];
        float qz = cbt[sg * 4 + 2][c];
        float qw = cbt[sg * 4 + 3][c];
        float4 st;
        st.x = xv.x + (qx - xv.x);
        st.y = xv.y + (qy - xv.y);
        st.z = xv.z + (qz - xv.z);
        st.w = xv.w + (qw - xv.w);
        *(float4*)(qout + go) = st;
        float dx = qx - xv.x, dy = qy - xv.y, dz = qz - xv.z, dw_ = qw - xv.w;
        lsum += dx * dx + dy * dy + dz * dz + dw_ * dw_;
    }
    #pragma unroll
    for (int off = 32; off; off >>= 1) lsum += __shfl_down(lsum, off);
    __shared__ float ps[4];
    if ((t & 63) == 0) ps[t >> 6] = lsum;
    __syncthreads();
    if (t == 0) atomicAdd(&loss_arr[bid & 255], ps[0] + ps[1] + ps[2] + ps[3]);
}

// ---------------- EMA finalize + stats (fused; block K_CODES does stats) ----------------
__global__ void kfinal2(const float* __restrict__ ema_c, const float* __restrict__ ema_w,
                        const float* __restrict__ counts, float* __restrict__ dw,
                        float* __restrict__ ncb, float* __restrict__ ncnt_out,
                        const float* __restrict__ loss_arr, float* __restrict__ out) {
    const int k = blockIdx.x;
    const int t = threadIdx.x;
    if (k < K_CODES) {
        const float ncnt = (DECAYF * ema_c[k] + (1.f - DECAYF) * counts[k] + EPSF)
                           / (8.f + (float)K_CODES * EPSF) * 8.f;
        const size_t o = (size_t)k * C_DIM + t;
        const float nwv = DECAYF * ema_w[o] + (1.f - DECAYF) * dw[o];
        dw[o]  = nwv;
        ncb[o] = nwv / ncnt;
        if (t == 0) ncnt_out[k] = ncnt;
    } else {
        float nz = 0.f, s = 0.f;
        for (int kk = t; kk < K_CODES; kk += 256) {
            float cnt = counts[kk];
            if (cnt != 0.f) nz += 1.f;
            float p = cnt * (1.f / 32768.f);
            s += p * logf(p + 1e-10f);
        }
        float ls = loss_arr[t];
        #pragma unroll
        for (int off = 32; off; off >>= 1) {
            s  += __shfl_down(s, off);
            nz += __shfl_down(nz, off);
            ls += __shfl_down(ls, off);
        }
        __shared__ float ss[4], zz[4], ll[4];
        const int wid = t >> 6, lane = t & 63;
        if (lane == 0) { ss[wid] = s; zz[wid] = nz; ll[wid] = ls; }
        __syncthreads();
        if (t == 0) {
            float st = ss[0] + ss[1] + ss[2] + ss[3];
            float zt = zz[0] + zz[1] + zz[2] + zz[3];
            float lt = ll[0] + ll[1] + ll[2] + ll[3];
            out[OFF_ELOSS] = COMMITF * lt / 8388608.f;
            out[OFF_PERP]  = expf(-st);
            out[OFF_UNIQ]  = zt;
        }
    }
}

// ======= fallback fp32 path (used only if ws too small) =======
__global__ void knorm(const float* __restrict__ cb, float* __restrict__ cnorm) {
    const int wid  = threadIdx.x >> 6;
    const int lane = threadIdx.x & 63;
    const int row  = blockIdx.x * 4 + wid;
    const float4 v = *(const float4*)(cb + (size_t)row * C_DIM + lane * 4);
    float s = v.x * v.x + v.y * v.y + v.z * v.z + v.w * v.w;
    #pragma unroll
    for (int off = 32; off; off >>= 1) s += __shfl_down(s, off);
    if (lane == 0) cnorm[row] = s;
}

__launch_bounds__(256, 1)
__global__ void kargmin_fp32(const float* __restrict__ x, const float* __restrict__ cb,
                             const float* __restrict__ cnorm, float* __restrict__ idxf) {
    __shared__ float xs[64][256];
    __shared__ float es[64][256];
    const int t  = threadIdx.x;
    const int n0 = blockIdx.x * 64;
    const int b  = n0 >> 12;
    const int s0 = n0 & 4095;
    {
        const int r  = t & 63;
        const int c0 = t >> 6;
        const float* xb = x + (size_t)b * C_DIM * 4096 + s0 + r;
        const int sw = SWZ(r);
        #pragma unroll 8
        for (int cc = 0; cc < 64; ++cc) {
            int c = cc * 4 + c0;
            xs[r][c ^ sw] = xb[(size_t)c * 4096];
        }
    }
    const int mg  = t >> 4;
    const int ng  = t & 15;
    const int m0  = mg * 4;
    const int nn0 = ng * 4;
    const int swm = SWZ(m0);
    const int swn = SWZ(nn0);
    float minv[4] = {1e30f, 1e30f, 1e30f, 1e30f};
    int   mini[4] = {0, 0, 0, 0};
    for (int k0 = 0; k0 < K_CODES; k0 += 64) {
        __syncthreads();
        {
            const int lane = t & 63;
            const int cw   = t >> 6;
            #pragma unroll
            for (int p = 0; p < 16; ++p) {
                int code = p * 4 + cw;
                float4 v = *(const float4*)(cb + (size_t)(k0 + code) * C_DIM + lane * 4);
                *(float4*)&es[code][(lane * 4) ^ SWZ(code)] = v;
            }
        }
        float cn[4];
        #pragma unroll
        for (int j = 0; j < 4; ++j) cn[j] = cnorm[k0 + nn0 + j];
        __syncthreads();
        float acc[4][4];
        #pragma unroll
        for (int i = 0; i < 4; ++i)
            #pragma unroll
            for (int j = 0; j < 4; ++j) acc[i][j] = 0.f;
        #pragma unroll 4
        for (int c = 0; c < C_DIM; c += 4) {
            float4 xa[4], eb[4];
            #pragma unroll
            for (int i = 0; i < 4; ++i) xa[i] = *(const float4*)&xs[m0 + i][c ^ swm];
            #pragma unroll
            for (int j = 0; j < 4; ++j) eb[j] = *(const float4*)&es[nn0 + j][c ^ swn];
            #pragma unroll
            for (int i = 0; i < 4; ++i)
                #pragma unroll
                for (int j = 0; j < 4; ++j)
                    acc[i][j] += xa[i].x * eb[j].x + xa[i].y * eb[j].y +
                                 xa[i].z * eb[j].z + xa[i].w * eb[j].w;
        }
        #pragma unroll
        for (int j = 0; j < 4; ++j) {
            const int kg = k0 + nn0 + j;
            #pragma unroll
            for (int i = 0; i < 4; ++i) {
                float dist = fmaf(-2.f, acc[i][j], cn[j]);
                if (dist < minv[i]) { minv[i] = dist; mini[i] = kg; }
            }
        }
    }
    #pragma unroll
    for (int off = 1; off < 16; off <<= 1) {
        #pragma unroll
        for (int i = 0; i < 4; ++i) {
            float ov = __shfl_xor(minv[i], off);
            int   oi = __shfl_xor(mini[i], off);
            if (ov < minv[i] || (ov == minv[i] && oi < mini[i])) { minv[i] = ov; mini[i] = oi; }
        }
    }
    if (ng == 0) {
        #pragma unroll
        for (int i = 0; i < 4; ++i) idxf[n0 + m0 + i] = (float)mini[i];
    }
}

__global__ void kquant_legacy(const float* __restrict__ x, const float* __restrict__ cb,
                              const float* __restrict__ idxf, float* __restrict__ qout,
                              float* __restrict__ dw, float* __restrict__ counts,
                              float* __restrict__ loss_arr) {
    const int t   = threadIdx.x;
    const int bid = blockIdx.x;
    const int sc  = bid & 15;
    const int c   = (bid >> 4) & 255;
    const int b   = bid >> 12;
    const int s   = sc * 256 + t;
    const int n   = b * 4096 + s;
    const int k   = (int)idxf[n];
    const size_t xoff = ((size_t)b * C_DIM + c) * 4096 + s;
    const float xv = x[xoff];
    const float q  = cb[(size_t)k * C_DIM + c];
    qout[xoff] = xv + (q - xv);
    atomicAdd(&dw[(size_t)k * C_DIM + c], xv);
    if (c == 0) atomicAdd(&counts[k], 1.0f);
    float d = q - xv;
    float p = d * d;
    #pragma unroll
    for (int off = 32; off; off >>= 1) p += __shfl_down(p, off);
    __shared__ float ps[4];
    if ((t & 63) == 0) ps[t >> 6] = p;
    __syncthreads();
    if (t == 0) atomicAdd(&loss_arr[bid & 255], ps[0] + ps[1] + ps[2] + ps[3]);
}

__global__ void kstats_legacy(const float* __restrict__ counts, const float* __restrict__ loss_arr,
                              float* __restrict__ out) {
    const int t = threadIdx.x;
    float nz = 0.f, s = 0.f;
    for (int k = t; k < K_CODES; k += 256) {
        float cnt = counts[k];
        if (cnt != 0.f) nz += 1.f;
        float p = cnt * (1.f / 32768.f);
        s += p * logf(p + 1e-10f);
    }
    float ls = loss_arr[t];
    #pragma unroll
    for (int off = 32; off; off >>= 1) {
        s  += __shfl_down(s, off);
        nz += __shfl_down(nz, off);
        ls += __shfl_down(ls, off);
    }
    __shared__ float ss[4], zz[4], ll[4];
    const int wid = t >> 6, lane = t & 63;
    if (lane == 0) { ss[wid] = s; zz[wid] = nz; ll[wid] = ls; }
    __syncthreads();
    if (t == 0) {
        out[OFF_ELOSS] = COMMITF * (ll[0] + ll[1] + ll[2] + ll[3]) / 8388608.f;
        out[OFF_PERP]  = expf(-(ss[0] + ss[1] + ss[2] + ss[3]));
        out[OFF_UNIQ]  = zz[0] + zz[1] + zz[2] + zz[3];
    }
}

__global__ void kfinal_legacy(const float* __restrict__ ema_c, const float* __restrict__ ema_w,
                              float* __restrict__ counts, float* __restrict__ dw,
                              float* __restrict__ ncb) {
    const int k = blockIdx.x;
    const int c = threadIdx.x;
    const float cnt  = counts[k];
    const float ncnt = (DECAYF * ema_c[k] + (1.f - DECAYF) * cnt + EPSF)
                       / (8.f + (float)K_CODES * EPSF) * 8.f;
    const size_t o = (size_t)k * C_DIM + c;
    const float nw = DECAYF * ema_w[o] + (1.f - DECAYF) * dw[o];
    __syncthreads();
    dw[o]  = nw;
    ncb[o] = nw / ncnt;
    if (c == 0) counts[k] = ncnt;
}

extern "C" void kernel_launch(void* const* d_in, const int* in_sizes, int n_in,
                              void* d_out, int out_size, void* d_ws, size_t ws_size,
                              hipStream_t stream) {
    const float* x     = (const float*)d_in[0];
    const float* cb    = (const float*)d_in[1];
    const float* ema_c = (const float*)d_in[2];
    const float* ema_w = (const float*)d_in[3];
    float* out = (float*)d_out;

    float* qout = out + OFF_QUANT;
    float* ncb  = out + OFF_NCB;
    float* ncnt = out + OFF_NCNT;
    float* nw   = out + OFF_NW;
    float* idxf = out + OFF_IDX;

    const size_t szA = (size_t)N_ROWS * C_DIM;    // 8388608 bytes per plane
    const size_t szB = (size_t)K_CODES * C_DIM;   // 2097152
    const size_t fcount = 8192 + 256 + 8192 + 4 + 2560;
    const size_t need = 2 * szA + 2 * szB + fcount * 4
                      + RESC_CAP * 8 + RESC_CAP * 4 + 4 + 8192 * 4 * 2 + 32768 * 4 + 64;
    const bool use_i8 = ws_size >= need;

    if (use_i8) {
        signed char* Ah = (signed char*)d_ws;
        signed char* Al = Ah + szA;
        signed char* Bh = Al + szA;
        signed char* Bl = Bh + szB;
        float* fbase      = (float*)(Bl + szB);
        float* cnorm      = fbase;
        float* loss_arr   = fbase + 8192;
        float* counts_raw = fbase + 8448;
        float* scl        = fbase + 16640;
        float* maxbuf     = fbase + 16644;
        uint2* rpair      = (uint2*)(fbase + fcount);
        unsigned* rrows   = (unsigned*)(rpair + RESC_CAP);
        unsigned* rcnt    = rrows + RESC_CAP;
        unsigned* off     = rcnt + 1;
        unsigned* cursor  = off + K_CODES;
        unsigned* rowlist = cursor + K_CODES;
        u64* wsmin = (u64*)(out + OFF_QUANT);   // 16.8 MB, consumed before kquant2 writes qout

        kmax<<<2560, 256, 0, stream>>>(x, cb, maxbuf);
        kscale<<<1, 256, 0, stream>>>(maxbuf, scl, counts_raw, loss_arr, rcnt);
        kprep<<<4096, 256, 0, stream>>>(cb, x, Ah, Al, Bh, Bl, cnorm, scl);
        kargmin_i8<<<4096, 512, 0, stream>>>(Ah, Al, Bh, Bl, cnorm, scl, wsmin);
        kcombine<<<N_ROWS / 256, 256, 0, stream>>>(wsmin, idxf, rcnt, rrows, rpair, counts_raw);
        krescue2<<<256, 256, 0, stream>>>(x, cb, cnorm, rcnt, rrows, rpair, idxf, counts_raw);
        kscan<<<1, 256, 0, stream>>>(counts_raw, off, cursor);
        kscatter<<<N_ROWS / 256, 256, 0, stream>>>(idxf, cursor, rowlist);
        kdw<<<K_CODES, 64, 0, stream>>>(Ah, Al, counts_raw, off, rowlist, scl, nw);
        kquant2<<<512, 256, 0, stream>>>(x, cb, idxf, qout, loss_arr);
        kfinal2<<<K_CODES + 1, C_DIM, 0, stream>>>(ema_c, ema_w, counts_raw, nw, ncb, ncnt,
                                                   loss_arr, out);
    } else {
        float* cnorm = (float*)d_ws;
        float* loss_arr = cnorm + K_CODES;
        hipMemsetAsync(ncnt, 0, K_CODES * sizeof(float), stream);
        hipMemsetAsync(nw, 0, (size_t)K_CODES * C_DIM * sizeof(float), stream);
        hipMemsetAsync(loss_arr, 0, 256 * sizeof(float), stream);
        knorm<<<K_CODES / 4, 256, 0, stream>>>(cb, cnorm);
        kargmin_fp32<<<N_ROWS / 64, 256, 0, stream>>>(x, cb, cnorm, idxf);
        kquant_legacy<<<32768, 256, 0, stream>>>(x, cb, idxf, qout, nw, ncnt, loss_arr);
        kstats_legacy<<<1, 256, 0, stream>>>(ncnt, loss_arr, out);
        kfinal_legacy<<<K_CODES, C_DIM, 0, stream>>>(ema_c, ema_w, ncnt, nw, ncb);
    }
}

// Round 13
// 639.576 us; speedup vs baseline: 1.7618x; 1.0498x over previous
//
#include <hip/hip_runtime.h>
#include <hip/hip_bf16.h>
#include <stdint.h>

#define N_ROWS 32768
#define K_CODES 8192
#define C_DIM 256
#define DECAYF 0.95f
#define COMMITF 0.25f
#define EPSF 1e-5f
#define RESC_EPS 0.045f
#define RESC_CAP 16384

// d_out layout (floats), reference return order
#define OFF_QUANT 0
#define OFF_ELOSS 8388608
#define OFF_PERP  8388609
#define OFF_UNIQ  8388610
#define OFF_NCB   8388611
#define OFF_NCNT  10485763
#define OFF_NW    10493955
#define OFF_IDX   12591107

typedef float f32x4 __attribute__((ext_vector_type(4)));
typedef int i32x4 __attribute__((ext_vector_type(4)));
typedef unsigned long long u64;

#define SWZ(r) ((((r) >> 2) & 7) << 2)

#if defined(__has_builtin)
#if __has_builtin(__builtin_amdgcn_global_load_lds)
#define HAVE_GLDS 1
#endif
#endif
#ifdef HAVE_GLDS
#define GLDS16(g, l) __builtin_amdgcn_global_load_lds( \
    (const __attribute__((address_space(1))) void*)(uintptr_t)(g), \
    (__attribute__((address_space(3))) void*)(uint32_t)(uintptr_t)(l), 16, 0, 0)
#else
#define GLDS16(g, l) do { *(float4*)(l) = *(const float4*)(g); } while (0)
#endif

__device__ __forceinline__ uint32_t fkey(float f) {
    uint32_t b = __float_as_uint(f);
    return b ^ ((uint32_t)((int32_t)b >> 31) | 0x80000000u);
}
__device__ __forceinline__ float funkey(uint32_t k) {
    uint32_t b = (k & 0x80000000u) ? (k ^ 0x80000000u) : ~k;
    return __uint_as_float(b);
}
// 14-bit fixed-point -> two signed i8 (h*128 + l), l in [-64,63]
__device__ __forceinline__ void enc8(float v, float inv, signed char& h, signed char& l) {
    int q = __float2int_rn(v * inv);
    q = q > 16319 ? 16319 : (q < -16320 ? -16320 : q);
    int hh = (q + 64) >> 7;
    h = (signed char)hh;
    l = (signed char)(q - (hh << 7));
}

// ---------------- per-block absmax of x (blocks 0-2047) and cb (2048-2559) ----------------
__global__ __launch_bounds__(256)
void kmax(const float* __restrict__ x, const float* __restrict__ cb, float* __restrict__ maxbuf) {
    const int bid = blockIdx.x, t = threadIdx.x;
    const float* src = bid < 2048 ? x : cb;
    const size_t base = bid < 2048 ? (size_t)bid * 4096 : (size_t)(bid - 2048) * 4096;
    float m = 0.f;
    #pragma unroll
    for (int i = 0; i < 4; ++i) {
        const float4 v = *(const float4*)(src + base + ((size_t)i * 256 + t) * 4);
        m = fmaxf(m, fmaxf(fmaxf(fabsf(v.x), fabsf(v.y)), fmaxf(fabsf(v.z), fabsf(v.w))));
    }
    #pragma unroll
    for (int off = 32; off; off >>= 1) m = fmaxf(m, __shfl_down(m, off));
    __shared__ float ps[4];
    if ((t & 63) == 0) ps[t >> 6] = m;
    __syncthreads();
    if (t == 0) maxbuf[bid] = fmaxf(fmaxf(ps[0], ps[1]), fmaxf(ps[2], ps[3]));
}

// ---------------- final scales + zero accumulators ----------------
__global__ void kscale(const float* __restrict__ maxbuf, float* __restrict__ scl,
                       float* __restrict__ counts, float* __restrict__ loss_arr,
                       unsigned* __restrict__ rcnt) {
    const int t = threadIdx.x;
    float mx = 0.f, me = 0.f;
    for (int i = t; i < 2048; i += 256) mx = fmaxf(mx, maxbuf[i]);
    for (int i = 2048 + t; i < 2560; i += 256) me = fmaxf(me, maxbuf[i]);
    #pragma unroll
    for (int off = 32; off; off >>= 1) {
        mx = fmaxf(mx, __shfl_down(mx, off));
        me = fmaxf(me, __shfl_down(me, off));
    }
    __shared__ float px[4], pe[4];
    if ((t & 63) == 0) { px[t >> 6] = mx; pe[t >> 6] = me; }
    __syncthreads();
    if (t == 0) {
        const float Sx = fmaxf(fmaxf(px[0], px[1]), fmaxf(px[2], px[3])) * (16384.f / 16320.f) + 1e-20f;
        const float Se = fmaxf(fmaxf(pe[0], pe[1]), fmaxf(pe[2], pe[3])) * (16384.f / 16320.f) + 1e-20f;
        scl[0] = Sx; scl[1] = Se; scl[2] = Sx * Se / 268435456.f;
        *rcnt = 0u;
    }
    for (int i = t; i < K_CODES; i += 256) counts[i] = 0.f;
    loss_arr[t] = 0.f;
}

// ---------------- encode cb (blocks 0-2047, + cnorm) and x (2048-4095, transpose) ----------------
__global__ __launch_bounds__(256)
void kprep(const float* __restrict__ cb, const float* __restrict__ x,
           signed char* __restrict__ Ah, signed char* __restrict__ Al,
           signed char* __restrict__ Bh, signed char* __restrict__ Bl,
           float* __restrict__ cnorm, const float* __restrict__ scl) {
    const int bid = blockIdx.x;
    const int t = threadIdx.x;
    if (bid < 2048) {
        const float inve = 16384.f / scl[1];
        const size_t i4 = ((size_t)bid * 256 + t) * 4;
        const float4 v = *(const float4*)(cb + i4);
        signed char h0, h1, h2, h3, l0, l1, l2, l3;
        enc8(v.x, inve, h0, l0); enc8(v.y, inve, h1, l1);
        enc8(v.z, inve, h2, l2); enc8(v.w, inve, h3, l3);
        *(char4*)(Bh + i4) = make_char4(h0, h1, h2, h3);
        *(char4*)(Bl + i4) = make_char4(l0, l1, l2, l3);
        float s = v.x * v.x + v.y * v.y + v.z * v.z + v.w * v.w;
        #pragma unroll
        for (int off = 32; off; off >>= 1) s += __shfl_down(s, off);
        if ((t & 63) == 0) cnorm[i4 >> 8] = s;
    } else {
        const float invx = 16384.f / scl[0];
        __shared__ float xt[64][65];
        const int xb_id = bid - 2048;       // 8 b * 4 ct * 64 st = 2048
        const int st = xb_id & 63;
        const int ct = (xb_id >> 6) & 3;
        const int b  = xb_id >> 8;
        const float* xb = x + ((size_t)b * C_DIM + ct * 64) * 4096 + st * 64;
        {
            const int s_l = t & 63, c0 = t >> 6;
            #pragma unroll
            for (int cc = 0; cc < 16; ++cc) {
                int c_l = cc * 4 + c0;
                xt[c_l][s_l] = xb[(size_t)c_l * 4096 + s_l];
            }
        }
        __syncthreads();
        const int c2 = (t & 31) * 2;
        const int s0 = t >> 5;
        #pragma unroll
        for (int ww = 0; ww < 8; ++ww) {
            int s_o = ww * 8 + s0;
            signed char h0, l0, h1, l1;
            enc8(xt[c2][s_o], invx, h0, l0);
            enc8(xt[c2 + 1][s_o], invx, h1, l1);
            size_t off = ((size_t)(b * 4096 + st * 64 + s_o)) * C_DIM + ct * 64 + c2;
            *(char2*)(Ah + off) = make_char2(h0, h1);
            *(char2*)(Al + off) = make_char2(l0, l1);
        }
    }
}

// ---------------- i8 MFMA distance GEMM + per-row top-2 argmin ----------------
// 128x256 tile, 8 waves (2Mx4N), per-wave 64x64 (acc[4][4] = 64 VGPR).
// BK=64 i8; 12 K-tiles: 0-3 (h,h), <<7, 4-7 (h,l), 8-11 (l,h).
// LDS 48KB dbuf -> 2 blocks/CU (16 waves) with launch_bounds(512,4).
__global__ __launch_bounds__(512, 4)
void kargmin_i8(const signed char* __restrict__ Ah, const signed char* __restrict__ Al,
                const signed char* __restrict__ Bh, const signed char* __restrict__ Bl,
                const float* __restrict__ cnorm, const float* __restrict__ scl,
                u64* __restrict__ wsmin) {
    __shared__ unsigned char As[2][128 * 64];   // 8KB x2
    __shared__ unsigned char Bs[2][256 * 64];   // 16KB x2

    const int t = threadIdx.x;
    const int lane = t & 63;
    const int wid = t >> 6;
    const int xcd = blockIdx.x & 7;
    const int ii = blockIdx.x >> 3;              // 0..1023 within XCD
    const int ntile = xcd * 4 + (ii & 3);        // 0..31
    const int mtile = ii >> 2;                   // 0..255
    const int m0 = mtile * 128;
    const int n0 = ntile * 256;
    const int wr = wid >> 2;                     // 0..1
    const int wc = wid & 3;                      // 0..3
    const int wm = wr * 64;
    const int wn = wc * 64;
    const int lm = lane & 15;
    const int lh = lane >> 4;
    const int NKT = 12;

    i32x4 acc[4][4];
    #pragma unroll
    for (int i = 0; i < 4; ++i)
        #pragma unroll
        for (int j = 0; j < 4; ++j) acc[i][j] = (i32x4){0, 0, 0, 0};

    const signed char* const PAp[3] = {Ah, Ah, Al};
    const signed char* const PBp[3] = {Bh, Bl, Bh};

    // staging: rows of 64B = 4 slots of 16B; swizzle slot ^= row&3
    const int sAr = t >> 2;          // A row 0..127
    const int ssl = t & 3;
    const int gsA = ssl ^ (sAr & 3);

    auto stage = [&](int kt, int buf) {
        const int seg = kt >> 2;
        const int kk0 = (kt & 3) * 64;
        const signed char* Ab = PAp[seg] + (size_t)m0 * 256 + kk0;
        const signed char* Bb = PBp[seg] + (size_t)n0 * 256 + kk0;
        GLDS16(Ab + (size_t)sAr * 256 + gsA * 16, &As[buf][t * 16]);
        #pragma unroll
        for (int it = 0; it < 2; ++it) {
            const int chunk = it * 512 + t;
            const int r = it * 128 + sAr;
            const int gs = ssl ^ (r & 3);
            GLDS16(Bb + (size_t)r * 256 + gs * 16, &Bs[buf][chunk * 16]);
        }
    };

    const int rboff = (lh ^ (lm & 3)) * 16;   // swizzled 16B slot within 64B row

    stage(0, 0);
    __syncthreads();

    for (int kt = 0; kt < NKT; ++kt) {
        const int cur = kt & 1;
        if (kt + 1 < NKT) stage(kt + 1, cur ^ 1);
        i32x4 a[4], b[4];
        #pragma unroll
        for (int j = 0; j < 4; ++j)
            b[j] = *(const i32x4*)&Bs[cur][(wn + j * 16 + lm) * 64 + rboff];
        #pragma unroll
        for (int i = 0; i < 4; ++i)
            a[i] = *(const i32x4*)&As[cur][(wm + i * 16 + lm) * 64 + rboff];
        #pragma unroll
        for (int i = 0; i < 4; ++i)
            #pragma unroll
            for (int j = 0; j < 4; ++j)
                acc[i][j] = __builtin_amdgcn_mfma_i32_16x16x64_i8(a[i], b[j], acc[i][j], 0, 0, 0);
        if (kt == 3) {
            // H segments complete: fold 128*H into the same accumulator
            #pragma unroll
            for (int i = 0; i < 4; ++i)
                #pragma unroll
                for (int j = 0; j < 4; ++j)
                    acc[i][j] = acc[i][j] << 7;
        }
        __syncthreads();
    }

    // epilogue: dist = cnorm - 2*scale*128*(128*H + M); per-row top-2
    const double dsc = (double)scl[2] * 128.0;
    float cn[4];
    #pragma unroll
    for (int j = 0; j < 4; ++j) cn[j] = cnorm[n0 + wn + j * 16 + lm];

    u64* redbuf = (u64*)&As[0][0];   // 128 rows x 4 wc x 2 u64 = 8KB
    #pragma unroll
    for (int i = 0; i < 4; ++i) {
        u64 p1[4], p2[4];
        #pragma unroll
        for (int r = 0; r < 4; ++r) {
            u64 b1 = ~0ull, b2 = ~0ull;
            #pragma unroll
            for (int j = 0; j < 4; ++j) {
                const float dist = (float)((double)cn[j] - 2.0 * dsc * (double)acc[i][j][r]);
                u64 pk = ((u64)fkey(dist) << 32) | (unsigned)(n0 + wn + j * 16 + lm);
                if (pk < b1) { b2 = b1; b1 = pk; }
                else if (pk < b2) b2 = pk;
            }
            p1[r] = b1; p2[r] = b2;
        }
        #pragma unroll
        for (int off = 1; off < 16; off <<= 1) {
            #pragma unroll
            for (int r = 0; r < 4; ++r) {
                u64 o1 = __shfl_xor(p1[r], off);
                u64 o2 = __shfl_xor(p2[r], off);
                u64 lo = p1[r] < o1 ? p1[r] : o1;
                u64 hi = p1[r] < o1 ? o1 : p1[r];
                u64 mn2 = p2[r] < o2 ? p2[r] : o2;
                p1[r] = lo;
                p2[r] = hi < mn2 ? hi : mn2;
            }
        }
        if (lm == 0) {
            #pragma unroll
            for (int r = 0; r < 4; ++r) {
                const int rl = wm + i * 16 + lh * 4 + r;   // 0..127
                redbuf[rl * 8 + wc * 2 + 0] = p1[r];
                redbuf[rl * 8 + wc * 2 + 1] = p2[r];
            }
        }
    }
    __syncthreads();
    if (t < 128) {
        u64 m1 = ~0ull, m2 = ~0ull;
        #pragma unroll
        for (int w = 0; w < 4; ++w) {
            u64 a1 = redbuf[t * 8 + w * 2 + 0];
            u64 a2 = redbuf[t * 8 + w * 2 + 1];
            u64 lo = m1 < a1 ? m1 : a1;
            u64 hi = m1 < a1 ? a1 : m1;
            u64 mn2 = m2 < a2 ? m2 : a2;
            m1 = lo;
            m2 = hi < mn2 ? hi : mn2;
        }
        size_t o = ((size_t)(m0 + t) * 32 + ntile) * 2;
        wsmin[o] = m1; wsmin[o + 1] = m2;
    }
}

// ---------------- combine per-ntile mins; histogram; flag near-ties ----------------
__global__ void kcombine(const u64* __restrict__ wsmin, float* __restrict__ idxf,
                         unsigned* __restrict__ rcnt, unsigned* __restrict__ rrows,
                         uint2* __restrict__ rpair, float* __restrict__ counts) {
    const int row = blockIdx.x * 256 + threadIdx.x;
    const u64* p = wsmin + (size_t)row * 64;
    u64 m1 = ~0ull, m2 = ~0ull;
    for (int i = 0; i < 64; i += 2) {
        u64 a = p[i], b = p[i + 1];
        u64 lo = a < m1 ? a : m1;
        u64 hi = a < m1 ? m1 : a;
        u64 c = m2 < b ? m2 : b;
        m1 = lo;
        m2 = hi < c ? hi : c;
    }
    const int k = (int)(unsigned)(m1 & 0xffffffffu);
    idxf[row] = (float)k;
    atomicAdd(&counts[k], 1.0f);
    float d1 = funkey((uint32_t)(m1 >> 32));
    float d2 = funkey((uint32_t)(m2 >> 32));
    if (d2 - d1 < RESC_EPS) {
        unsigned slot = atomicAdd(rcnt, 1u);
        if (slot < RESC_CAP) {
            rrows[slot] = (unsigned)row;
            rpair[slot] = make_uint2((unsigned)k, (unsigned)(m2 & 0xffffffffu));
        }
    }
}

// ---------------- exact fp32 pair re-score (wave per flagged row) ----------------
__global__ __launch_bounds__(256)
void krescue2(const float* __restrict__ x, const float* __restrict__ cb,
              const float* __restrict__ cnorm, const unsigned* __restrict__ rcnt,
              const unsigned* __restrict__ rrows, const uint2* __restrict__ rpair,
              float* __restrict__ idxf, float* __restrict__ counts) {
    const int lane = threadIdx.x & 63;
    const int wv = threadIdx.x >> 6;
    unsigned cnt = *rcnt; if (cnt > RESC_CAP) cnt = RESC_CAP;
    for (unsigned i = blockIdx.x * 4 + wv; i < cnt; i += gridDim.x * 4) {
        const int row = (int)rrows[i];
        const uint2 kk = rpair[i];
        const int b = row >> 12, s = row & 4095;
        float d1 = 0.f, d2 = 0.f;
        #pragma unroll
        for (int q = 0; q < 4; ++q) {
            const int c = lane + q * 64;
            const float xv = x[((size_t)(b * 256 + c)) * 4096 + s];
            d1 = fmaf(xv, cb[(size_t)kk.x * 256 + c], d1);
            d2 = fmaf(xv, cb[(size_t)kk.y * 256 + c], d2);
        }
        #pragma unroll
        for (int off = 32; off; off >>= 1) {
            d1 += __shfl_down(d1, off);
            d2 += __shfl_down(d2, off);
        }
        if (lane == 0) {
            const float dist1 = fmaf(-2.f, d1, cnorm[kk.x]);
            const float dist2 = fmaf(-2.f, d2, cnorm[kk.y]);
            const u64 p1 = ((u64)fkey(dist1) << 32) | kk.x;
            const u64 p2 = ((u64)fkey(dist2) << 32) | kk.y;
            const int knew = (int)(unsigned)((p1 < p2 ? p1 : p2) & 0xffffffffu);
            const int kold = (int)kk.x;
            if (knew != kold) {
                atomicAdd(&counts[kold], -1.0f);
                atomicAdd(&counts[knew], 1.0f);
                idxf[row] = (float)knew;
            }
        }
    }
}

// ---------------- CSR build: scan / scatter ----------------
__global__ void kscan(const float* __restrict__ counts, unsigned* __restrict__ off,
                      unsigned* __restrict__ cursor) {
    __shared__ unsigned part[256];
    const int t = threadIdx.x;
    unsigned local[32];
    unsigned s = 0;
    #pragma unroll
    for (int i = 0; i < 32; ++i) { local[i] = s; s += (unsigned)counts[t * 32 + i]; }
    part[t] = s;
    __syncthreads();
    if (t == 0) {
        unsigned run = 0;
        for (int i = 0; i < 256; ++i) { unsigned v = part[i]; part[i] = run; run += v; }
    }
    __syncthreads();
    const unsigned base = part[t];
    #pragma unroll
    for (int i = 0; i < 32; ++i) {
        unsigned o = base + local[i];
        off[t * 32 + i] = o;
        cursor[t * 32 + i] = o;
    }
}

__global__ void kscatter(const float* __restrict__ idxf, unsigned* __restrict__ cursor,
                         unsigned* __restrict__ rowlist) {
    const int n = blockIdx.x * 256 + threadIdx.x;
    const int k = (int)idxf[n];
    unsigned pos = atomicAdd(&cursor[k], 1u);
    rowlist[pos] = (unsigned)n;
}

// ---------------- dw = segment_sum(x) via CSR, exact-int from i8 planes ----------------
__global__ void kdw(const signed char* __restrict__ Ah, const signed char* __restrict__ Al,
                    const float* __restrict__ counts, const unsigned* __restrict__ off,
                    const unsigned* __restrict__ rowlist, const float* __restrict__ scl,
                    float* __restrict__ dwout) {
    const int k = blockIdx.x;
    const int lane = threadIdx.x;   // 64
    const int cnt = (int)counts[k];
    const unsigned base = off[k];
    int ax = 0, ay = 0, az = 0, aw = 0;
    for (int i = 0; i < cnt; ++i) {
        const unsigned row = rowlist[base + i];
        const char4 h = *(const char4*)(Ah + (size_t)row * C_DIM + lane * 4);
        const char4 l = *(const char4*)(Al + (size_t)row * C_DIM + lane * 4);
        ax += h.x * 128 + l.x;
        ay += h.y * 128 + l.y;
        az += h.z * 128 + l.z;
        aw += h.w * 128 + l.w;
    }
    const float sxf = scl[0] * (1.f / 16384.f);
    float4 o;
    o.x = (float)ax * sxf; o.y = (float)ay * sxf;
    o.z = (float)az * sxf; o.w = (float)aw * sxf;
    *(float4*)(dwout + (size_t)k * C_DIM + lane * 4) = o;
}

// ---------------- quantize (gather-transpose) + e_loss ----------------
__global__ __launch_bounds__(256)
void kquant2(const float* __restrict__ x, const float* __restrict__ cb,
             const float* __restrict__ idxf, float* __restrict__ qout,
             float* __restrict__ loss_arr) {
    __shared__ int ki[64];
    __shared__ float cbt[64][257];
    const int t = threadIdx.x;
    const int bid = blockIdx.x;
    const int chunk = bid & 63;
    const int b = bid >> 6;
    const int s0 = chunk * 64;
    if (t < 64) ki[t] = (int)idxf[b * 4096 + s0 + t];
    __syncthreads();
    {
        const int lane = t & 63;
        const int rr = t >> 6;
        #pragma unroll
        for (int p = 0; p < 16; ++p) {
            const int r = p * 4 + rr;
            const float4 v = *(const float4*)(cb + (size_t)ki[r] * C_DIM + lane * 4);
            cbt[r][lane * 4 + 0] = v.x;
            cbt[r][lane * 4 + 1] = v.y;
            cbt[r][lane * 4 + 2] = v.z;
            cbt[r][lane * 4 + 3] = v.w;
        }
    }
    __syncthreads();
    const int sg = t & 15;
    const int c0 = t >> 4;
    float lsum = 0.f;
    #pragma unroll
    for (int cc = 0; cc < 16; ++cc) {
        const int c = cc * 16 + c0;
        const size_t go = ((size_t)b * C_DIM + c) * 4096 + s0 + sg * 4;
        const float4 xv = *(const float4*)(x + go);
        float qx = cbt[sg * 4 + 0][c];
        float qy = cbt[sg * 4 + 1][c];
        float qz = cbt[sg * 4 + 2][c];
        float qw = cbt[sg * 4 + 3][c];
        float4 st;
        st.x = xv.x + (qx - xv.x);
        st.y = xv.y + (qy - xv.y);
        st.z = xv.z + (qz - xv.z);
        st.w = xv.w + (qw - xv.w);
        *(float4*)(qout + go) = st;
        float dx = qx - xv.x, dy = qy - xv.y, dz = qz - xv.z, dw_ = qw - xv.w;
        lsum += dx * dx + dy * dy + dz * dz + dw_ * dw_;
    }
    #pragma unroll
    for (int off = 32; off; off >>= 1) lsum += __shfl_down(lsum, off);
    __shared__ float ps[4];
    if ((t & 63) == 0) ps[t >> 6] = lsum;
    __syncthreads();
    if (t == 0) atomicAdd(&loss_arr[bid & 255], ps[0] + ps[1] + ps[2] + ps[3]);
}

// ---------------- EMA finalize + stats (fused; block K_CODES does stats) ----------------
__global__ void kfinal2(const float* __restrict__ ema_c, const float* __restrict__ ema_w,
                        const float* __restrict__ counts, float* __restrict__ dw,
                        float* __restrict__ ncb, float* __restrict__ ncnt_out,
                        const float* __restrict__ loss_arr, float* __restrict__ out) {
    const int k = blockIdx.x;
    const int t = threadIdx.x;
    if (k < K_CODES) {
        const float ncnt = (DECAYF * ema_c[k] + (1.f - DECAYF) * counts[k] + EPSF)
                           / (8.f + (float)K_CODES * EPSF) * 8.f;
        const size_t o = (size_t)k * C_DIM + t;
        const float nwv = DECAYF * ema_w[o] + (1.f - DECAYF) * dw[o];
        dw[o]  = nwv;
        ncb[o] = nwv / ncnt;
        if (t == 0) ncnt_out[k] = ncnt;
    } else {
        float nz = 0.f, s = 0.f;
        for (int kk = t; kk < K_CODES; kk += 256) {
            float cnt = counts[kk];
            if (cnt != 0.f) nz += 1.f;
            float p = cnt * (1.f / 32768.f);
            s += p * logf(p + 1e-10f);
        }
        float ls = loss_arr[t];
        #pragma unroll
        for (int off = 32; off; off >>= 1) {
            s  += __shfl_down(s, off);
            nz += __shfl_down(nz, off);
            ls += __shfl_down(ls, off);
        }
        __shared__ float ss[4], zz[4], ll[4];
        const int wid = t >> 6, lane = t & 63;
        if (lane == 0) { ss[wid] = s; zz[wid] = nz; ll[wid] = ls; }
        __syncthreads();
        if (t == 0) {
            float st = ss[0] + ss[1] + ss[2] + ss[3];
            float zt = zz[0] + zz[1] + zz[2] + zz[3];
            float lt = ll[0] + ll[1] + ll[2] + ll[3];
            out[OFF_ELOSS] = COMMITF * lt / 8388608.f;
            out[OFF_PERP]  = expf(-st);
            out[OFF_UNIQ]  = zt;
        }
    }
}

// ======= fallback fp32 path (used only if ws too small) =======
__global__ void knorm(const float* __restrict__ cb, float* __restrict__ cnorm) {
    const int wid  = threadIdx.x >> 6;
    const int lane = threadIdx.x & 63;
    const int row  = blockIdx.x * 4 + wid;
    const float4 v = *(const float4*)(cb + (size_t)row * C_DIM + lane * 4);
    float s = v.x * v.x + v.y * v.y + v.z * v.z + v.w * v.w;
    #pragma unroll
    for (int off = 32; off; off >>= 1) s += __shfl_down(s, off);
    if (lane == 0) cnorm[row] = s;
}

__launch_bounds__(256, 1)
__global__ void kargmin_fp32(const float* __restrict__ x, const float* __restrict__ cb,
                             const float* __restrict__ cnorm, float* __restrict__ idxf) {
    __shared__ float xs[64][256];
    __shared__ float es[64][256];
    const int t  = threadIdx.x;
    const int n0 = blockIdx.x * 64;
    const int b  = n0 >> 12;
    const int s0 = n0 & 4095;
    {
        const int r  = t & 63;
        const int c0 = t >> 6;
        const float* xb = x + (size_t)b * C_DIM * 4096 + s0 + r;
        const int sw = SWZ(r);
        #pragma unroll 8
        for (int cc = 0; cc < 64; ++cc) {
            int c = cc * 4 + c0;
            xs[r][c ^ sw] = xb[(size_t)c * 4096];
        }
    }
    const int mg  = t >> 4;
    const int ng  = t & 15;
    const int m0  = mg * 4;
    const int nn0 = ng * 4;
    const int swm = SWZ(m0);
    const int swn = SWZ(nn0);
    float minv[4] = {1e30f, 1e30f, 1e30f, 1e30f};
    int   mini[4] = {0, 0, 0, 0};
    for (int k0 = 0; k0 < K_CODES; k0 += 64) {
        __syncthreads();
        {
            const int lane = t & 63;
            const int cw   = t >> 6;
            #pragma unroll
            for (int p = 0; p < 16; ++p) {
                int code = p * 4 + cw;
                float4 v = *(const float4*)(cb + (size_t)(k0 + code) * C_DIM + lane * 4);
                *(float4*)&es[code][(lane * 4) ^ SWZ(code)] = v;
            }
        }
        float cn[4];
        #pragma unroll
        for (int j = 0; j < 4; ++j) cn[j] = cnorm[k0 + nn0 + j];
        __syncthreads();
        float acc[4][4];
        #pragma unroll
        for (int i = 0; i < 4; ++i)
            #pragma unroll
            for (int j = 0; j < 4; ++j) acc[i][j] = 0.f;
        #pragma unroll 4
        for (int c = 0; c < C_DIM; c += 4) {
            float4 xa[4], eb[4];
            #pragma unroll
            for (int i = 0; i < 4; ++i) xa[i] = *(const float4*)&xs[m0 + i][c ^ swm];
            #pragma unroll
            for (int j = 0; j < 4; ++j) eb[j] = *(const float4*)&es[nn0 + j][c ^ swn];
            #pragma unroll
            for (int i = 0; i < 4; ++i)
                #pragma unroll
                for (int j = 0; j < 4; ++j)
                    acc[i][j] += xa[i].x * eb[j].x + xa[i].y * eb[j].y +
                                 xa[i].z * eb[j].z + xa[i].w * eb[j].w;
        }
        #pragma unroll
        for (int j = 0; j < 4; ++j) {
            const int kg = k0 + nn0 + j;
            #pragma unroll
            for (int i = 0; i < 4; ++i) {
                float dist = fmaf(-2.f, acc[i][j], cn[j]);
                if (dist < minv[i]) { minv[i] = dist; mini[i] = kg; }
            }
        }
    }
    #pragma unroll
    for (int off = 1; off < 16; off <<= 1) {
        #pragma unroll
        for (int i = 0; i < 4; ++i) {
            float ov = __shfl_xor(minv[i], off);
            int   oi = __shfl_xor(mini[i], off);
            if (ov < minv[i] || (ov == minv[i] && oi < mini[i])) { minv[i] = ov; mini[i] = oi; }
        }
    }
    if (ng == 0) {
        #pragma unroll
        for (int i = 0; i < 4; ++i) idxf[n0 + m0 + i] = (float)mini[i];
    }
}

__global__ void kquant_legacy(const float* __restrict__ x, const float* __restrict__ cb,
                              const float* __restrict__ idxf, float* __restrict__ qout,
                              float* __restrict__ dw, float* __restrict__ counts,
                              float* __restrict__ loss_arr) {
    const int t   = threadIdx.x;
    const int bid = blockIdx.x;
    const int sc  = bid & 15;
    const int c   = (bid >> 4) & 255;
    const int b   = bid >> 12;
    const int s   = sc * 256 + t;
    const int n   = b * 4096 + s;
    const int k   = (int)idxf[n];
    const size_t xoff = ((size_t)b * C_DIM + c) * 4096 + s;
    const float xv = x[xoff];
    const float q  = cb[(size_t)k * C_DIM + c];
    qout[xoff] = xv + (q - xv);
    atomicAdd(&dw[(size_t)k * C_DIM + c], xv);
    if (c == 0) atomicAdd(&counts[k], 1.0f);
    float d = q - xv;
    float p = d * d;
    #pragma unroll
    for (int off = 32; off; off >>= 1) p += __shfl_down(p, off);
    __shared__ float ps[4];
    if ((t & 63) == 0) ps[t >> 6] = p;
    __syncthreads();
    if (t == 0) atomicAdd(&loss_arr[bid & 255], ps[0] + ps[1] + ps[2] + ps[3]);
}

__global__ void kstats_legacy(const float* __restrict__ counts, const float* __restrict__ loss_arr,
                              float* __restrict__ out) {
    const int t = threadIdx.x;
    float nz = 0.f, s = 0.f;
    for (int k = t; k < K_CODES; k += 256) {
        float cnt = counts[k];
        if (cnt != 0.f) nz += 1.f;
        float p = cnt * (1.f / 32768.f);
        s += p * logf(p + 1e-10f);
    }
    float ls = loss_arr[t];
    #pragma unroll
    for (int off = 32; off; off >>= 1) {
        s  += __shfl_down(s, off);
        nz += __shfl_down(nz, off);
        ls += __shfl_down(ls, off);
    }
    __shared__ float ss[4], zz[4], ll[4];
    const int wid = t >> 6, lane = t & 63;
    if (lane == 0) { ss[wid] = s; zz[wid] = nz; ll[wid] = ls; }
    __syncthreads();
    if (t == 0) {
        out[OFF_ELOSS] = COMMITF * (ll[0] + ll[1] + ll[2] + ll[3]) / 8388608.f;
        out[OFF_PERP]  = expf(-(ss[0] + ss[1] + ss[2] + ss[3]));
        out[OFF_UNIQ]  = zz[0] + zz[1] + zz[2] + zz[3];
    }
}

__global__ void kfinal_legacy(const float* __restrict__ ema_c, const float* __restrict__ ema_w,
                              float* __restrict__ counts, float* __restrict__ dw,
                              float* __restrict__ ncb) {
    const int k = blockIdx.x;
    const int c = threadIdx.x;
    const float cnt  = counts[k];
    const float ncnt = (DECAYF * ema_c[k] + (1.f - DECAYF) * cnt + EPSF)
                       / (8.f + (float)K_CODES * EPSF) * 8.f;
    const size_t o = (size_t)k * C_DIM + c;
    const float nw = DECAYF * ema_w[o] + (1.f - DECAYF) * dw[o];
    __syncthreads();
    dw[o]  = nw;
    ncb[o] = nw / ncnt;
    if (c == 0) counts[k] = ncnt;
}

extern "C" void kernel_launch(void* const* d_in, const int* in_sizes, int n_in,
                              void* d_out, int out_size, void* d_ws, size_t ws_size,
                              hipStream_t stream) {
    const float* x     = (const float*)d_in[0];
    const float* cb    = (const float*)d_in[1];
    const float* ema_c = (const float*)d_in[2];
    const float* ema_w = (const float*)d_in[3];
    float* out = (float*)d_out;

    float* qout = out + OFF_QUANT;
    float* ncb  = out + OFF_NCB;
    float* ncnt = out + OFF_NCNT;
    float* nw   = out + OFF_NW;
    float* idxf = out + OFF_IDX;

    const size_t szA = (size_t)N_ROWS * C_DIM;    // 8388608 bytes per plane
    const size_t szB = (size_t)K_CODES * C_DIM;   // 2097152
    const size_t fcount = 8192 + 256 + 8192 + 4 + 2560;
    const size_t need = 2 * szA + 2 * szB + fcount * 4
                      + RESC_CAP * 8 + RESC_CAP * 4 + 4 + 8192 * 4 * 2 + 32768 * 4 + 64;
    const bool use_i8 = ws_size >= need;

    if (use_i8) {
        signed char* Ah = (signed char*)d_ws;
        signed char* Al = Ah + szA;
        signed char* Bh = Al + szA;
        signed char* Bl = Bh + szB;
        float* fbase      = (float*)(Bl + szB);
        float* cnorm      = fbase;
        float* loss_arr   = fbase + 8192;
        float* counts_raw = fbase + 8448;
        float* scl        = fbase + 16640;
        float* maxbuf     = fbase + 16644;
        uint2* rpair      = (uint2*)(fbase + fcount);
        unsigned* rrows   = (unsigned*)(rpair + RESC_CAP);
        unsigned* rcnt    = rrows + RESC_CAP;
        unsigned* off     = rcnt + 1;
        unsigned* cursor  = off + K_CODES;
        unsigned* rowlist = cursor + K_CODES;
        u64* wsmin = (u64*)(out + OFF_QUANT);   // 16.8 MB, consumed before kquant2 writes qout

        kmax<<<2560, 256, 0, stream>>>(x, cb, maxbuf);
        kscale<<<1, 256, 0, stream>>>(maxbuf, scl, counts_raw, loss_arr, rcnt);
        kprep<<<4096, 256, 0, stream>>>(cb, x, Ah, Al, Bh, Bl, cnorm, scl);
        kargmin_i8<<<8192, 512, 0, stream>>>(Ah, Al, Bh, Bl, cnorm, scl, wsmin);
        kcombine<<<N_ROWS / 256, 256, 0, stream>>>(wsmin, idxf, rcnt, rrows, rpair, counts_raw);
        krescue2<<<256, 256, 0, stream>>>(x, cb, cnorm, rcnt, rrows, rpair, idxf, counts_raw);
        kscan<<<1, 256, 0, stream>>>(counts_raw, off, cursor);
        kscatter<<<N_ROWS / 256, 256, 0, stream>>>(idxf, cursor, rowlist);
        kdw<<<K_CODES, 64, 0, stream>>>(Ah, Al, counts_raw, off, rowlist, scl, nw);
        kquant2<<<512, 256, 0, stream>>>(x, cb, idxf, qout, loss_arr);
        kfinal2<<<K_CODES + 1, C_DIM, 0, stream>>>(ema_c, ema_w, counts_raw, nw, ncb, ncnt,
                                                   loss_arr, out);
    } else {
        float* cnorm = (float*)d_ws;
        float* loss_arr = cnorm + K_CODES;
        hipMemsetAsync(ncnt, 0, K_CODES * sizeof(float), stream);
        hipMemsetAsync(nw, 0, (size_t)K_CODES * C_DIM * sizeof(float), stream);
        hipMemsetAsync(loss_arr, 0, 256 * sizeof(float), stream);
        knorm<<<K_CODES / 4, 256, 0, stream>>>(cb, cnorm);
        kargmin_fp32<<<N_ROWS / 64, 256, 0, stream>>>(x, cb, cnorm, idxf);
        kquant_legacy<<<32768, 256, 0, stream>>>(x, cb, idxf, qout, nw, ncnt, loss_arr);
        kstats_legacy<<<1, 256, 0, stream>>>(ncnt, loss_arr, out);
        kfinal_legacy<<<K_CODES, C_DIM, 0, stream>>>(ema_c, ema_w, ncnt, nw, ncb);
    }
}

// Round 14
// 628.716 us; speedup vs baseline: 1.7923x; 1.0173x over previous
//
#include <hip/hip_runtime.h>
#include <hip/hip_bf16.h>
#include <stdint.h>

#define N_ROWS 32768
#define K_CODES 8192
#define C_DIM 256
#define DECAYF 0.95f
#define COMMITF 0.25f
#define EPSF 1e-5f
#define RESC_EPS 0.045f
#define RESC_CAP 16384

// d_out layout (floats), reference return order
#define OFF_QUANT 0
#define OFF_ELOSS 8388608
#define OFF_PERP  8388609
#define OFF_UNIQ  8388610
#define OFF_NCB   8388611
#define OFF_NCNT  10485763
#define OFF_NW    10493955
#define OFF_IDX   12591107

typedef float f32x4 __attribute__((ext_vector_type(4)));
typedef int i32x4 __attribute__((ext_vector_type(4)));
typedef unsigned long long u64;

#define SWZ(r) ((((r) >> 2) & 7) << 2)

#if defined(__has_builtin)
#if __has_builtin(__builtin_amdgcn_global_load_lds)
#define HAVE_GLDS 1
#endif
#endif
#ifdef HAVE_GLDS
#define GLDS16(g, l) __builtin_amdgcn_global_load_lds( \
    (const __attribute__((address_space(1))) void*)(uintptr_t)(g), \
    (__attribute__((address_space(3))) void*)(uint32_t)(uintptr_t)(l), 16, 0, 0)
#else
#define GLDS16(g, l) do { *(float4*)(l) = *(const float4*)(g); } while (0)
#endif

__device__ __forceinline__ uint32_t fkey(float f) {
    uint32_t b = __float_as_uint(f);
    return b ^ ((uint32_t)((int32_t)b >> 31) | 0x80000000u);
}
__device__ __forceinline__ float funkey(uint32_t k) {
    uint32_t b = (k & 0x80000000u) ? (k ^ 0x80000000u) : ~k;
    return __uint_as_float(b);
}
// 14-bit fixed-point -> two signed i8 (h*128 + l), l in [-64,63]
__device__ __forceinline__ void enc8(float v, float inv, signed char& h, signed char& l) {
    int q = __float2int_rn(v * inv);
    q = q > 16319 ? 16319 : (q < -16320 ? -16320 : q);
    int hh = (q + 64) >> 7;
    h = (signed char)hh;
    l = (signed char)(q - (hh << 7));
}

// ---------------- per-block absmax of x (blocks 0-2047) and cb (2048-2559) ----------------
__global__ __launch_bounds__(256)
void kmax(const float* __restrict__ x, const float* __restrict__ cb, float* __restrict__ maxbuf) {
    const int bid = blockIdx.x, t = threadIdx.x;
    const float* src = bid < 2048 ? x : cb;
    const size_t base = bid < 2048 ? (size_t)bid * 4096 : (size_t)(bid - 2048) * 4096;
    float m = 0.f;
    #pragma unroll
    for (int i = 0; i < 4; ++i) {
        const float4 v = *(const float4*)(src + base + ((size_t)i * 256 + t) * 4);
        m = fmaxf(m, fmaxf(fmaxf(fabsf(v.x), fabsf(v.y)), fmaxf(fabsf(v.z), fabsf(v.w))));
    }
    #pragma unroll
    for (int off = 32; off; off >>= 1) m = fmaxf(m, __shfl_down(m, off));
    __shared__ float ps[4];
    if ((t & 63) == 0) ps[t >> 6] = m;
    __syncthreads();
    if (t == 0) maxbuf[bid] = fmaxf(fmaxf(ps[0], ps[1]), fmaxf(ps[2], ps[3]));
}

// ---------------- final scales + zero accumulators ----------------
__global__ void kscale(const float* __restrict__ maxbuf, float* __restrict__ scl,
                       float* __restrict__ counts, float* __restrict__ loss_arr,
                       unsigned* __restrict__ rcnt) {
    const int t = threadIdx.x;
    float mx = 0.f, me = 0.f;
    for (int i = t; i < 2048; i += 256) mx = fmaxf(mx, maxbuf[i]);
    for (int i = 2048 + t; i < 2560; i += 256) me = fmaxf(me, maxbuf[i]);
    #pragma unroll
    for (int off = 32; off; off >>= 1) {
        mx = fmaxf(mx, __shfl_down(mx, off));
        me = fmaxf(me, __shfl_down(me, off));
    }
    __shared__ float px[4], pe[4];
    if ((t & 63) == 0) { px[t >> 6] = mx; pe[t >> 6] = me; }
    __syncthreads();
    if (t == 0) {
        const float Sx = fmaxf(fmaxf(px[0], px[1]), fmaxf(px[2], px[3])) * (16384.f / 16320.f) + 1e-20f;
        const float Se = fmaxf(fmaxf(pe[0], pe[1]), fmaxf(pe[2], pe[3])) * (16384.f / 16320.f) + 1e-20f;
        scl[0] = Sx; scl[1] = Se; scl[2] = Sx * Se / 268435456.f;
        *rcnt = 0u;
    }
    for (int i = t; i < K_CODES; i += 256) counts[i] = 0.f;
    loss_arr[t] = 0.f;
}

// ---------------- encode cb (blocks 0-2047, + cnorm) and x (2048-4095, transpose) ----------------
__global__ __launch_bounds__(256)
void kprep(const float* __restrict__ cb, const float* __restrict__ x,
           signed char* __restrict__ Ah, signed char* __restrict__ Al,
           signed char* __restrict__ Bh, signed char* __restrict__ Bl,
           float* __restrict__ cnorm, const float* __restrict__ scl) {
    const int bid = blockIdx.x;
    const int t = threadIdx.x;
    if (bid < 2048) {
        const float inve = 16384.f / scl[1];
        const size_t i4 = ((size_t)bid * 256 + t) * 4;
        const float4 v = *(const float4*)(cb + i4);
        signed char h0, h1, h2, h3, l0, l1, l2, l3;
        enc8(v.x, inve, h0, l0); enc8(v.y, inve, h1, l1);
        enc8(v.z, inve, h2, l2); enc8(v.w, inve, h3, l3);
        *(char4*)(Bh + i4) = make_char4(h0, h1, h2, h3);
        *(char4*)(Bl + i4) = make_char4(l0, l1, l2, l3);
        float s = v.x * v.x + v.y * v.y + v.z * v.z + v.w * v.w;
        #pragma unroll
        for (int off = 32; off; off >>= 1) s += __shfl_down(s, off);
        if ((t & 63) == 0) cnorm[i4 >> 8] = s;
    } else {
        const float invx = 16384.f / scl[0];
        __shared__ float xt[64][65];
        const int xb_id = bid - 2048;       // 8 b * 4 ct * 64 st = 2048
        const int st = xb_id & 63;
        const int ct = (xb_id >> 6) & 3;
        const int b  = xb_id >> 8;
        const float* xb = x + ((size_t)b * C_DIM + ct * 64) * 4096 + st * 64;
        {
            const int s_l = t & 63, c0 = t >> 6;
            #pragma unroll
            for (int cc = 0; cc < 16; ++cc) {
                int c_l = cc * 4 + c0;
                xt[c_l][s_l] = xb[(size_t)c_l * 4096 + s_l];
            }
        }
        __syncthreads();
        const int c2 = (t & 31) * 2;
        const int s0 = t >> 5;
        #pragma unroll
        for (int ww = 0; ww < 8; ++ww) {
            int s_o = ww * 8 + s0;
            signed char h0, l0, h1, l1;
            enc8(xt[c2][s_o], invx, h0, l0);
            enc8(xt[c2 + 1][s_o], invx, h1, l1);
            size_t off = ((size_t)(b * 4096 + st * 64 + s_o)) * C_DIM + ct * 64 + c2;
            *(char2*)(Ah + off) = make_char2(h0, h1);
            *(char2*)(Al + off) = make_char2(l0, l1);
        }
    }
}

// ---------------- i8 MFMA distance GEMM + per-row top-2 argmin ----------------
// 128x256 tile, 8 waves (2Mx4N), per-wave 64x64 (acc[4][4]).
// BK=64 i8; 12 K-tiles: 0-3 (h,h), <<7, 4-7 (h,l), 8-11 (l,h).
// LDS 48KB dbuf, 2 blocks/CU. Swizzle slot = base ^ (row&3) ^ ((row>>2)&3)
// -> exact 2-way bank aliasing (free) instead of r13's 4-way.
__global__ __launch_bounds__(512, 4)
void kargmin_i8(const signed char* __restrict__ Ah, const signed char* __restrict__ Al,
                const signed char* __restrict__ Bh, const signed char* __restrict__ Bl,
                const float* __restrict__ cnorm, const float* __restrict__ scl,
                u64* __restrict__ wsmin) {
    __shared__ unsigned char As[2][128 * 64];   // 8KB x2
    __shared__ unsigned char Bs[2][256 * 64];   // 16KB x2

    const int t = threadIdx.x;
    const int lane = t & 63;
    const int wid = t >> 6;
    const int xcd = blockIdx.x & 7;
    const int ii = blockIdx.x >> 3;              // 0..1023 within XCD
    const int ntile = xcd * 4 + (ii & 3);        // 0..31
    const int mtile = ii >> 2;                   // 0..255
    const int m0 = mtile * 128;
    const int n0 = ntile * 256;
    const int wr = wid >> 2;                     // 0..1
    const int wc = wid & 3;                      // 0..3
    const int wm = wr * 64;
    const int wn = wc * 64;
    const int lm = lane & 15;
    const int lh = lane >> 4;
    const int NKT = 12;

    i32x4 acc[4][4];
    #pragma unroll
    for (int i = 0; i < 4; ++i)
        #pragma unroll
        for (int j = 0; j < 4; ++j) acc[i][j] = (i32x4){0, 0, 0, 0};

    const signed char* const PAp[3] = {Ah, Ah, Al};
    const signed char* const PBp[3] = {Bh, Bl, Bh};

    // staging: rows of 64B = 4 slots of 16B; swizzle slot ^= (row&3)^((row>>2)&3)
    const int sAr = t >> 2;          // A row 0..127
    const int ssl = t & 3;
    const int gsA = ssl ^ (sAr & 3) ^ ((sAr >> 2) & 3);

    auto stage = [&](int kt, int buf) {
        const int seg = kt >> 2;
        const int kk0 = (kt & 3) * 64;
        const signed char* Ab = PAp[seg] + (size_t)m0 * 256 + kk0;
        const signed char* Bb = PBp[seg] + (size_t)n0 * 256 + kk0;
        GLDS16(Ab + (size_t)sAr * 256 + gsA * 16, &As[buf][t * 16]);
        #pragma unroll
        for (int it = 0; it < 2; ++it) {
            const int chunk = it * 512 + t;
            const int r = it * 128 + sAr;        // r&3==sAr&3, (r>>2)&3==(sAr>>2)&3
            GLDS16(Bb + (size_t)r * 256 + gsA * 16, &Bs[buf][chunk * 16]);
        }
    };

    const int rboff = (lh ^ (lm & 3) ^ ((lm >> 2) & 3)) * 16;   // 2-way-free slot

    stage(0, 0);
    __syncthreads();

    for (int kt = 0; kt < NKT; ++kt) {
        const int cur = kt & 1;
        if (kt + 1 < NKT) stage(kt + 1, cur ^ 1);
        i32x4 a[4], b[4];
        #pragma unroll
        for (int j = 0; j < 4; ++j)
            b[j] = *(const i32x4*)&Bs[cur][(wn + j * 16 + lm) * 64 + rboff];
        #pragma unroll
        for (int i = 0; i < 4; ++i)
            a[i] = *(const i32x4*)&As[cur][(wm + i * 16 + lm) * 64 + rboff];
        #pragma unroll
        for (int i = 0; i < 4; ++i)
            #pragma unroll
            for (int j = 0; j < 4; ++j)
                acc[i][j] = __builtin_amdgcn_mfma_i32_16x16x64_i8(a[i], b[j], acc[i][j], 0, 0, 0);
        if (kt == 3) {
            // H segments complete: fold 128*H into the same accumulator
            #pragma unroll
            for (int i = 0; i < 4; ++i)
                #pragma unroll
                for (int j = 0; j < 4; ++j)
                    acc[i][j] = acc[i][j] << 7;
        }
        __syncthreads();
    }

    // epilogue (f32): dist = cnorm - 256*scl2*(128*H + M); per-row top-2
    const float ndsc = -256.f * scl[2];
    float cn[4];
    #pragma unroll
    for (int j = 0; j < 4; ++j) cn[j] = cnorm[n0 + wn + j * 16 + lm];

    u64* redbuf = (u64*)&As[0][0];   // 128 rows x 4 wc x 2 u64 = 8KB
    #pragma unroll
    for (int i = 0; i < 4; ++i) {
        u64 p1[4], p2[4];
        #pragma unroll
        for (int r = 0; r < 4; ++r) {
            u64 b1 = ~0ull, b2 = ~0ull;
            #pragma unroll
            for (int j = 0; j < 4; ++j) {
                const float dist = fmaf(ndsc, (float)acc[i][j][r], cn[j]);
                u64 pk = ((u64)fkey(dist) << 32) | (unsigned)(n0 + wn + j * 16 + lm);
                if (pk < b1) { b2 = b1; b1 = pk; }
                else if (pk < b2) b2 = pk;
            }
            p1[r] = b1; p2[r] = b2;
        }
        #pragma unroll
        for (int off = 1; off < 16; off <<= 1) {
            #pragma unroll
            for (int r = 0; r < 4; ++r) {
                u64 o1 = __shfl_xor(p1[r], off);
                u64 o2 = __shfl_xor(p2[r], off);
                u64 lo = p1[r] < o1 ? p1[r] : o1;
                u64 hi = p1[r] < o1 ? o1 : p1[r];
                u64 mn2 = p2[r] < o2 ? p2[r] : o2;
                p1[r] = lo;
                p2[r] = hi < mn2 ? hi : mn2;
            }
        }
        if (lm == 0) {
            #pragma unroll
            for (int r = 0; r < 4; ++r) {
                const int rl = wm + i * 16 + lh * 4 + r;   // 0..127
                redbuf[rl * 8 + wc * 2 + 0] = p1[r];
                redbuf[rl * 8 + wc * 2 + 1] = p2[r];
            }
        }
    }
    __syncthreads();
    if (t < 128) {
        u64 m1 = ~0ull, m2 = ~0ull;
        #pragma unroll
        for (int w = 0; w < 4; ++w) {
            u64 a1 = redbuf[t * 8 + w * 2 + 0];
            u64 a2 = redbuf[t * 8 + w * 2 + 1];
            u64 lo = m1 < a1 ? m1 : a1;
            u64 hi = m1 < a1 ? a1 : m1;
            u64 mn2 = m2 < a2 ? m2 : a2;
            m1 = lo;
            m2 = hi < mn2 ? hi : mn2;
        }
        size_t o = ((size_t)(m0 + t) * 32 + ntile) * 2;
        wsmin[o] = m1; wsmin[o + 1] = m2;
    }
}

// ---------------- combine per-ntile mins; histogram; flag near-ties ----------------
__global__ void kcombine(const u64* __restrict__ wsmin, float* __restrict__ idxf,
                         unsigned* __restrict__ rcnt, unsigned* __restrict__ rrows,
                         uint2* __restrict__ rpair, float* __restrict__ counts) {
    const int row = blockIdx.x * 256 + threadIdx.x;
    const u64* p = wsmin + (size_t)row * 64;
    u64 m1 = ~0ull, m2 = ~0ull;
    for (int i = 0; i < 64; i += 2) {
        u64 a = p[i], b = p[i + 1];
        u64 lo = a < m1 ? a : m1;
        u64 hi = a < m1 ? m1 : a;
        u64 c = m2 < b ? m2 : b;
        m1 = lo;
        m2 = hi < c ? hi : c;
    }
    const int k = (int)(unsigned)(m1 & 0xffffffffu);
    idxf[row] = (float)k;
    atomicAdd(&counts[k], 1.0f);
    float d1 = funkey((uint32_t)(m1 >> 32));
    float d2 = funkey((uint32_t)(m2 >> 32));
    if (d2 - d1 < RESC_EPS) {
        unsigned slot = atomicAdd(rcnt, 1u);
        if (slot < RESC_CAP) {
            rrows[slot] = (unsigned)row;
            rpair[slot] = make_uint2((unsigned)k, (unsigned)(m2 & 0xffffffffu));
        }
    }
}

// ---------------- exact fp32 pair re-score (wave per flagged row) ----------------
__global__ __launch_bounds__(256)
void krescue2(const float* __restrict__ x, const float* __restrict__ cb,
              const float* __restrict__ cnorm, const unsigned* __restrict__ rcnt,
              const unsigned* __restrict__ rrows, const uint2* __restrict__ rpair,
              float* __restrict__ idxf, float* __restrict__ counts) {
    const int lane = threadIdx.x & 63;
    const int wv = threadIdx.x >> 6;
    unsigned cnt = *rcnt; if (cnt > RESC_CAP) cnt = RESC_CAP;
    for (unsigned i = blockIdx.x * 4 + wv; i < cnt; i += gridDim.x * 4) {
        const int row = (int)rrows[i];
        const uint2 kk = rpair[i];
        const int b = row >> 12, s = row & 4095;
        float d1 = 0.f, d2 = 0.f;
        #pragma unroll
        for (int q = 0; q < 4; ++q) {
            const int c = lane + q * 64;
            const float xv = x[((size_t)(b * 256 + c)) * 4096 + s];
            d1 = fmaf(xv, cb[(size_t)kk.x * 256 + c], d1);
            d2 = fmaf(xv, cb[(size_t)kk.y * 256 + c], d2);
        }
        #pragma unroll
        for (int off = 32; off; off >>= 1) {
            d1 += __shfl_down(d1, off);
            d2 += __shfl_down(d2, off);
        }
        if (lane == 0) {
            const float dist1 = fmaf(-2.f, d1, cnorm[kk.x]);
            const float dist2 = fmaf(-2.f, d2, cnorm[kk.y]);
            const u64 p1 = ((u64)fkey(dist1) << 32) | kk.x;
            const u64 p2 = ((u64)fkey(dist2) << 32) | kk.y;
            const int knew = (int)(unsigned)((p1 < p2 ? p1 : p2) & 0xffffffffu);
            const int kold = (int)kk.x;
            if (knew != kold) {
                atomicAdd(&counts[kold], -1.0f);
                atomicAdd(&counts[knew], 1.0f);
                idxf[row] = (float)knew;
            }
        }
    }
}

// ---------------- CSR build: scan / scatter ----------------
__global__ void kscan(const float* __restrict__ counts, unsigned* __restrict__ off,
                      unsigned* __restrict__ cursor) {
    __shared__ unsigned part[256];
    const int t = threadIdx.x;
    unsigned local[32];
    unsigned s = 0;
    #pragma unroll
    for (int i = 0; i < 32; ++i) { local[i] = s; s += (unsigned)counts[t * 32 + i]; }
    part[t] = s;
    __syncthreads();
    if (t == 0) {
        unsigned run = 0;
        for (int i = 0; i < 256; ++i) { unsigned v = part[i]; part[i] = run; run += v; }
    }
    __syncthreads();
    const unsigned base = part[t];
    #pragma unroll
    for (int i = 0; i < 32; ++i) {
        unsigned o = base + local[i];
        off[t * 32 + i] = o;
        cursor[t * 32 + i] = o;
    }
}

__global__ void kscatter(const float* __restrict__ idxf, unsigned* __restrict__ cursor,
                         unsigned* __restrict__ rowlist) {
    const int n = blockIdx.x * 256 + threadIdx.x;
    const int k = (int)idxf[n];
    unsigned pos = atomicAdd(&cursor[k], 1u);
    rowlist[pos] = (unsigned)n;
}

// ---------------- dw = segment_sum(x) via CSR, exact-int from i8 planes ----------------
__global__ void kdw(const signed char* __restrict__ Ah, const signed char* __restrict__ Al,
                    const float* __restrict__ counts, const unsigned* __restrict__ off,
                    const unsigned* __restrict__ rowlist, const float* __restrict__ scl,
                    float* __restrict__ dwout) {
    const int k = blockIdx.x;
    const int lane = threadIdx.x;   // 64
    const int cnt = (int)counts[k];
    const unsigned base = off[k];
    int ax = 0, ay = 0, az = 0, aw = 0;
    for (int i = 0; i < cnt; ++i) {
        const unsigned row = rowlist[base + i];
        const char4 h = *(const char4*)(Ah + (size_t)row * C_DIM + lane * 4);
        const char4 l = *(const char4*)(Al + (size_t)row * C_DIM + lane * 4);
        ax += h.x * 128 + l.x;
        ay += h.y * 128 + l.y;
        az += h.z * 128 + l.z;
        aw += h.w * 128 + l.w;
    }
    const float sxf = scl[0] * (1.f / 16384.f);
    float4 o;
    o.x = (float)ax * sxf; o.y = (float)ay * sxf;
    o.z = (float)az * sxf; o.w = (float)aw * sxf;
    *(float4*)(dwout + (size_t)k * C_DIM + lane * 4) = o;
}

// ---------------- quantize (gather-transpose) + e_loss ----------------
__global__ __launch_bounds__(256)
void kquant2(const float* __restrict__ x, const float* __restrict__ cb,
             const float* __restrict__ idxf, float* __restrict__ qout,
             float* __restrict__ loss_arr) {
    __shared__ int ki[64];
    __shared__ float cbt[64][257];
    const int t = threadIdx.x;
    const int bid = blockIdx.x;
    const int chunk = bid & 63;
    const int b = bid >> 6;
    const int s0 = chunk * 64;
    if (t < 64) ki[t] = (int)idxf[b * 4096 + s0 + t];
    __syncthreads();
    {
        const int lane = t & 63;
        const int rr = t >> 6;
        #pragma unroll
        for (int p = 0; p < 16; ++p) {
            const int r = p * 4 + rr;
            const float4 v = *(const float4*)(cb + (size_t)ki[r] * C_DIM + lane * 4);
            cbt[r][lane * 4 + 0] = v.x;
            cbt[r][lane * 4 + 1] = v.y;
            cbt[r][lane * 4 + 2] = v.z;
            cbt[r][lane * 4 + 3] = v.w;
        }
    }
    __syncthreads();
    const int sg = t & 15;
    const int c0 = t >> 4;
    float lsum = 0.f;
    #pragma unroll
    for (int cc = 0; cc < 16; ++cc) {
        const int c = cc * 16 + c0;
        const size_t go = ((size_t)b * C_DIM + c) * 4096 + s0 + sg * 4;
        const float4 xv = *(const float4*)(x + go);
        float qx = cbt[sg * 4 + 0][c];
        float qy = cbt[sg * 4 + 1][c];
        float qz = cbt[sg * 4 + 2][c];
        float qw = cbt[sg * 4 + 3][c];
        float4 st;
        st.x = xv.x + (qx - xv.x);
        st.y = xv.y + (qy - xv.y);
        st.z = xv.z + (qz - xv.z);
        st.w = xv.w + (qw - xv.w);
        *(float4*)(qout + go) = st;
        float dx = qx - xv.x, dy = qy - xv.y, dz = qz - xv.z, dw_ = qw - xv.w;
        lsum += dx * dx + dy * dy + dz * dz + dw_ * dw_;
    }
    #pragma unroll
    for (int off = 32; off; off >>= 1) lsum += __shfl_down(lsum, off);
    __shared__ float ps[4];
    if ((t & 63) == 0) ps[t >> 6] = lsum;
    __syncthreads();
    if (t == 0) atomicAdd(&loss_arr[bid & 255], ps[0] + ps[1] + ps[2] + ps[3]);
}

// ---------------- EMA finalize + stats (fused; block K_CODES does stats) ----------------
__global__ void kfinal2(const float* __restrict__ ema_c, const float* __restrict__ ema_w,
                        const float* __restrict__ counts, float* __restrict__ dw,
                        float* __restrict__ ncb, float* __restrict__ ncnt_out,
                        const float* __restrict__ loss_arr, float* __restrict__ out) {
    const int k = blockIdx.x;
    const int t = threadIdx.x;
    if (k < K_CODES) {
        const float ncnt = (DECAYF * ema_c[k] + (1.f - DECAYF) * counts[k] + EPSF)
                           / (8.f + (float)K_CODES * EPSF) * 8.f;
        const size_t o = (size_t)k * C_DIM + t;
        const float nwv = DECAYF * ema_w[o] + (1.f - DECAYF) * dw[o];
        dw[o]  = nwv;
        ncb[o] = nwv / ncnt;
        if (t == 0) ncnt_out[k] = ncnt;
    } else {
        float nz = 0.f, s = 0.f;
        for (int kk = t; kk < K_CODES; kk += 256) {
            float cnt = counts[kk];
            if (cnt != 0.f) nz += 1.f;
            float p = cnt * (1.f / 32768.f);
            s += p * logf(p + 1e-10f);
        }
        float ls = loss_arr[t];
        #pragma unroll
        for (int off = 32; off; off >>= 1) {
            s  += __shfl_down(s, off);
            nz += __shfl_down(nz, off);
            ls += __shfl_down(ls, off);
        }
        __shared__ float ss[4], zz[4], ll[4];
        const int wid = t >> 6, lane = t & 63;
        if (lane == 0) { ss[wid] = s; zz[wid] = nz; ll[wid] = ls; }
        __syncthreads();
        if (t == 0) {
            float st = ss[0] + ss[1] + ss[2] + ss[3];
            float zt = zz[0] + zz[1] + zz[2] + zz[3];
            float lt = ll[0] + ll[1] + ll[2] + ll[3];
            out[OFF_ELOSS] = COMMITF * lt / 8388608.f;
            out[OFF_PERP]  = expf(-st);
            out[OFF_UNIQ]  = zt;
        }
    }
}

// ======= fallback fp32 path (used only if ws too small) =======
__global__ void knorm(const float* __restrict__ cb, float* __restrict__ cnorm) {
    const int wid  = threadIdx.x >> 6;
    const int lane = threadIdx.x & 63;
    const int row  = blockIdx.x * 4 + wid;
    const float4 v = *(const float4*)(cb + (size_t)row * C_DIM + lane * 4);
    float s = v.x * v.x + v.y * v.y + v.z * v.z + v.w * v.w;
    #pragma unroll
    for (int off = 32; off; off >>= 1) s += __shfl_down(s, off);
    if (lane == 0) cnorm[row] = s;
}

__launch_bounds__(256, 1)
__global__ void kargmin_fp32(const float* __restrict__ x, const float* __restrict__ cb,
                             const float* __restrict__ cnorm, float* __restrict__ idxf) {
    __shared__ float xs[64][256];
    __shared__ float es[64][256];
    const int t  = threadIdx.x;
    const int n0 = blockIdx.x * 64;
    const int b  = n0 >> 12;
    const int s0 = n0 & 4095;
    {
        const int r  = t & 63;
        const int c0 = t >> 6;
        const float* xb = x + (size_t)b * C_DIM * 4096 + s0 + r;
        const int sw = SWZ(r);
        #pragma unroll 8
        for (int cc = 0; cc < 64; ++cc) {
            int c = cc * 4 + c0;
            xs[r][c ^ sw] = xb[(size_t)c * 4096];
        }
    }
    const int mg  = t >> 4;
    const int ng  = t & 15;
    const int m0  = mg * 4;
    const int nn0 = ng * 4;
    const int swm = SWZ(m0);
    const int swn = SWZ(nn0);
    float minv[4] = {1e30f, 1e30f, 1e30f, 1e30f};
    int   mini[4] = {0, 0, 0, 0};
    for (int k0 = 0; k0 < K_CODES; k0 += 64) {
        __syncthreads();
        {
            const int lane = t & 63;
            const int cw   = t >> 6;
            #pragma unroll
            for (int p = 0; p < 16; ++p) {
                int code = p * 4 + cw;
                float4 v = *(const float4*)(cb + (size_t)(k0 + code) * C_DIM + lane * 4);
                *(float4*)&es[code][(lane * 4) ^ SWZ(code)] = v;
            }
        }
        float cn[4];
        #pragma unroll
        for (int j = 0; j < 4; ++j) cn[j] = cnorm[k0 + nn0 + j];
        __syncthreads();
        float acc[4][4];
        #pragma unroll
        for (int i = 0; i < 4; ++i)
            #pragma unroll
            for (int j = 0; j < 4; ++j) acc[i][j] = 0.f;
        #pragma unroll 4
        for (int c = 0; c < C_DIM; c += 4) {
            float4 xa[4], eb[4];
            #pragma unroll
            for (int i = 0; i < 4; ++i) xa[i] = *(const float4*)&xs[m0 + i][c ^ swm];
            #pragma unroll
            for (int j = 0; j < 4; ++j) eb[j] = *(const float4*)&es[nn0 + j][c ^ swn];
            #pragma unroll
            for (int i = 0; i < 4; ++i)
                #pragma unroll
                for (int j = 0; j < 4; ++j)
                    acc[i][j] += xa[i].x * eb[j].x + xa[i].y * eb[j].y +
                                 xa[i].z * eb[j].z + xa[i].w * eb[j].w;
        }
        #pragma unroll
        for (int j = 0; j < 4; ++j) {
            const int kg = k0 + nn0 + j;
            #pragma unroll
            for (int i = 0; i < 4; ++i) {
                float dist = fmaf(-2.f, acc[i][j], cn[j]);
                if (dist < minv[i]) { minv[i] = dist; mini[i] = kg; }
            }
        }
    }
    #pragma unroll
    for (int off = 1; off < 16; off <<= 1) {
        #pragma unroll
        for (int i = 0; i < 4; ++i) {
            float ov = __shfl_xor(minv[i], off);
            int   oi = __shfl_xor(mini[i], off);
            if (ov < minv[i] || (ov == minv[i] && oi < mini[i])) { minv[i] = ov; mini[i] = oi; }
        }
    }
    if (ng == 0) {
        #pragma unroll
        for (int i = 0; i < 4; ++i) idxf[n0 + m0 + i] = (float)mini[i];
    }
}

__global__ void kquant_legacy(const float* __restrict__ x, const float* __restrict__ cb,
                              const float* __restrict__ idxf, float* __restrict__ qout,
                              float* __restrict__ dw, float* __restrict__ counts,
                              float* __restrict__ loss_arr) {
    const int t   = threadIdx.x;
    const int bid = blockIdx.x;
    const int sc  = bid & 15;
    const int c   = (bid >> 4) & 255;
    const int b   = bid >> 12;
    const int s   = sc * 256 + t;
    const int n   = b * 4096 + s;
    const int k   = (int)idxf[n];
    const size_t xoff = ((size_t)b * C_DIM + c) * 4096 + s;
    const float xv = x[xoff];
    const float q  = cb[(size_t)k * C_DIM + c];
    qout[xoff] = xv + (q - xv);
    atomicAdd(&dw[(size_t)k * C_DIM + c], xv);
    if (c == 0) atomicAdd(&counts[k], 1.0f);
    float d = q - xv;
    float p = d * d;
    #pragma unroll
    for (int off = 32; off; off >>= 1) p += __shfl_down(p, off);
    __shared__ float ps[4];
    if ((t & 63) == 0) ps[t >> 6] = p;
    __syncthreads();
    if (t == 0) atomicAdd(&loss_arr[bid & 255], ps[0] + ps[1] + ps[2] + ps[3]);
}

__global__ void kstats_legacy(const float* __restrict__ counts, const float* __restrict__ loss_arr,
                              float* __restrict__ out) {
    const int t = threadIdx.x;
    float nz = 0.f, s = 0.f;
    for (int k = t; k < K_CODES; k += 256) {
        float cnt = counts[k];
        if (cnt != 0.f) nz += 1.f;
        float p = cnt * (1.f / 32768.f);
        s += p * logf(p + 1e-10f);
    }
    float ls = loss_arr[t];
    #pragma unroll
    for (int off = 32; off; off >>= 1) {
        s  += __shfl_down(s, off);
        nz += __shfl_down(nz, off);
        ls += __shfl_down(ls, off);
    }
    __shared__ float ss[4], zz[4], ll[4];
    const int wid = t >> 6, lane = t & 63;
    if (lane == 0) { ss[wid] = s; zz[wid] = nz; ll[wid] = ls; }
    __syncthreads();
    if (t == 0) {
        out[OFF_ELOSS] = COMMITF * (ll[0] + ll[1] + ll[2] + ll[3]) / 8388608.f;
        out[OFF_PERP]  = expf(-(ss[0] + ss[1] + ss[2] + ss[3]));
        out[OFF_UNIQ]  = zz[0] + zz[1] + zz[2] + zz[3];
    }
}

__global__ void kfinal_legacy(const float* __restrict__ ema_c, const float* __restrict__ ema_w,
                              float* __restrict__ counts, float* __restrict__ dw,
                              float* __restrict__ ncb) {
    const int k = blockIdx.x;
    const int c = threadIdx.x;
    const float cnt  = counts[k];
    const float ncnt = (DECAYF * ema_c[k] + (1.f - DECAYF) * cnt + EPSF)
                       / (8.f + (float)K_CODES * EPSF) * 8.f;
    const size_t o = (size_t)k * C_DIM + c;
    const float nw = DECAYF * ema_w[o] + (1.f - DECAYF) * dw[o];
    __syncthreads();
    dw[o]  = nw;
    ncb[o] = nw / ncnt;
    if (c == 0) counts[k] = ncnt;
}

extern "C" void kernel_launch(void* const* d_in, const int* in_sizes, int n_in,
                              void* d_out, int out_size, void* d_ws, size_t ws_size,
                              hipStream_t stream) {
    const float* x     = (const float*)d_in[0];
    const float* cb    = (const float*)d_in[1];
    const float* ema_c = (const float*)d_in[2];
    const float* ema_w = (const float*)d_in[3];
    float* out = (float*)d_out;

    float* qout = out + OFF_QUANT;
    float* ncb  = out + OFF_NCB;
    float* ncnt = out + OFF_NCNT;
    float* nw   = out + OFF_NW;
    float* idxf = out + OFF_IDX;

    const size_t szA = (size_t)N_ROWS * C_DIM;    // 8388608 bytes per plane
    const size_t szB = (size_t)K_CODES * C_DIM;   // 2097152
    const size_t fcount = 8192 + 256 + 8192 + 4 + 2560;
    const size_t need = 2 * szA + 2 * szB + fcount * 4
                      + RESC_CAP * 8 + RESC_CAP * 4 + 4 + 8192 * 4 * 2 + 32768 * 4 + 64;
    const bool use_i8 = ws_size >= need;

    if (use_i8) {
        signed char* Ah = (signed char*)d_ws;
        signed char* Al = Ah + szA;
        signed char* Bh = Al + szA;
        signed char* Bl = Bh + szB;
        float* fbase      = (float*)(Bl + szB);
        float* cnorm      = fbase;
        float* loss_arr   = fbase + 8192;
        float* counts_raw = fbase + 8448;
        float* scl        = fbase + 16640;
        float* maxbuf     = fbase + 16644;
        uint2* rpair      = (uint2*)(fbase + fcount);
        unsigned* rrows   = (unsigned*)(rpair + RESC_CAP);
        unsigned* rcnt    = rrows + RESC_CAP;
        unsigned* off     = rcnt + 1;
        unsigned* cursor  = off + K_CODES;
        unsigned* rowlist = cursor + K_CODES;
        u64* wsmin = (u64*)(out + OFF_QUANT);   // 16.8 MB, consumed before kquant2 writes qout

        kmax<<<2560, 256, 0, stream>>>(x, cb, maxbuf);
        kscale<<<1, 256, 0, stream>>>(maxbuf, scl, counts_raw, loss_arr, rcnt);
        kprep<<<4096, 256, 0, stream>>>(cb, x, Ah, Al, Bh, Bl, cnorm, scl);
        kargmin_i8<<<8192, 512, 0, stream>>>(Ah, Al, Bh, Bl, cnorm, scl, wsmin);
        kcombine<<<N_ROWS / 256, 256, 0, stream>>>(wsmin, idxf, rcnt, rrows, rpair, counts_raw);
        krescue2<<<256, 256, 0, stream>>>(x, cb, cnorm, rcnt, rrows, rpair, idxf, counts_raw);
        kscan<<<1, 256, 0, stream>>>(counts_raw, off, cursor);
        kscatter<<<N_ROWS / 256, 256, 0, stream>>>(idxf, cursor, rowlist);
        kdw<<<K_CODES, 64, 0, stream>>>(Ah, Al, counts_raw, off, rowlist, scl, nw);
        kquant2<<<512, 256, 0, stream>>>(x, cb, idxf, qout, loss_arr);
        kfinal2<<<K_CODES + 1, C_DIM, 0, stream>>>(ema_c, ema_w, counts_raw, nw, ncb, ncnt,
                                                   loss_arr, out);
    } else {
        float* cnorm = (float*)d_ws;
        float* loss_arr = cnorm + K_CODES;
        hipMemsetAsync(ncnt, 0, K_CODES * sizeof(float), stream);
        hipMemsetAsync(nw, 0, (size_t)K_CODES * C_DIM * sizeof(float), stream);
        hipMemsetAsync(loss_arr, 0, 256 * sizeof(float), stream);
        knorm<<<K_CODES / 4, 256, 0, stream>>>(cb, cnorm);
        kargmin_fp32<<<N_ROWS / 64, 256, 0, stream>>>(x, cb, cnorm, idxf);
        kquant_legacy<<<32768, 256, 0, stream>>>(x, cb, idxf, qout, nw, ncnt, loss_arr);
        kstats_legacy<<<1, 256, 0, stream>>>(ncnt, loss_arr, out);
        kfinal_legacy<<<K_CODES, C_DIM, 0, stream>>>(ema_c, ema_w, ncnt, nw, ncb);
    }
}